// Round 2
// baseline (3374.894 us; speedup 1.0000x reference)
//
#include <hip/hip_runtime.h>

#define N_NODES 100000
#define N_EDGES 400000
#define N_GRAPHS 5000
#define NPG 20

// ---------------- node encoder: h0[N,64] (cols 52..63 zero) ----------------
__global__ void k_encode_nodes(const float* __restrict__ x,
                               const float* __restrict__ atom_emb,
                               const float* __restrict__ bool_emb,
                               const float* __restrict__ Wn,
                               const float* __restrict__ bn,
                               float* __restrict__ h0) {
  int n = blockIdx.x * blockDim.x + threadIdx.x;
  if (n >= N_NODES) return;
  const float* xr = x + (size_t)n * 14;
  float* h = h0 + (size_t)n * 64;
  int ai = (int)xr[0];
  #pragma unroll
  for (int j = 0; j < 16; j++) h[j] = atom_emb[ai * 16 + j];
  float xc[10];
  #pragma unroll
  for (int k = 0; k < 10; k++) xc[k] = xr[1 + k];
  #pragma unroll
  for (int c = 0; c < 30; c++) {
    float s = bn[c];
    #pragma unroll
    for (int k = 0; k < 10; k++) s += xc[k] * Wn[k * 30 + c];
    h[16 + c] = s;
  }
  #pragma unroll
  for (int t = 0; t < 3; t++) {
    int b = (int)xr[11 + t];
    h[46 + 2 * t]     = bool_emb[2 * b];
    h[46 + 2 * t + 1] = bool_emb[2 * b + 1];
  }
  #pragma unroll
  for (int j = 52; j < 64; j++) h[j] = 0.0f;  // zero pad for K=64 GEMM
}

// ---------------- edge encoder (no float atomics) + int degree histogram ----
__global__ void k_encode_edges(const float* __restrict__ eattr,
                               const int* __restrict__ dst,
                               const float* __restrict__ bond_emb,
                               const float* __restrict__ bool_emb,
                               const float* __restrict__ We,
                               const float* __restrict__ be,
                               float* __restrict__ e_full,
                               int* __restrict__ cnt) {
  int e = blockIdx.x * blockDim.x + threadIdx.x;
  if (e >= N_EDGES) return;
  const float* r = eattr + (size_t)e * 5;
  float row[16];
  int bi = (int)r[0];
  #pragma unroll
  for (int j = 0; j < 8; j++) row[j] = bond_emb[bi * 8 + j];
  float ec = r[1];
  row[8] = ec * We[0] + be[0];
  row[9] = ec * We[1] + be[1];
  #pragma unroll
  for (int t = 0; t < 3; t++) {
    int b = (int)r[2 + t];
    row[10 + 2 * t]     = bool_emb[2 * b];
    row[10 + 2 * t + 1] = bool_emb[2 * b + 1];
  }
  float4* out = (float4*)(e_full + (size_t)e * 16);
  out[0] = make_float4(row[0], row[1], row[2], row[3]);
  out[1] = make_float4(row[4], row[5], row[6], row[7]);
  out[2] = make_float4(row[8], row[9], row[10], row[11]);
  out[3] = make_float4(row[12], row[13], row[14], row[15]);
  atomicAdd(cnt + dst[e], 1);
}

// ---------------- single-block exclusive scan over (cnt[n]+1) ----------------
__global__ __launch_bounds__(1024) void k_scan(const int* __restrict__ cnt,
                                               int* __restrict__ indptr,
                                               int* __restrict__ cursor) {
  __shared__ int sums[1024];
  int t = threadIdx.x;
  const int per = (N_NODES + 1023) / 1024;
  int beg = t * per;
  int end = beg + per; if (end > N_NODES) end = N_NODES;
  int s = 0;
  for (int i = beg; i < end; i++) s += cnt[i] + 1;
  sums[t] = s;
  __syncthreads();
  for (int off = 1; off < 1024; off <<= 1) {
    int v = (t >= off) ? sums[t - off] : 0;
    __syncthreads();
    sums[t] += v;
    __syncthreads();
  }
  int run = (t > 0) ? sums[t - 1] : 0;
  for (int i = beg; i < end; i++) {
    indptr[i] = run;
    cursor[i] = run;
    run += cnt[i] + 1;
  }
  if (t == 1023) indptr[N_NODES] = sums[1023];
}

// ---------------- CSR fill (edges then self-loops) ----------------
__global__ void k_fill(const int* __restrict__ dst,
                       int* __restrict__ cursor,
                       int* __restrict__ eord) {
  int i = blockIdx.x * blockDim.x + threadIdx.x;
  if (i >= N_EDGES + N_NODES) return;
  int d = (i < N_EDGES) ? dst[i] : (i - N_EDGES);
  int p = atomicAdd(&cursor[d], 1);
  eord[p] = i;
}

// ---------------- loop_attr[n] = mean of in-edge attrs (CSR pass) -----------
__global__ void k_loop_attr(const int* __restrict__ indptr,
                            const int* __restrict__ eord,
                            float* __restrict__ e_full) {
  int n = blockIdx.x * blockDim.x + threadIdx.x;
  if (n >= N_NODES) return;
  int beg = indptr[n], end = indptr[n + 1];
  float4 s0 = make_float4(0, 0, 0, 0), s1 = s0, s2 = s0, s3 = s0;
  int c = 0;
  for (int j = beg; j < end; j++) {
    int eid = eord[j];
    if (eid >= N_EDGES) continue;
    const float4* ep = (const float4*)(e_full + (size_t)eid * 16);
    float4 a = ep[0], b = ep[1], cc = ep[2], d = ep[3];
    s0.x += a.x; s0.y += a.y; s0.z += a.z; s0.w += a.w;
    s1.x += b.x; s1.y += b.y; s1.z += b.z; s1.w += b.w;
    s2.x += cc.x; s2.y += cc.y; s2.z += cc.z; s2.w += cc.w;
    s3.x += d.x; s3.y += d.y; s3.z += d.z; s3.w += d.w;
    c++;
  }
  float inv = 1.0f / (float)(c > 0 ? c : 1);
  s0.x *= inv; s0.y *= inv; s0.z *= inv; s0.w *= inv;
  s1.x *= inv; s1.y *= inv; s1.z *= inv; s1.w *= inv;
  s2.x *= inv; s2.y *= inv; s2.z *= inv; s2.w *= inv;
  s3.x *= inv; s3.y *= inv; s3.z *= inv; s3.w *= inv;
  float4* lp = (float4*)(e_full + (size_t)(N_EDGES + n) * 16);
  lp[0] = s0; lp[1] = s1; lp[2] = s2; lp[3] = s3;
}

// ---------------- tiled GEMM: out[N,128] = A[N,KPAD(:K)] @ W[K,128] + b -----
// Block: 256 threads, tile 64 rows x 128 cols, TK=64.
// Thread (tx=tid&15, ty=tid>>4) computes rows ty*4..+3, cols tx*8..+7.
template <int KPAD, int K>
__global__ __launch_bounds__(256) void k_gemm(const float* __restrict__ A,
                                              const float* __restrict__ W,
                                              const float* __restrict__ b,
                                              float* __restrict__ out) {
  __shared__ float As[64][68];    // As[k][row], padded; float4-aligned rows
  __shared__ float Ws[64 * 128];  // Ws[k][col]
  const int tid = threadIdx.x;
  const int tx = tid & 15, ty = tid >> 4;
  const int lane = tid & 63, wv = tid >> 6;
  const int m0 = blockIdx.x * 64;
  const int r0 = ty * 4, c0 = tx * 8;

  float acc[4][8];
  #pragma unroll
  for (int i = 0; i < 4; i++)
    #pragma unroll
    for (int j = 0; j < 8; j++) acc[i][j] = 0.0f;

  const int arow = m0 + lane < N_NODES ? m0 + lane : N_NODES - 1;

  for (int kk0 = 0; kk0 < KPAD; kk0 += 64) {
    // stage A tile transposed: wave wv loads ks [wv*16, wv*16+16) of row `lane`
    {
      const float* ap = A + (size_t)arow * KPAD + kk0 + wv * 16;
      float4 v0 = ((const float4*)ap)[0];
      float4 v1 = ((const float4*)ap)[1];
      float4 v2 = ((const float4*)ap)[2];
      float4 v3 = ((const float4*)ap)[3];
      int kb = wv * 16;
      As[kb + 0][lane] = v0.x; As[kb + 1][lane] = v0.y; As[kb + 2][lane] = v0.z; As[kb + 3][lane] = v0.w;
      As[kb + 4][lane] = v1.x; As[kb + 5][lane] = v1.y; As[kb + 6][lane] = v1.z; As[kb + 7][lane] = v1.w;
      As[kb + 8][lane] = v2.x; As[kb + 9][lane] = v2.y; As[kb +10][lane] = v2.z; As[kb +11][lane] = v2.w;
      As[kb +12][lane] = v3.x; As[kb +13][lane] = v3.y; As[kb +14][lane] = v3.z; As[kb +15][lane] = v3.w;
    }
    // stage W tile: 64x128 floats, clamp rows >= K (A is zero there)
    #pragma unroll
    for (int i = 0; i < 8; i++) {
      int idx = tid + i * 256;        // float4 index
      int row = idx >> 5, col4 = idx & 31;
      int wrow = kk0 + row; if (wrow >= K) wrow = K - 1;
      float4 v = *(const float4*)(W + (size_t)wrow * 128 + col4 * 4);
      *(float4*)(Ws + row * 128 + col4 * 4) = v;
    }
    __syncthreads();
    #pragma unroll
    for (int kk = 0; kk < 64; kk++) {
      float4 av = *(const float4*)&As[kk][r0];
      float4 w0 = *(const float4*)(Ws + kk * 128 + c0);
      float4 w1 = *(const float4*)(Ws + kk * 128 + c0 + 4);
      float a[4] = {av.x, av.y, av.z, av.w};
      float w[8] = {w0.x, w0.y, w0.z, w0.w, w1.x, w1.y, w1.z, w1.w};
      #pragma unroll
      for (int i = 0; i < 4; i++)
        #pragma unroll
        for (int j = 0; j < 8; j++) acc[i][j] += a[i] * w[j];
    }
    __syncthreads();
  }
  float bl[8];
  #pragma unroll
  for (int j = 0; j < 8; j++) bl[j] = b[c0 + j];
  #pragma unroll
  for (int i = 0; i < 4; i++) {
    int n = m0 + r0 + i;
    if (n >= N_NODES) break;
    float4 o0 = make_float4(acc[i][0] + bl[0], acc[i][1] + bl[1], acc[i][2] + bl[2], acc[i][3] + bl[3]);
    float4 o1 = make_float4(acc[i][4] + bl[4], acc[i][5] + bl[5], acc[i][6] + bl[6], acc[i][7] + bl[7]);
    float4* op = (float4*)(out + (size_t)n * 128 + c0);
    op[0] = o0; op[1] = o1;
  }
}

// ---------------- GATv2 edge pass: one wave per dst node, online softmax ----
__global__ __launch_bounds__(256) void k_gat(const float* __restrict__ xl,
                                             const float* __restrict__ xr,
                                             const float* __restrict__ e_full,
                                             const int* __restrict__ srcA,
                                             const int* __restrict__ indptr,
                                             const int* __restrict__ eord,
                                             const float* __restrict__ Wedge,
                                             const float* __restrict__ att,
                                             const float* __restrict__ bias,
                                             float* __restrict__ hout) {
  int wid = (blockIdx.x * 256 + threadIdx.x) >> 6;
  int nw = (gridDim.x * 256) >> 6;
  int lane = threadIdx.x & 63;
  int c = lane * 2;
  float wreg[32];
  #pragma unroll
  for (int k = 0; k < 16; k++) {
    wreg[2 * k]     = Wedge[k * 128 + c];
    wreg[2 * k + 1] = Wedge[k * 128 + c + 1];
  }
  float att0 = att[c], att1 = att[c + 1];
  float b0 = bias[c], b1 = bias[c + 1];
  wid = __builtin_amdgcn_readfirstlane(wid);
  for (int n = wid; n < N_NODES; n += nw) {
    int beg = indptr[n], end = indptr[n + 1];
    float2 xrv = *(const float2*)(xr + (size_t)n * 128 + c);
    float amax = -1e30f, denom = 0.f, acc0 = 0.f, acc1 = 0.f;
    for (int j = beg; j < end; j++) {
      int eid = eord[j];
      int s = (eid < N_EDGES) ? srcA[eid] : n;
      const float4* ep = (const float4*)(e_full + (size_t)eid * 16);
      float4 q0 = ep[0], q1 = ep[1], q2 = ep[2], q3 = ep[3];
      float2 xlv = *(const float2*)(xl + (size_t)s * 128 + c);
      float ev[16] = {q0.x, q0.y, q0.z, q0.w, q1.x, q1.y, q1.z, q1.w,
                      q2.x, q2.y, q2.z, q2.w, q3.x, q3.y, q3.z, q3.w};
      float el0 = 0.f, el1 = 0.f;
      #pragma unroll
      for (int k = 0; k < 16; k++) {
        el0 += ev[k] * wreg[2 * k];
        el1 += ev[k] * wreg[2 * k + 1];
      }
      float m0 = xlv.x + xrv.x + el0;
      float m1 = xlv.y + xrv.y + el1;
      float l0 = m0 > 0.f ? m0 : 0.2f * m0;
      float l1 = m1 > 0.f ? m1 : 0.2f * m1;
      float t = l0 * att0 + l1 * att1;
      #pragma unroll
      for (int off = 1; off < 64; off <<= 1) t += __shfl_xor(t, off, 64);
      // online softmax update (t is wave-uniform after reduction)
      if (t > amax) {
        float sc = __expf(amax - t);
        denom *= sc; acc0 *= sc; acc1 *= sc;
        amax = t;
      }
      float ex = __expf(t - amax);
      denom += ex;
      acc0 += ex * xlv.x;
      acc1 += ex * xlv.y;
    }
    float inv = 1.0f / denom;
    float o0 = acc0 * inv + b0;
    float o1 = acc1 * inv + b1;
    float2 o; o.x = o0 > 0.f ? o0 : 0.f; o.y = o1 > 0.f ? o1 : 0.f;
    *(float2*)(hout + (size_t)n * 128 + c) = o;
  }
}

// ---------------- readout: global max pool over 20 contiguous nodes --------
__global__ void k_readout(const float* __restrict__ h, float* __restrict__ out) {
  int wid = (blockIdx.x * blockDim.x + threadIdx.x) >> 6;
  int lane = threadIdx.x & 63;
  if (wid >= N_GRAPHS) return;
  int c = lane * 2;
  float m0 = -1e30f, m1 = -1e30f;
  for (int i = 0; i < NPG; i++) {
    const float2 v = *(const float2*)(h + ((size_t)(wid * NPG + i)) * 128 + c);
    m0 = fmaxf(m0, v.x);
    m1 = fmaxf(m1, v.y);
  }
  float2 o; o.x = m0; o.y = m1;
  *(float2*)(out + (size_t)wid * 128 + c) = o;
}

extern "C" void kernel_launch(void* const* d_in, const int* in_sizes, int n_in,
                              void* d_out, int out_size, void* d_ws, size_t ws_size,
                              hipStream_t stream) {
  (void)in_sizes; (void)n_in; (void)out_size; (void)ws_size;
  const float* x        = (const float*)d_in[0];
  const int*   eindex   = (const int*)d_in[1];
  const float* eattr    = (const float*)d_in[2];
  const float* atom_emb = (const float*)d_in[4];
  const float* bond_emb = (const float*)d_in[5];
  const float* bool_emb = (const float*)d_in[6];
  const float* Wn   = (const float*)d_in[7];
  const float* bn   = (const float*)d_in[8];
  const float* We   = (const float*)d_in[9];
  const float* be   = (const float*)d_in[10];
  const float* Wl1  = (const float*)d_in[11];
  const float* bl1  = (const float*)d_in[12];
  const float* Wr1  = (const float*)d_in[13];
  const float* br1  = (const float*)d_in[14];
  const float* Wedge1 = (const float*)d_in[15];
  const float* att1 = (const float*)d_in[16];
  const float* bias1 = (const float*)d_in[17];
  const float* Wl2  = (const float*)d_in[18];
  const float* bl2  = (const float*)d_in[19];
  const float* Wr2  = (const float*)d_in[20];
  const float* br2  = (const float*)d_in[21];
  const float* Wedge2 = (const float*)d_in[22];
  const float* att2 = (const float*)d_in[23];
  const float* bias2 = (const float*)d_in[24];

  const int* srcA = eindex;
  const int* dstA = eindex + N_EDGES;

  char* p = (char*)d_ws;
  auto alloc = [&](size_t bytes) {
    char* r = p;
    p += (bytes + 255) & ~(size_t)255;
    return r;
  };
  float* h0     = (float*)alloc((size_t)N_NODES * 64 * 4);
  float* h      = (float*)alloc((size_t)N_NODES * 128 * 4);
  float* xl     = (float*)alloc((size_t)N_NODES * 128 * 4);
  float* xrb    = (float*)alloc((size_t)N_NODES * 128 * 4);
  float* efull  = (float*)alloc((size_t)(N_EDGES + N_NODES) * 16 * 4);
  int*   cnt    = (int*)alloc((size_t)N_NODES * 4);
  int*   indptr = (int*)alloc((size_t)(N_NODES + 1) * 4);
  int*   cursor = (int*)alloc((size_t)N_NODES * 4);
  int*   eord   = (int*)alloc((size_t)(N_EDGES + N_NODES) * 4);

  hipMemsetAsync(cnt, 0, (size_t)N_NODES * 4, stream);

  k_encode_nodes<<<(N_NODES + 255) / 256, 256, 0, stream>>>(x, atom_emb, bool_emb, Wn, bn, h0);
  k_encode_edges<<<(N_EDGES + 255) / 256, 256, 0, stream>>>(eattr, dstA, bond_emb, bool_emb, We, be, efull, cnt);
  k_scan<<<1, 1024, 0, stream>>>(cnt, indptr, cursor);
  k_fill<<<(N_EDGES + N_NODES + 255) / 256, 256, 0, stream>>>(dstA, cursor, eord);
  k_loop_attr<<<(N_NODES + 255) / 256, 256, 0, stream>>>(indptr, eord, efull);

  const int GB = (N_NODES + 63) / 64;  // 1563 blocks

  // layer 1 (K=52, A stride 64 zero-padded)
  k_gemm<64, 52><<<GB, 256, 0, stream>>>(h0, Wl1, bl1, xl);
  k_gemm<64, 52><<<GB, 256, 0, stream>>>(h0, Wr1, br1, xrb);
  k_gat<<<2048, 256, 0, stream>>>(xl, xrb, efull, srcA, indptr, eord, Wedge1, att1, bias1, h);

  // layer 2 (K=128)
  k_gemm<128, 128><<<GB, 256, 0, stream>>>(h, Wl2, bl2, xl);
  k_gemm<128, 128><<<GB, 256, 0, stream>>>(h, Wr2, br2, xrb);
  k_gat<<<2048, 256, 0, stream>>>(xl, xrb, efull, srcA, indptr, eord, Wedge2, att2, bias2, h);

  // layer 3 (shared weights with layer 2)
  k_gemm<128, 128><<<GB, 256, 0, stream>>>(h, Wl2, bl2, xl);
  k_gemm<128, 128><<<GB, 256, 0, stream>>>(h, Wr2, br2, xrb);
  k_gat<<<2048, 256, 0, stream>>>(xl, xrb, efull, srcA, indptr, eord, Wedge2, att2, bias2, h);

  k_readout<<<(N_GRAPHS * 64 + 255) / 256, 256, 0, stream>>>(h, (float*)d_out);
}

// Round 3
// 1023.372 us; speedup vs baseline: 3.2978x; 3.2978x over previous
//
#include <hip/hip_runtime.h>

#define N_NODES 100000
#define N_EDGES 400000
#define N_GRAPHS 5000
#define NPG 20

// ---------------- node encoder: h0[N,64] (cols 52..63 zero) ----------------
__global__ void k_encode_nodes(const float* __restrict__ x,
                               const float* __restrict__ atom_emb,
                               const float* __restrict__ bool_emb,
                               const float* __restrict__ Wn,
                               const float* __restrict__ bn,
                               float* __restrict__ h0) {
  int n = blockIdx.x * blockDim.x + threadIdx.x;
  if (n >= N_NODES) return;
  const float* xr = x + (size_t)n * 14;
  float* h = h0 + (size_t)n * 64;
  int ai = (int)xr[0];
  #pragma unroll
  for (int j = 0; j < 16; j++) h[j] = atom_emb[ai * 16 + j];
  float xc[10];
  #pragma unroll
  for (int k = 0; k < 10; k++) xc[k] = xr[1 + k];
  #pragma unroll
  for (int c = 0; c < 30; c++) {
    float s = bn[c];
    #pragma unroll
    for (int k = 0; k < 10; k++) s += xc[k] * Wn[k * 30 + c];
    h[16 + c] = s;
  }
  #pragma unroll
  for (int t = 0; t < 3; t++) {
    int b = (int)xr[11 + t];
    h[46 + 2 * t]     = bool_emb[2 * b];
    h[46 + 2 * t + 1] = bool_emb[2 * b + 1];
  }
  #pragma unroll
  for (int j = 52; j < 64; j++) h[j] = 0.0f;  // zero pad for K=64 GEMM
}

// ---------------- edge encoder (no float atomics) + int degree histogram ----
__global__ void k_encode_edges(const float* __restrict__ eattr,
                               const int* __restrict__ dst,
                               const float* __restrict__ bond_emb,
                               const float* __restrict__ bool_emb,
                               const float* __restrict__ We,
                               const float* __restrict__ be,
                               float* __restrict__ e_full,
                               int* __restrict__ cnt) {
  int e = blockIdx.x * blockDim.x + threadIdx.x;
  if (e >= N_EDGES) return;
  const float* r = eattr + (size_t)e * 5;
  float row[16];
  int bi = (int)r[0];
  #pragma unroll
  for (int j = 0; j < 8; j++) row[j] = bond_emb[bi * 8 + j];
  float ec = r[1];
  row[8] = ec * We[0] + be[0];
  row[9] = ec * We[1] + be[1];
  #pragma unroll
  for (int t = 0; t < 3; t++) {
    int b = (int)r[2 + t];
    row[10 + 2 * t]     = bool_emb[2 * b];
    row[10 + 2 * t + 1] = bool_emb[2 * b + 1];
  }
  float4* out = (float4*)(e_full + (size_t)e * 16);
  out[0] = make_float4(row[0], row[1], row[2], row[3]);
  out[1] = make_float4(row[4], row[5], row[6], row[7]);
  out[2] = make_float4(row[8], row[9], row[10], row[11]);
  out[3] = make_float4(row[12], row[13], row[14], row[15]);
  atomicAdd(cnt + dst[e], 1);
}

// ---------------- single-block exclusive scan over (cnt[n]+1) ----------------
__global__ __launch_bounds__(1024) void k_scan(const int* __restrict__ cnt,
                                               int* __restrict__ indptr,
                                               int* __restrict__ cursor) {
  __shared__ int sums[1024];
  int t = threadIdx.x;
  const int per = (N_NODES + 1023) / 1024;
  int beg = t * per;
  int end = beg + per; if (end > N_NODES) end = N_NODES;
  int s = 0;
  for (int i = beg; i < end; i++) s += cnt[i] + 1;
  sums[t] = s;
  __syncthreads();
  for (int off = 1; off < 1024; off <<= 1) {
    int v = (t >= off) ? sums[t - off] : 0;
    __syncthreads();
    sums[t] += v;
    __syncthreads();
  }
  int run = (t > 0) ? sums[t - 1] : 0;
  for (int i = beg; i < end; i++) {
    indptr[i] = run;
    cursor[i] = run;
    run += cnt[i] + 1;
  }
  if (t == 1023) indptr[N_NODES] = sums[1023];
}

// ---------------- CSR fill (edges then self-loops) ----------------
__global__ void k_fill(const int* __restrict__ dst,
                       int* __restrict__ cursor,
                       int* __restrict__ eord) {
  int i = blockIdx.x * blockDim.x + threadIdx.x;
  if (i >= N_EDGES + N_NODES) return;
  int d = (i < N_EDGES) ? dst[i] : (i - N_EDGES);
  int p = atomicAdd(&cursor[d], 1);
  eord[p] = i;
}

// ---------------- loop_attr[n] = mean of in-edge attrs (CSR pass) -----------
__global__ void k_loop_attr(const int* __restrict__ indptr,
                            const int* __restrict__ eord,
                            float* __restrict__ e_full) {
  int n = blockIdx.x * blockDim.x + threadIdx.x;
  if (n >= N_NODES) return;
  int beg = indptr[n], end = indptr[n + 1];
  float4 s0 = make_float4(0, 0, 0, 0), s1 = s0, s2 = s0, s3 = s0;
  int c = 0;
  for (int j = beg; j < end; j++) {
    int eid = eord[j];
    if (eid >= N_EDGES) continue;
    const float4* ep = (const float4*)(e_full + (size_t)eid * 16);
    float4 a = ep[0], b = ep[1], cc = ep[2], d = ep[3];
    s0.x += a.x; s0.y += a.y; s0.z += a.z; s0.w += a.w;
    s1.x += b.x; s1.y += b.y; s1.z += b.z; s1.w += b.w;
    s2.x += cc.x; s2.y += cc.y; s2.z += cc.z; s2.w += cc.w;
    s3.x += d.x; s3.y += d.y; s3.z += d.z; s3.w += d.w;
    c++;
  }
  float inv = 1.0f / (float)(c > 0 ? c : 1);
  s0.x *= inv; s0.y *= inv; s0.z *= inv; s0.w *= inv;
  s1.x *= inv; s1.y *= inv; s1.z *= inv; s1.w *= inv;
  s2.x *= inv; s2.y *= inv; s2.z *= inv; s2.w *= inv;
  s3.x *= inv; s3.y *= inv; s3.z *= inv; s3.w *= inv;
  float4* lp = (float4*)(e_full + (size_t)(N_EDGES + n) * 16);
  lp[0] = s0; lp[1] = s1; lp[2] = s2; lp[3] = s3;
}

// ---------------- tiled GEMM: out[N,128] = A[N,KPAD(:K)] @ W[K,128] + b -----
// Block: 256 threads, tile 64 rows x 128 cols, TK=32.
// Thread (tx=tid&15, ty=tid>>4): rows ty*4..+3, cols {tx*4..+3, 64+tx*4..+3}.
// (column split at +64 keeps Ws LDS reads at 2-way aliasing = free on gfx950)
template <int KPAD, int K>
__global__ __launch_bounds__(256, 4) void k_gemm(const float* __restrict__ A,
                                                 const float* __restrict__ W,
                                                 const float* __restrict__ b,
                                                 float* __restrict__ out) {
  __shared__ float As[32][68];    // As[k][row] transposed, pad 68
  __shared__ float Ws[32 * 128];  // Ws[k][col]
  const int tid = threadIdx.x;
  const int tx = tid & 15, ty = tid >> 4;
  const int lane = tid & 63, wv = tid >> 6;
  const int m0 = blockIdx.x * 64;
  const int r0 = ty * 4, c0 = tx * 4;

  float acc[4][8];
  #pragma unroll
  for (int i = 0; i < 4; i++)
    #pragma unroll
    for (int j = 0; j < 8; j++) acc[i][j] = 0.0f;

  const int arow = (m0 + lane < N_NODES) ? m0 + lane : N_NODES - 1;

  for (int kk0 = 0; kk0 < KPAD; kk0 += 32) {
    // stage A tile transposed: wave wv loads ks [wv*8, wv*8+8) of row `lane`
    {
      const float* ap = A + (size_t)arow * KPAD + kk0 + wv * 8;
      float4 v0 = ((const float4*)ap)[0];
      float4 v1 = ((const float4*)ap)[1];
      int kb = wv * 8;
      As[kb + 0][lane] = v0.x; As[kb + 1][lane] = v0.y;
      As[kb + 2][lane] = v0.z; As[kb + 3][lane] = v0.w;
      As[kb + 4][lane] = v1.x; As[kb + 5][lane] = v1.y;
      As[kb + 6][lane] = v1.z; As[kb + 7][lane] = v1.w;
    }
    // stage W tile: 32x128 floats = 1024 float4 / 256 threads = 4 each
    #pragma unroll
    for (int i = 0; i < 4; i++) {
      int idx = tid + i * 256;        // float4 index
      int row = idx >> 5, col4 = idx & 31;
      int wrow = kk0 + row; if (wrow >= K) wrow = K - 1;  // A is zero there
      float4 v = *(const float4*)(W + (size_t)wrow * 128 + col4 * 4);
      *(float4*)(Ws + row * 128 + col4 * 4) = v;
    }
    __syncthreads();
    #pragma unroll 4
    for (int kk = 0; kk < 32; kk++) {
      float4 av = *(const float4*)&As[kk][r0];
      float4 w0 = *(const float4*)(Ws + kk * 128 + c0);
      float4 w1 = *(const float4*)(Ws + kk * 128 + c0 + 64);
      float a[4] = {av.x, av.y, av.z, av.w};
      float w[8] = {w0.x, w0.y, w0.z, w0.w, w1.x, w1.y, w1.z, w1.w};
      #pragma unroll
      for (int i = 0; i < 4; i++)
        #pragma unroll
        for (int j = 0; j < 8; j++) acc[i][j] += a[i] * w[j];
    }
    __syncthreads();
  }
  float bl[8];
  #pragma unroll
  for (int j = 0; j < 4; j++) { bl[j] = b[c0 + j]; bl[4 + j] = b[c0 + 64 + j]; }
  #pragma unroll
  for (int i = 0; i < 4; i++) {
    int n = m0 + r0 + i;
    if (n >= N_NODES) break;
    float4 o0 = make_float4(acc[i][0] + bl[0], acc[i][1] + bl[1], acc[i][2] + bl[2], acc[i][3] + bl[3]);
    float4 o1 = make_float4(acc[i][4] + bl[4], acc[i][5] + bl[5], acc[i][6] + bl[6], acc[i][7] + bl[7]);
    *(float4*)(out + (size_t)n * 128 + c0) = o0;
    *(float4*)(out + (size_t)n * 128 + c0 + 64) = o1;
  }
}

// ---------------- GATv2 edge pass: one wave per dst node, online softmax ----
__global__ __launch_bounds__(256) void k_gat(const float* __restrict__ xl,
                                             const float* __restrict__ xr,
                                             const float* __restrict__ e_full,
                                             const int* __restrict__ srcA,
                                             const int* __restrict__ indptr,
                                             const int* __restrict__ eord,
                                             const float* __restrict__ Wedge,
                                             const float* __restrict__ att,
                                             const float* __restrict__ bias,
                                             float* __restrict__ hout) {
  int wid = (blockIdx.x * 256 + threadIdx.x) >> 6;
  int nw = (gridDim.x * 256) >> 6;
  int lane = threadIdx.x & 63;
  int c = lane * 2;
  float wreg[32];
  #pragma unroll
  for (int k = 0; k < 16; k++) {
    wreg[2 * k]     = Wedge[k * 128 + c];
    wreg[2 * k + 1] = Wedge[k * 128 + c + 1];
  }
  float att0 = att[c], att1 = att[c + 1];
  float b0 = bias[c], b1 = bias[c + 1];
  wid = __builtin_amdgcn_readfirstlane(wid);
  for (int n = wid; n < N_NODES; n += nw) {
    int beg = indptr[n], end = indptr[n + 1];
    float2 xrv = *(const float2*)(xr + (size_t)n * 128 + c);
    float amax = -1e30f, denom = 0.f, acc0 = 0.f, acc1 = 0.f;
    for (int j = beg; j < end; j++) {
      int eid = eord[j];
      int s = (eid < N_EDGES) ? srcA[eid] : n;
      const float4* ep = (const float4*)(e_full + (size_t)eid * 16);
      float4 q0 = ep[0], q1 = ep[1], q2 = ep[2], q3 = ep[3];
      float2 xlv = *(const float2*)(xl + (size_t)s * 128 + c);
      float ev[16] = {q0.x, q0.y, q0.z, q0.w, q1.x, q1.y, q1.z, q1.w,
                      q2.x, q2.y, q2.z, q2.w, q3.x, q3.y, q3.z, q3.w};
      float el0 = 0.f, el1 = 0.f;
      #pragma unroll
      for (int k = 0; k < 16; k++) {
        el0 += ev[k] * wreg[2 * k];
        el1 += ev[k] * wreg[2 * k + 1];
      }
      float m0 = xlv.x + xrv.x + el0;
      float m1 = xlv.y + xrv.y + el1;
      float l0 = m0 > 0.f ? m0 : 0.2f * m0;
      float l1 = m1 > 0.f ? m1 : 0.2f * m1;
      float t = l0 * att0 + l1 * att1;
      #pragma unroll
      for (int off = 1; off < 64; off <<= 1) t += __shfl_xor(t, off, 64);
      // online softmax update (t is wave-uniform after reduction)
      if (t > amax) {
        float sc = __expf(amax - t);
        denom *= sc; acc0 *= sc; acc1 *= sc;
        amax = t;
      }
      float ex = __expf(t - amax);
      denom += ex;
      acc0 += ex * xlv.x;
      acc1 += ex * xlv.y;
    }
    float inv = 1.0f / denom;
    float o0 = acc0 * inv + b0;
    float o1 = acc1 * inv + b1;
    float2 o; o.x = o0 > 0.f ? o0 : 0.f; o.y = o1 > 0.f ? o1 : 0.f;
    *(float2*)(hout + (size_t)n * 128 + c) = o;
  }
}

// ---------------- readout: global max pool over 20 contiguous nodes --------
__global__ void k_readout(const float* __restrict__ h, float* __restrict__ out) {
  int wid = (blockIdx.x * blockDim.x + threadIdx.x) >> 6;
  int lane = threadIdx.x & 63;
  if (wid >= N_GRAPHS) return;
  int c = lane * 2;
  float m0 = -1e30f, m1 = -1e30f;
  for (int i = 0; i < NPG; i++) {
    const float2 v = *(const float2*)(h + ((size_t)(wid * NPG + i)) * 128 + c);
    m0 = fmaxf(m0, v.x);
    m1 = fmaxf(m1, v.y);
  }
  float2 o; o.x = m0; o.y = m1;
  *(float2*)(out + (size_t)wid * 128 + c) = o;
}

extern "C" void kernel_launch(void* const* d_in, const int* in_sizes, int n_in,
                              void* d_out, int out_size, void* d_ws, size_t ws_size,
                              hipStream_t stream) {
  (void)in_sizes; (void)n_in; (void)out_size; (void)ws_size;
  const float* x        = (const float*)d_in[0];
  const int*   eindex   = (const int*)d_in[1];
  const float* eattr    = (const float*)d_in[2];
  const float* atom_emb = (const float*)d_in[4];
  const float* bond_emb = (const float*)d_in[5];
  const float* bool_emb = (const float*)d_in[6];
  const float* Wn   = (const float*)d_in[7];
  const float* bn   = (const float*)d_in[8];
  const float* We   = (const float*)d_in[9];
  const float* be   = (const float*)d_in[10];
  const float* Wl1  = (const float*)d_in[11];
  const float* bl1  = (const float*)d_in[12];
  const float* Wr1  = (const float*)d_in[13];
  const float* br1  = (const float*)d_in[14];
  const float* Wedge1 = (const float*)d_in[15];
  const float* att1 = (const float*)d_in[16];
  const float* bias1 = (const float*)d_in[17];
  const float* Wl2  = (const float*)d_in[18];
  const float* bl2  = (const float*)d_in[19];
  const float* Wr2  = (const float*)d_in[20];
  const float* br2  = (const float*)d_in[21];
  const float* Wedge2 = (const float*)d_in[22];
  const float* att2 = (const float*)d_in[23];
  const float* bias2 = (const float*)d_in[24];

  const int* srcA = eindex;
  const int* dstA = eindex + N_EDGES;

  char* p = (char*)d_ws;
  auto alloc = [&](size_t bytes) {
    char* r = p;
    p += (bytes + 255) & ~(size_t)255;
    return r;
  };
  float* h0     = (float*)alloc((size_t)N_NODES * 64 * 4);
  float* h      = (float*)alloc((size_t)N_NODES * 128 * 4);
  float* xl     = (float*)alloc((size_t)N_NODES * 128 * 4);
  float* xrb    = (float*)alloc((size_t)N_NODES * 128 * 4);
  float* efull  = (float*)alloc((size_t)(N_EDGES + N_NODES) * 16 * 4);
  int*   cnt    = (int*)alloc((size_t)N_NODES * 4);
  int*   indptr = (int*)alloc((size_t)(N_NODES + 1) * 4);
  int*   cursor = (int*)alloc((size_t)N_NODES * 4);
  int*   eord   = (int*)alloc((size_t)(N_EDGES + N_NODES) * 4);

  hipMemsetAsync(cnt, 0, (size_t)N_NODES * 4, stream);

  k_encode_nodes<<<(N_NODES + 255) / 256, 256, 0, stream>>>(x, atom_emb, bool_emb, Wn, bn, h0);
  k_encode_edges<<<(N_EDGES + 255) / 256, 256, 0, stream>>>(eattr, dstA, bond_emb, bool_emb, We, be, efull, cnt);
  k_scan<<<1, 1024, 0, stream>>>(cnt, indptr, cursor);
  k_fill<<<(N_EDGES + N_NODES + 255) / 256, 256, 0, stream>>>(dstA, cursor, eord);
  k_loop_attr<<<(N_NODES + 255) / 256, 256, 0, stream>>>(indptr, eord, efull);

  const int GB = (N_NODES + 63) / 64;  // 1563 blocks

  // layer 1 (K=52, A stride 64 zero-padded)
  k_gemm<64, 52><<<GB, 256, 0, stream>>>(h0, Wl1, bl1, xl);
  k_gemm<64, 52><<<GB, 256, 0, stream>>>(h0, Wr1, br1, xrb);
  k_gat<<<2048, 256, 0, stream>>>(xl, xrb, efull, srcA, indptr, eord, Wedge1, att1, bias1, h);

  // layer 2 (K=128)
  k_gemm<128, 128><<<GB, 256, 0, stream>>>(h, Wl2, bl2, xl);
  k_gemm<128, 128><<<GB, 256, 0, stream>>>(h, Wr2, br2, xrb);
  k_gat<<<2048, 256, 0, stream>>>(xl, xrb, efull, srcA, indptr, eord, Wedge2, att2, bias2, h);

  // layer 3 (shared weights with layer 2)
  k_gemm<128, 128><<<GB, 256, 0, stream>>>(h, Wl2, bl2, xl);
  k_gemm<128, 128><<<GB, 256, 0, stream>>>(h, Wr2, br2, xrb);
  k_gat<<<2048, 256, 0, stream>>>(xl, xrb, efull, srcA, indptr, eord, Wedge2, att2, bias2, h);

  k_readout<<<(N_GRAPHS * 64 + 255) / 256, 256, 0, stream>>>(h, (float*)d_out);
}

// Round 4
// 798.015 us; speedup vs baseline: 4.2291x; 1.2824x over previous
//
#include <hip/hip_runtime.h>

#define N_NODES 100000
#define N_EDGES 400000
#define N_GRAPHS 5000
#define NPG 20
#define SCAN_NB 256
#define SCAN_CHUNK ((N_NODES + SCAN_NB - 1) / SCAN_NB)  // 391

// ---------------- node encoder: h0[N,64] (cols 52..63 zero) ----------------
__global__ void k_encode_nodes(const float* __restrict__ x,
                               const float* __restrict__ atom_emb,
                               const float* __restrict__ bool_emb,
                               const float* __restrict__ Wn,
                               const float* __restrict__ bn,
                               float* __restrict__ h0) {
  int n = blockIdx.x * blockDim.x + threadIdx.x;
  if (n >= N_NODES) return;
  const float* xr = x + (size_t)n * 14;
  float* h = h0 + (size_t)n * 64;
  int ai = (int)xr[0];
  #pragma unroll
  for (int j = 0; j < 16; j++) h[j] = atom_emb[ai * 16 + j];
  float xc[10];
  #pragma unroll
  for (int k = 0; k < 10; k++) xc[k] = xr[1 + k];
  #pragma unroll
  for (int c = 0; c < 30; c++) {
    float s = bn[c];
    #pragma unroll
    for (int k = 0; k < 10; k++) s += xc[k] * Wn[k * 30 + c];
    h[16 + c] = s;
  }
  #pragma unroll
  for (int t = 0; t < 3; t++) {
    int b = (int)xr[11 + t];
    h[46 + 2 * t]     = bool_emb[2 * b];
    h[46 + 2 * t + 1] = bool_emb[2 * b + 1];
  }
  #pragma unroll
  for (int j = 52; j < 64; j++) h[j] = 0.0f;  // zero pad for K=64 GEMM
}

// ---------------- edge encoder (no float atomics) + int degree histogram ----
__global__ void k_encode_edges(const float* __restrict__ eattr,
                               const int* __restrict__ dst,
                               const float* __restrict__ bond_emb,
                               const float* __restrict__ bool_emb,
                               const float* __restrict__ We,
                               const float* __restrict__ be,
                               float* __restrict__ e_full,
                               int* __restrict__ cnt) {
  int e = blockIdx.x * blockDim.x + threadIdx.x;
  if (e >= N_EDGES) return;
  const float* r = eattr + (size_t)e * 5;
  float row[16];
  int bi = (int)r[0];
  #pragma unroll
  for (int j = 0; j < 8; j++) row[j] = bond_emb[bi * 8 + j];
  float ec = r[1];
  row[8] = ec * We[0] + be[0];
  row[9] = ec * We[1] + be[1];
  #pragma unroll
  for (int t = 0; t < 3; t++) {
    int b = (int)r[2 + t];
    row[10 + 2 * t]     = bool_emb[2 * b];
    row[10 + 2 * t + 1] = bool_emb[2 * b + 1];
  }
  float4* out = (float4*)(e_full + (size_t)e * 16);
  out[0] = make_float4(row[0], row[1], row[2], row[3]);
  out[1] = make_float4(row[4], row[5], row[6], row[7]);
  out[2] = make_float4(row[8], row[9], row[10], row[11]);
  out[3] = make_float4(row[12], row[13], row[14], row[15]);
  atomicAdd(cnt + dst[e], 1);
}

// ---------------- hierarchical scan over (cnt[n]+1), 3 phases ---------------
__global__ __launch_bounds__(256) void k_scan1(const int* __restrict__ cnt,
                                               int* __restrict__ bsum) {
  __shared__ int red[256];
  int b = blockIdx.x, t = threadIdx.x;
  int beg = b * SCAN_CHUNK;
  int end = beg + SCAN_CHUNK; if (end > N_NODES) end = N_NODES;
  int s = 0;
  for (int i = beg + t; i < end; i += 256) s += cnt[i] + 1;  // coalesced
  red[t] = s;
  __syncthreads();
  for (int off = 128; off > 0; off >>= 1) {
    if (t < off) red[t] += red[t + off];
    __syncthreads();
  }
  if (t == 0) bsum[b] = red[0];
}

__global__ __launch_bounds__(256) void k_scan2(int* __restrict__ bsum) {
  __shared__ int sh[256];
  int t = threadIdx.x;
  sh[t] = bsum[t];
  __syncthreads();
  for (int off = 1; off < 256; off <<= 1) {
    int v = (t >= off) ? sh[t - off] : 0;
    __syncthreads();
    sh[t] += v;
    __syncthreads();
  }
  bsum[t] = (t > 0) ? sh[t - 1] : 0;  // exclusive
}

__global__ __launch_bounds__(256) void k_scan3(const int* __restrict__ cnt,
                                               const int* __restrict__ bsum,
                                               int* __restrict__ indptr,
                                               int* __restrict__ cursor) {
  __shared__ int sh[256];
  __shared__ int carry;
  int b = blockIdx.x, t = threadIdx.x;
  int beg = b * SCAN_CHUNK;
  int end = beg + SCAN_CHUNK; if (end > N_NODES) end = N_NODES;
  if (t == 0) carry = bsum[b];
  __syncthreads();
  for (int base = beg; base < end; base += 256) {
    int i = base + t;
    int v = (i < end) ? cnt[i] + 1 : 0;
    sh[t] = v;
    __syncthreads();
    for (int off = 1; off < 256; off <<= 1) {
      int u = (t >= off) ? sh[t - off] : 0;
      __syncthreads();
      sh[t] += u;
      __syncthreads();
    }
    int excl = sh[t] - v;
    if (i < end) {
      int val = carry + excl;
      indptr[i] = val;
      cursor[i] = val;
    }
    __syncthreads();
    if (t == 255) carry += sh[255];
    __syncthreads();
  }
  if (b == 0 && t == 0) indptr[N_NODES] = N_EDGES + N_NODES;  // total is constant
}

// ---------------- CSR fill (edges then self-loops) ----------------
__global__ void k_fill(const int* __restrict__ dst,
                       int* __restrict__ cursor,
                       int* __restrict__ eord) {
  int i = blockIdx.x * blockDim.x + threadIdx.x;
  if (i >= N_EDGES + N_NODES) return;
  int d = (i < N_EDGES) ? dst[i] : (i - N_EDGES);
  int p = atomicAdd(&cursor[d], 1);
  eord[p] = i;
}

// ---------------- loop_attr[n] = mean of in-edge attrs (CSR pass) -----------
__global__ void k_loop_attr(const int* __restrict__ indptr,
                            const int* __restrict__ eord,
                            float* __restrict__ e_full) {
  int n = blockIdx.x * blockDim.x + threadIdx.x;
  if (n >= N_NODES) return;
  int beg = indptr[n], end = indptr[n + 1];
  float4 s0 = make_float4(0, 0, 0, 0), s1 = s0, s2 = s0, s3 = s0;
  int c = 0;
  for (int j = beg; j < end; j++) {
    int eid = eord[j];
    if (eid >= N_EDGES) continue;
    const float4* ep = (const float4*)(e_full + (size_t)eid * 16);
    float4 a = ep[0], b = ep[1], cc = ep[2], d = ep[3];
    s0.x += a.x; s0.y += a.y; s0.z += a.z; s0.w += a.w;
    s1.x += b.x; s1.y += b.y; s1.z += b.z; s1.w += b.w;
    s2.x += cc.x; s2.y += cc.y; s2.z += cc.z; s2.w += cc.w;
    s3.x += d.x; s3.y += d.y; s3.z += d.z; s3.w += d.w;
    c++;
  }
  float inv = 1.0f / (float)(c > 0 ? c : 1);
  s0.x *= inv; s0.y *= inv; s0.z *= inv; s0.w *= inv;
  s1.x *= inv; s1.y *= inv; s1.z *= inv; s1.w *= inv;
  s2.x *= inv; s2.y *= inv; s2.z *= inv; s2.w *= inv;
  s3.x *= inv; s3.y *= inv; s3.z *= inv; s3.w *= inv;
  float4* lp = (float4*)(e_full + (size_t)(N_EDGES + n) * 16);
  lp[0] = s0; lp[1] = s1; lp[2] = s2; lp[3] = s3;
}

// ---------------- fused dual GEMM: xl/xr = A @ {Wl,Wr} + {bl,br} ------------
// Block: 256 threads, tile 64 rows x 128 cols, TK=32, A staged once for both.
// Thread (tx=tid&15, ty=tid>>4): rows ty*4..+3, cols {tx*4..+3, 64+tx*4..+3}.
template <int KPAD, int K>
__global__ __launch_bounds__(256, 3) void k_gemm2(const float* __restrict__ A,
                                                  const float* __restrict__ Wl,
                                                  const float* __restrict__ bl_,
                                                  const float* __restrict__ Wr,
                                                  const float* __restrict__ br_,
                                                  float* __restrict__ outl,
                                                  float* __restrict__ outr) {
  __shared__ float As[32][68];     // As[k][row] transposed, pad 68
  __shared__ float Ws[2][32 * 128];
  const int tid = threadIdx.x;
  const int tx = tid & 15, ty = tid >> 4;
  const int lane = tid & 63, wv = tid >> 6;
  const int m0 = blockIdx.x * 64;
  const int r0 = ty * 4, c0 = tx * 4;

  float accL[4][8], accR[4][8];
  #pragma unroll
  for (int i = 0; i < 4; i++)
    #pragma unroll
    for (int j = 0; j < 8; j++) { accL[i][j] = 0.0f; accR[i][j] = 0.0f; }

  const int arow = (m0 + lane < N_NODES) ? m0 + lane : N_NODES - 1;

  for (int kk0 = 0; kk0 < KPAD; kk0 += 32) {
    // stage A tile transposed: wave wv loads ks [wv*8, wv*8+8) of row `lane`
    {
      const float* ap = A + (size_t)arow * KPAD + kk0 + wv * 8;
      float4 v0 = ((const float4*)ap)[0];
      float4 v1 = ((const float4*)ap)[1];
      int kb = wv * 8;
      As[kb + 0][lane] = v0.x; As[kb + 1][lane] = v0.y;
      As[kb + 2][lane] = v0.z; As[kb + 3][lane] = v0.w;
      As[kb + 4][lane] = v1.x; As[kb + 5][lane] = v1.y;
      As[kb + 6][lane] = v1.z; As[kb + 7][lane] = v1.w;
    }
    // stage both W tiles: 2 x 1024 float4 / 256 threads = 4 each per W
    #pragma unroll
    for (int i = 0; i < 4; i++) {
      int idx = tid + i * 256;
      int row = idx >> 5, col4 = idx & 31;
      int wrow = kk0 + row; if (wrow >= K) wrow = K - 1;  // A is zero there
      *(float4*)(Ws[0] + row * 128 + col4 * 4) = *(const float4*)(Wl + (size_t)wrow * 128 + col4 * 4);
      *(float4*)(Ws[1] + row * 128 + col4 * 4) = *(const float4*)(Wr + (size_t)wrow * 128 + col4 * 4);
    }
    __syncthreads();
    #pragma unroll 2
    for (int kk = 0; kk < 32; kk++) {
      float4 av = *(const float4*)&As[kk][r0];
      float a[4] = {av.x, av.y, av.z, av.w};
      float4 l0 = *(const float4*)(Ws[0] + kk * 128 + c0);
      float4 l1 = *(const float4*)(Ws[0] + kk * 128 + c0 + 64);
      float4 rr0 = *(const float4*)(Ws[1] + kk * 128 + c0);
      float4 rr1 = *(const float4*)(Ws[1] + kk * 128 + c0 + 64);
      float wL[8] = {l0.x, l0.y, l0.z, l0.w, l1.x, l1.y, l1.z, l1.w};
      float wR[8] = {rr0.x, rr0.y, rr0.z, rr0.w, rr1.x, rr1.y, rr1.z, rr1.w};
      #pragma unroll
      for (int i = 0; i < 4; i++)
        #pragma unroll
        for (int j = 0; j < 8; j++) {
          accL[i][j] += a[i] * wL[j];
          accR[i][j] += a[i] * wR[j];
        }
    }
    __syncthreads();
  }
  float blv[8], brv[8];
  #pragma unroll
  for (int j = 0; j < 4; j++) {
    blv[j] = bl_[c0 + j]; blv[4 + j] = bl_[c0 + 64 + j];
    brv[j] = br_[c0 + j]; brv[4 + j] = br_[c0 + 64 + j];
  }
  #pragma unroll
  for (int i = 0; i < 4; i++) {
    int n = m0 + r0 + i;
    if (n >= N_NODES) break;
    *(float4*)(outl + (size_t)n * 128 + c0) =
        make_float4(accL[i][0] + blv[0], accL[i][1] + blv[1], accL[i][2] + blv[2], accL[i][3] + blv[3]);
    *(float4*)(outl + (size_t)n * 128 + c0 + 64) =
        make_float4(accL[i][4] + blv[4], accL[i][5] + blv[5], accL[i][6] + blv[6], accL[i][7] + blv[7]);
    *(float4*)(outr + (size_t)n * 128 + c0) =
        make_float4(accR[i][0] + brv[0], accR[i][1] + brv[1], accR[i][2] + brv[2], accR[i][3] + brv[3]);
    *(float4*)(outr + (size_t)n * 128 + c0 + 64) =
        make_float4(accR[i][4] + brv[4], accR[i][5] + brv[5], accR[i][6] + brv[6], accR[i][7] + brv[7]);
  }
}

// ---------------- GATv2 edge pass: one wave per dst node, online softmax ----
__global__ __launch_bounds__(256) void k_gat(const float* __restrict__ xl,
                                             const float* __restrict__ xr,
                                             const float* __restrict__ e_full,
                                             const int* __restrict__ srcA,
                                             const int* __restrict__ indptr,
                                             const int* __restrict__ eord,
                                             const float* __restrict__ Wedge,
                                             const float* __restrict__ att,
                                             const float* __restrict__ bias,
                                             float* __restrict__ hout) {
  int wid = (blockIdx.x * 256 + threadIdx.x) >> 6;
  int nw = (gridDim.x * 256) >> 6;
  int lane = threadIdx.x & 63;
  int c = lane * 2;
  float wreg[32];
  #pragma unroll
  for (int k = 0; k < 16; k++) {
    wreg[2 * k]     = Wedge[k * 128 + c];
    wreg[2 * k + 1] = Wedge[k * 128 + c + 1];
  }
  float att0 = att[c], att1 = att[c + 1];
  float b0 = bias[c], b1 = bias[c + 1];
  wid = __builtin_amdgcn_readfirstlane(wid);
  for (int n = wid; n < N_NODES; n += nw) {
    int beg = indptr[n], end = indptr[n + 1];
    float2 xrv = *(const float2*)(xr + (size_t)n * 128 + c);
    float amax = -1e30f, denom = 0.f, acc0 = 0.f, acc1 = 0.f;
    for (int j = beg; j < end; j++) {
      int eid = eord[j];
      int s = (eid < N_EDGES) ? srcA[eid] : n;
      const float4* ep = (const float4*)(e_full + (size_t)eid * 16);
      float4 q0 = ep[0], q1 = ep[1], q2 = ep[2], q3 = ep[3];
      float2 xlv = *(const float2*)(xl + (size_t)s * 128 + c);
      float ev[16] = {q0.x, q0.y, q0.z, q0.w, q1.x, q1.y, q1.z, q1.w,
                      q2.x, q2.y, q2.z, q2.w, q3.x, q3.y, q3.z, q3.w};
      float el0 = 0.f, el1 = 0.f;
      #pragma unroll
      for (int k = 0; k < 16; k++) {
        el0 += ev[k] * wreg[2 * k];
        el1 += ev[k] * wreg[2 * k + 1];
      }
      float m0 = xlv.x + xrv.x + el0;
      float m1 = xlv.y + xrv.y + el1;
      float l0 = m0 > 0.f ? m0 : 0.2f * m0;
      float l1 = m1 > 0.f ? m1 : 0.2f * m1;
      float t = l0 * att0 + l1 * att1;
      #pragma unroll
      for (int off = 1; off < 64; off <<= 1) t += __shfl_xor(t, off, 64);
      // online softmax update (t is wave-uniform after reduction)
      if (t > amax) {
        float sc = __expf(amax - t);
        denom *= sc; acc0 *= sc; acc1 *= sc;
        amax = t;
      }
      float ex = __expf(t - amax);
      denom += ex;
      acc0 += ex * xlv.x;
      acc1 += ex * xlv.y;
    }
    float inv = 1.0f / denom;
    float o0 = acc0 * inv + b0;
    float o1 = acc1 * inv + b1;
    float2 o; o.x = o0 > 0.f ? o0 : 0.f; o.y = o1 > 0.f ? o1 : 0.f;
    *(float2*)(hout + (size_t)n * 128 + c) = o;
  }
}

// ---------------- readout: global max pool over 20 contiguous nodes --------
__global__ void k_readout(const float* __restrict__ h, float* __restrict__ out) {
  int wid = (blockIdx.x * blockDim.x + threadIdx.x) >> 6;
  int lane = threadIdx.x & 63;
  if (wid >= N_GRAPHS) return;
  int c = lane * 2;
  float m0 = -1e30f, m1 = -1e30f;
  for (int i = 0; i < NPG; i++) {
    const float2 v = *(const float2*)(h + ((size_t)(wid * NPG + i)) * 128 + c);
    m0 = fmaxf(m0, v.x);
    m1 = fmaxf(m1, v.y);
  }
  float2 o; o.x = m0; o.y = m1;
  *(float2*)(out + (size_t)wid * 128 + c) = o;
}

extern "C" void kernel_launch(void* const* d_in, const int* in_sizes, int n_in,
                              void* d_out, int out_size, void* d_ws, size_t ws_size,
                              hipStream_t stream) {
  (void)in_sizes; (void)n_in; (void)out_size; (void)ws_size;
  const float* x        = (const float*)d_in[0];
  const int*   eindex   = (const int*)d_in[1];
  const float* eattr    = (const float*)d_in[2];
  const float* atom_emb = (const float*)d_in[4];
  const float* bond_emb = (const float*)d_in[5];
  const float* bool_emb = (const float*)d_in[6];
  const float* Wn   = (const float*)d_in[7];
  const float* bn   = (const float*)d_in[8];
  const float* We   = (const float*)d_in[9];
  const float* be   = (const float*)d_in[10];
  const float* Wl1  = (const float*)d_in[11];
  const float* bl1  = (const float*)d_in[12];
  const float* Wr1  = (const float*)d_in[13];
  const float* br1  = (const float*)d_in[14];
  const float* Wedge1 = (const float*)d_in[15];
  const float* att1 = (const float*)d_in[16];
  const float* bias1 = (const float*)d_in[17];
  const float* Wl2  = (const float*)d_in[18];
  const float* bl2  = (const float*)d_in[19];
  const float* Wr2  = (const float*)d_in[20];
  const float* br2  = (const float*)d_in[21];
  const float* Wedge2 = (const float*)d_in[22];
  const float* att2 = (const float*)d_in[23];
  const float* bias2 = (const float*)d_in[24];

  const int* srcA = eindex;
  const int* dstA = eindex + N_EDGES;

  char* p = (char*)d_ws;
  auto alloc = [&](size_t bytes) {
    char* r = p;
    p += (bytes + 255) & ~(size_t)255;
    return r;
  };
  float* h0     = (float*)alloc((size_t)N_NODES * 64 * 4);
  float* h      = (float*)alloc((size_t)N_NODES * 128 * 4);
  float* xl     = (float*)alloc((size_t)N_NODES * 128 * 4);
  float* xrb    = (float*)alloc((size_t)N_NODES * 128 * 4);
  float* efull  = (float*)alloc((size_t)(N_EDGES + N_NODES) * 16 * 4);
  int*   cnt    = (int*)alloc((size_t)N_NODES * 4);
  int*   indptr = (int*)alloc((size_t)(N_NODES + 1) * 4);
  int*   cursor = (int*)alloc((size_t)N_NODES * 4);
  int*   eord   = (int*)alloc((size_t)(N_EDGES + N_NODES) * 4);
  int*   bsum   = (int*)alloc((size_t)SCAN_NB * 4);

  hipMemsetAsync(cnt, 0, (size_t)N_NODES * 4, stream);

  k_encode_nodes<<<(N_NODES + 255) / 256, 256, 0, stream>>>(x, atom_emb, bool_emb, Wn, bn, h0);
  k_encode_edges<<<(N_EDGES + 255) / 256, 256, 0, stream>>>(eattr, dstA, bond_emb, bool_emb, We, be, efull, cnt);
  k_scan1<<<SCAN_NB, 256, 0, stream>>>(cnt, bsum);
  k_scan2<<<1, 256, 0, stream>>>(bsum);
  k_scan3<<<SCAN_NB, 256, 0, stream>>>(cnt, bsum, indptr, cursor);
  k_fill<<<(N_EDGES + N_NODES + 255) / 256, 256, 0, stream>>>(dstA, cursor, eord);
  k_loop_attr<<<(N_NODES + 255) / 256, 256, 0, stream>>>(indptr, eord, efull);

  const int GB = (N_NODES + 63) / 64;  // 1563 blocks

  // layer 1 (K=52, A stride 64 zero-padded)
  k_gemm2<64, 52><<<GB, 256, 0, stream>>>(h0, Wl1, bl1, Wr1, br1, xl, xrb);
  k_gat<<<2048, 256, 0, stream>>>(xl, xrb, efull, srcA, indptr, eord, Wedge1, att1, bias1, h);

  // layer 2 (K=128)
  k_gemm2<128, 128><<<GB, 256, 0, stream>>>(h, Wl2, bl2, Wr2, br2, xl, xrb);
  k_gat<<<2048, 256, 0, stream>>>(xl, xrb, efull, srcA, indptr, eord, Wedge2, att2, bias2, h);

  // layer 3 (shared weights with layer 2)
  k_gemm2<128, 128><<<GB, 256, 0, stream>>>(h, Wl2, bl2, Wr2, br2, xl, xrb);
  k_gat<<<2048, 256, 0, stream>>>(xl, xrb, efull, srcA, indptr, eord, Wedge2, att2, bias2, h);

  k_readout<<<(N_GRAPHS * 64 + 255) / 256, 256, 0, stream>>>(h, (float*)d_out);
}

// Round 5
// 752.167 us; speedup vs baseline: 4.4869x; 1.0610x over previous
//
#include <hip/hip_runtime.h>

#define N_NODES 100000
#define N_EDGES 400000
#define N_GRAPHS 5000
#define NPG 20
#define SCAN_NB 256
#define SCAN_CHUNK ((N_NODES + SCAN_NB - 1) / SCAN_NB)  // 391
#define TAB_STRIDE 3968  // 22*128 + 8*128 + 128

// ---------------- node encoder: h0[N,64] (cols 52..63 zero) ----------------
__global__ void k_encode_nodes(const float* __restrict__ x,
                               const float* __restrict__ atom_emb,
                               const float* __restrict__ bool_emb,
                               const float* __restrict__ Wn,
                               const float* __restrict__ bn,
                               float* __restrict__ h0) {
  int n = blockIdx.x * blockDim.x + threadIdx.x;
  if (n >= N_NODES) return;
  const float* xr = x + (size_t)n * 14;
  float* h = h0 + (size_t)n * 64;
  int ai = (int)xr[0];
  #pragma unroll
  for (int j = 0; j < 16; j++) h[j] = atom_emb[ai * 16 + j];
  float xc[10];
  #pragma unroll
  for (int k = 0; k < 10; k++) xc[k] = xr[1 + k];
  #pragma unroll
  for (int c = 0; c < 30; c++) {
    float s = bn[c];
    #pragma unroll
    for (int k = 0; k < 10; k++) s += xc[k] * Wn[k * 30 + c];
    h[16 + c] = s;
  }
  #pragma unroll
  for (int t = 0; t < 3; t++) {
    int b = (int)xr[11 + t];
    h[46 + 2 * t]     = bool_emb[2 * b];
    h[46 + 2 * t + 1] = bool_emb[2 * b + 1];
  }
  #pragma unroll
  for (int j = 52; j < 64; j++) h[j] = 0.0f;  // zero pad for K=64 GEMM
}

// ---------------- edge encoder (no float atomics) + int degree histogram ----
__global__ void k_encode_edges(const float* __restrict__ eattr,
                               const int* __restrict__ dst,
                               const float* __restrict__ bond_emb,
                               const float* __restrict__ bool_emb,
                               const float* __restrict__ We,
                               const float* __restrict__ be,
                               float* __restrict__ e_full,
                               int* __restrict__ cnt) {
  int e = blockIdx.x * blockDim.x + threadIdx.x;
  if (e >= N_EDGES) return;
  const float* r = eattr + (size_t)e * 5;
  float row[16];
  int bi = (int)r[0];
  #pragma unroll
  for (int j = 0; j < 8; j++) row[j] = bond_emb[bi * 8 + j];
  float ec = r[1];
  row[8] = ec * We[0] + be[0];
  row[9] = ec * We[1] + be[1];
  #pragma unroll
  for (int t = 0; t < 3; t++) {
    int b = (int)r[2 + t];
    row[10 + 2 * t]     = bool_emb[2 * b];
    row[10 + 2 * t + 1] = bool_emb[2 * b + 1];
  }
  float4* out = (float4*)(e_full + (size_t)e * 16);
  out[0] = make_float4(row[0], row[1], row[2], row[3]);
  out[1] = make_float4(row[4], row[5], row[6], row[7]);
  out[2] = make_float4(row[8], row[9], row[10], row[11]);
  out[3] = make_float4(row[12], row[13], row[14], row[15]);
  atomicAdd(cnt + dst[e], 1);
}

// ---------------- logit tables: elin = T1[bi] + ec*v + T2[combo] ------------
// tabs layout per set: [T1 22*128][T2 8*128][v 128]; 2 sets (Wedge1, Wedge2).
__global__ void k_build_tabs(const float* __restrict__ Wedge1,
                             const float* __restrict__ Wedge2,
                             const float* __restrict__ bond_emb,
                             const float* __restrict__ bool_emb,
                             const float* __restrict__ We,
                             const float* __restrict__ be,
                             float* __restrict__ tabs) {
  int t = threadIdx.x;
  int s = t >> 7, c = t & 127;
  const float* W = s ? Wedge2 : Wedge1;
  float* T1 = tabs + s * TAB_STRIDE;
  float* T2 = T1 + 22 * 128;
  float* v  = T1 + 30 * 128;
  for (int b = 0; b < 22; b++) {
    float acc = 0.f;
    #pragma unroll
    for (int k = 0; k < 8; k++) acc += bond_emb[b * 8 + k] * W[k * 128 + c];
    T1[b * 128 + c] = acc;
  }
  float w8 = W[8 * 128 + c], w9 = W[9 * 128 + c];
  v[c] = We[0] * w8 + We[1] * w9;
  float cst = be[0] * w8 + be[1] * w9;
  for (int combo = 0; combo < 8; combo++) {
    float acc = cst;
    #pragma unroll
    for (int tt = 0; tt < 3; tt++) {
      int bt = (combo >> tt) & 1;
      acc += bool_emb[bt * 2 + 0] * W[(10 + 2 * tt + 0) * 128 + c];
      acc += bool_emb[bt * 2 + 1] * W[(10 + 2 * tt + 1) * 128 + c];
    }
    T2[combo * 128 + c] = acc;
  }
}

// ---------------- hierarchical scan over (cnt[n]+1), 3 phases ---------------
__global__ __launch_bounds__(256) void k_scan1(const int* __restrict__ cnt,
                                               int* __restrict__ bsum) {
  __shared__ int red[256];
  int b = blockIdx.x, t = threadIdx.x;
  int beg = b * SCAN_CHUNK;
  int end = beg + SCAN_CHUNK; if (end > N_NODES) end = N_NODES;
  int s = 0;
  for (int i = beg + t; i < end; i += 256) s += cnt[i] + 1;  // coalesced
  red[t] = s;
  __syncthreads();
  for (int off = 128; off > 0; off >>= 1) {
    if (t < off) red[t] += red[t + off];
    __syncthreads();
  }
  if (t == 0) bsum[b] = red[0];
}

__global__ __launch_bounds__(256) void k_scan2(int* __restrict__ bsum) {
  __shared__ int sh[256];
  int t = threadIdx.x;
  sh[t] = bsum[t];
  __syncthreads();
  for (int off = 1; off < 256; off <<= 1) {
    int v = (t >= off) ? sh[t - off] : 0;
    __syncthreads();
    sh[t] += v;
    __syncthreads();
  }
  bsum[t] = (t > 0) ? sh[t - 1] : 0;  // exclusive
}

__global__ __launch_bounds__(256) void k_scan3(const int* __restrict__ cnt,
                                               const int* __restrict__ bsum,
                                               int* __restrict__ indptr,
                                               int* __restrict__ cursor) {
  __shared__ int sh[256];
  __shared__ int carry;
  int b = blockIdx.x, t = threadIdx.x;
  int beg = b * SCAN_CHUNK;
  int end = beg + SCAN_CHUNK; if (end > N_NODES) end = N_NODES;
  if (t == 0) carry = bsum[b];
  __syncthreads();
  for (int base = beg; base < end; base += 256) {
    int i = base + t;
    int v = (i < end) ? cnt[i] + 1 : 0;
    sh[t] = v;
    __syncthreads();
    for (int off = 1; off < 256; off <<= 1) {
      int u = (t >= off) ? sh[t - off] : 0;
      __syncthreads();
      sh[t] += u;
      __syncthreads();
    }
    int excl = sh[t] - v;
    if (i < end) {
      int val = carry + excl;
      indptr[i] = val;
      cursor[i] = val;
    }
    __syncthreads();
    if (t == 255) carry += sh[255];
    __syncthreads();
  }
  if (b == 0 && t == 0) indptr[N_NODES] = N_EDGES + N_NODES;  // total is constant
}

// ---------------- CSR fill: eord + position-ordered srcs/ecode --------------
// ecode[p] = {meta, ec}: meta = bi | (combo<<5), or 1<<15 for self-loops.
__global__ void k_fill(const int* __restrict__ srcA,
                       const int* __restrict__ dst,
                       const float* __restrict__ eattr,
                       int* __restrict__ cursor,
                       int* __restrict__ eord,
                       int* __restrict__ srcs,
                       float2* __restrict__ ecode) {
  int i = blockIdx.x * blockDim.x + threadIdx.x;
  if (i >= N_EDGES + N_NODES) return;
  int d, s, meta;
  float ec;
  if (i < N_EDGES) {
    d = dst[i];
    s = srcA[i];
    const float* r = eattr + (size_t)i * 5;
    int bi = (int)r[0];
    ec = r[1];
    int combo = (int)r[2] + 2 * (int)r[3] + 4 * (int)r[4];
    meta = bi | (combo << 5);
  } else {
    d = i - N_EDGES;
    s = d;
    meta = 1 << 15;
    ec = 0.f;
  }
  int p = atomicAdd(&cursor[d], 1);
  eord[p] = i;
  srcs[p] = s;
  ecode[p] = make_float2(__int_as_float(meta), ec);
}

// ---------------- loop_attr[n] = mean of in-edge attrs (CSR pass) -----------
__global__ void k_loop_attr(const int* __restrict__ indptr,
                            const int* __restrict__ eord,
                            float* __restrict__ e_full) {
  int n = blockIdx.x * blockDim.x + threadIdx.x;
  if (n >= N_NODES) return;
  int beg = indptr[n], end = indptr[n + 1];
  float4 s0 = make_float4(0, 0, 0, 0), s1 = s0, s2 = s0, s3 = s0;
  int c = 0;
  for (int j = beg; j < end; j++) {
    int eid = eord[j];
    if (eid >= N_EDGES) continue;
    const float4* ep = (const float4*)(e_full + (size_t)eid * 16);
    float4 a = ep[0], b = ep[1], cc = ep[2], d = ep[3];
    s0.x += a.x; s0.y += a.y; s0.z += a.z; s0.w += a.w;
    s1.x += b.x; s1.y += b.y; s1.z += b.z; s1.w += b.w;
    s2.x += cc.x; s2.y += cc.y; s2.z += cc.z; s2.w += cc.w;
    s3.x += d.x; s3.y += d.y; s3.z += d.z; s3.w += d.w;
    c++;
  }
  float inv = 1.0f / (float)(c > 0 ? c : 1);
  s0.x *= inv; s0.y *= inv; s0.z *= inv; s0.w *= inv;
  s1.x *= inv; s1.y *= inv; s1.z *= inv; s1.w *= inv;
  s2.x *= inv; s2.y *= inv; s2.z *= inv; s2.w *= inv;
  s3.x *= inv; s3.y *= inv; s3.z *= inv; s3.w *= inv;
  float4* lp = (float4*)(e_full + (size_t)(N_EDGES + n) * 16);
  lp[0] = s0; lp[1] = s1; lp[2] = s2; lp[3] = s3;
}

// ---------------- fused dual GEMM: xl/xr = A @ {Wl,Wr} + {bl,br} ------------
template <int KPAD, int K>
__global__ __launch_bounds__(256, 3) void k_gemm2(const float* __restrict__ A,
                                                  const float* __restrict__ Wl,
                                                  const float* __restrict__ bl_,
                                                  const float* __restrict__ Wr,
                                                  const float* __restrict__ br_,
                                                  float* __restrict__ outl,
                                                  float* __restrict__ outr) {
  __shared__ float As[32][68];     // As[k][row] transposed, pad 68
  __shared__ float Ws[2][32 * 128];
  const int tid = threadIdx.x;
  const int tx = tid & 15, ty = tid >> 4;
  const int lane = tid & 63, wv = tid >> 6;
  const int m0 = blockIdx.x * 64;
  const int r0 = ty * 4, c0 = tx * 4;

  float accL[4][8], accR[4][8];
  #pragma unroll
  for (int i = 0; i < 4; i++)
    #pragma unroll
    for (int j = 0; j < 8; j++) { accL[i][j] = 0.0f; accR[i][j] = 0.0f; }

  const int arow = (m0 + lane < N_NODES) ? m0 + lane : N_NODES - 1;

  for (int kk0 = 0; kk0 < KPAD; kk0 += 32) {
    {
      const float* ap = A + (size_t)arow * KPAD + kk0 + wv * 8;
      float4 v0 = ((const float4*)ap)[0];
      float4 v1 = ((const float4*)ap)[1];
      int kb = wv * 8;
      As[kb + 0][lane] = v0.x; As[kb + 1][lane] = v0.y;
      As[kb + 2][lane] = v0.z; As[kb + 3][lane] = v0.w;
      As[kb + 4][lane] = v1.x; As[kb + 5][lane] = v1.y;
      As[kb + 6][lane] = v1.z; As[kb + 7][lane] = v1.w;
    }
    #pragma unroll
    for (int i = 0; i < 4; i++) {
      int idx = tid + i * 256;
      int row = idx >> 5, col4 = idx & 31;
      int wrow = kk0 + row; if (wrow >= K) wrow = K - 1;  // A is zero there
      *(float4*)(Ws[0] + row * 128 + col4 * 4) = *(const float4*)(Wl + (size_t)wrow * 128 + col4 * 4);
      *(float4*)(Ws[1] + row * 128 + col4 * 4) = *(const float4*)(Wr + (size_t)wrow * 128 + col4 * 4);
    }
    __syncthreads();
    #pragma unroll 2
    for (int kk = 0; kk < 32; kk++) {
      float4 av = *(const float4*)&As[kk][r0];
      float a[4] = {av.x, av.y, av.z, av.w};
      float4 l0 = *(const float4*)(Ws[0] + kk * 128 + c0);
      float4 l1 = *(const float4*)(Ws[0] + kk * 128 + c0 + 64);
      float4 rr0 = *(const float4*)(Ws[1] + kk * 128 + c0);
      float4 rr1 = *(const float4*)(Ws[1] + kk * 128 + c0 + 64);
      float wL[8] = {l0.x, l0.y, l0.z, l0.w, l1.x, l1.y, l1.z, l1.w};
      float wR[8] = {rr0.x, rr0.y, rr0.z, rr0.w, rr1.x, rr1.y, rr1.z, rr1.w};
      #pragma unroll
      for (int i = 0; i < 4; i++)
        #pragma unroll
        for (int j = 0; j < 8; j++) {
          accL[i][j] += a[i] * wL[j];
          accR[i][j] += a[i] * wR[j];
        }
    }
    __syncthreads();
  }
  float blv[8], brv[8];
  #pragma unroll
  for (int j = 0; j < 4; j++) {
    blv[j] = bl_[c0 + j]; blv[4 + j] = bl_[c0 + 64 + j];
    brv[j] = br_[c0 + j]; brv[4 + j] = br_[c0 + 64 + j];
  }
  #pragma unroll
  for (int i = 0; i < 4; i++) {
    int n = m0 + r0 + i;
    if (n >= N_NODES) break;
    *(float4*)(outl + (size_t)n * 128 + c0) =
        make_float4(accL[i][0] + blv[0], accL[i][1] + blv[1], accL[i][2] + blv[2], accL[i][3] + blv[3]);
    *(float4*)(outl + (size_t)n * 128 + c0 + 64) =
        make_float4(accL[i][4] + blv[4], accL[i][5] + blv[5], accL[i][6] + blv[6], accL[i][7] + blv[7]);
    *(float4*)(outr + (size_t)n * 128 + c0) =
        make_float4(accR[i][0] + brv[0], accR[i][1] + brv[1], accR[i][2] + brv[2], accR[i][3] + brv[3]);
    *(float4*)(outr + (size_t)n * 128 + c0 + 64) =
        make_float4(accR[i][4] + brv[4], accR[i][5] + brv[5], accR[i][6] + brv[6], accR[i][7] + brv[7]);
  }
}

// ---------------- GATv2 edge pass: wave/node, tables + depth-2 pipeline -----
__global__ __launch_bounds__(256) void k_gat(const float* __restrict__ xl,
                                             const float* __restrict__ xr,
                                             const float* __restrict__ e_full,
                                             const int* __restrict__ indptr,
                                             const int* __restrict__ srcs,
                                             const float2* __restrict__ ecode,
                                             const float* __restrict__ tabs,
                                             const float* __restrict__ Wedge,
                                             const float* __restrict__ att,
                                             const float* __restrict__ bias,
                                             float* __restrict__ hout) {
  int wid = (blockIdx.x * 256 + threadIdx.x) >> 6;
  int nw = (gridDim.x * 256) >> 6;
  int lane = threadIdx.x & 63;
  int c = lane * 2;
  // Wedge columns for the (once-per-node) self-loop path
  float wreg[32];
  #pragma unroll
  for (int k = 0; k < 16; k++) {
    wreg[2 * k]     = Wedge[k * 128 + c];
    wreg[2 * k + 1] = Wedge[k * 128 + c + 1];
  }
  const float* T1 = tabs;             // 22 x 128
  const float* T2 = tabs + 22 * 128;  // 8 x 128
  float v0 = tabs[30 * 128 + c], v1 = tabs[30 * 128 + c + 1];
  float att0 = att[c], att1 = att[c + 1];
  float b0 = bias[c], b1 = bias[c + 1];
  wid = __builtin_amdgcn_readfirstlane(wid);
  for (int n = wid; n < N_NODES; n += nw) {
    int beg = indptr[n], end = indptr[n + 1];
    float2 xrv = *(const float2*)(xr + (size_t)n * 128 + c);
    float amax = -1e30f, denom = 0.f, acc0 = 0.f, acc1 = 0.f;
    // depth-2 pipeline: s/ecode at distance 2, xl row at distance 1
    int j1 = (beg + 1 < end) ? beg + 1 : end - 1;
    int s0 = srcs[beg];           float2 e0 = ecode[beg];
    int s1 = srcs[j1];            float2 e1 = ecode[j1];
    float2 xl0 = *(const float2*)(xl + (size_t)s0 * 128 + c);
    for (int j = beg; j < end; j++) {
      int j2 = (j + 2 < end) ? j + 2 : end - 1;
      int s2 = srcs[j2];          float2 e2 = ecode[j2];
      float2 xl1 = *(const float2*)(xl + (size_t)s1 * 128 + c);
      // ---- compute with (s0, e0, xl0) ----
      int meta = __float_as_int(e0.x);
      float el0, el1;
      if (meta & 0x8000) {  // self-loop (wave-uniform): full 16-dim dot
        const float4* ep = (const float4*)(e_full + (size_t)(N_EDGES + n) * 16);
        float4 q0 = ep[0], q1 = ep[1], q2 = ep[2], q3 = ep[3];
        float ev[16] = {q0.x, q0.y, q0.z, q0.w, q1.x, q1.y, q1.z, q1.w,
                        q2.x, q2.y, q2.z, q2.w, q3.x, q3.y, q3.z, q3.w};
        el0 = 0.f; el1 = 0.f;
        #pragma unroll
        for (int k = 0; k < 16; k++) {
          el0 += ev[k] * wreg[2 * k];
          el1 += ev[k] * wreg[2 * k + 1];
        }
      } else {
        int bi = meta & 31, combo = (meta >> 5) & 7;
        float2 t1 = *(const float2*)(T1 + bi * 128 + c);
        float2 t2 = *(const float2*)(T2 + combo * 128 + c);
        el0 = t1.x + t2.x + e0.y * v0;
        el1 = t1.y + t2.y + e0.y * v1;
      }
      float m0 = xl0.x + xrv.x + el0;
      float m1 = xl0.y + xrv.y + el1;
      float l0 = m0 > 0.f ? m0 : 0.2f * m0;
      float l1 = m1 > 0.f ? m1 : 0.2f * m1;
      float t = l0 * att0 + l1 * att1;
      #pragma unroll
      for (int off = 1; off < 64; off <<= 1) t += __shfl_xor(t, off, 64);
      // branchless online softmax
      float tmax = fmaxf(amax, t);
      float sc = __expf(amax - tmax);
      float ex = __expf(t - tmax);
      denom = denom * sc + ex;
      acc0 = acc0 * sc + ex * xl0.x;
      acc1 = acc1 * sc + ex * xl0.y;
      amax = tmax;
      // ---- shift pipeline ----
      s0 = s1; e0 = e1; xl0 = xl1;
      s1 = s2; e1 = e2;
    }
    float inv = 1.0f / denom;
    float o0 = acc0 * inv + b0;
    float o1 = acc1 * inv + b1;
    float2 o; o.x = o0 > 0.f ? o0 : 0.f; o.y = o1 > 0.f ? o1 : 0.f;
    *(float2*)(hout + (size_t)n * 128 + c) = o;
  }
}

// ---------------- readout: global max pool over 20 contiguous nodes --------
__global__ void k_readout(const float* __restrict__ h, float* __restrict__ out) {
  int wid = (blockIdx.x * blockDim.x + threadIdx.x) >> 6;
  int lane = threadIdx.x & 63;
  if (wid >= N_GRAPHS) return;
  int c = lane * 2;
  float m0 = -1e30f, m1 = -1e30f;
  for (int i = 0; i < NPG; i++) {
    const float2 v = *(const float2*)(h + ((size_t)(wid * NPG + i)) * 128 + c);
    m0 = fmaxf(m0, v.x);
    m1 = fmaxf(m1, v.y);
  }
  float2 o; o.x = m0; o.y = m1;
  *(float2*)(out + (size_t)wid * 128 + c) = o;
}

extern "C" void kernel_launch(void* const* d_in, const int* in_sizes, int n_in,
                              void* d_out, int out_size, void* d_ws, size_t ws_size,
                              hipStream_t stream) {
  (void)in_sizes; (void)n_in; (void)out_size; (void)ws_size;
  const float* x        = (const float*)d_in[0];
  const int*   eindex   = (const int*)d_in[1];
  const float* eattr    = (const float*)d_in[2];
  const float* atom_emb = (const float*)d_in[4];
  const float* bond_emb = (const float*)d_in[5];
  const float* bool_emb = (const float*)d_in[6];
  const float* Wn   = (const float*)d_in[7];
  const float* bn   = (const float*)d_in[8];
  const float* We   = (const float*)d_in[9];
  const float* be   = (const float*)d_in[10];
  const float* Wl1  = (const float*)d_in[11];
  const float* bl1  = (const float*)d_in[12];
  const float* Wr1  = (const float*)d_in[13];
  const float* br1  = (const float*)d_in[14];
  const float* Wedge1 = (const float*)d_in[15];
  const float* att1 = (const float*)d_in[16];
  const float* bias1 = (const float*)d_in[17];
  const float* Wl2  = (const float*)d_in[18];
  const float* bl2  = (const float*)d_in[19];
  const float* Wr2  = (const float*)d_in[20];
  const float* br2  = (const float*)d_in[21];
  const float* Wedge2 = (const float*)d_in[22];
  const float* att2 = (const float*)d_in[23];
  const float* bias2 = (const float*)d_in[24];

  const int* srcA = eindex;
  const int* dstA = eindex + N_EDGES;

  char* p = (char*)d_ws;
  auto alloc = [&](size_t bytes) {
    char* r = p;
    p += (bytes + 255) & ~(size_t)255;
    return r;
  };
  float*  h0     = (float*)alloc((size_t)N_NODES * 64 * 4);
  float*  h      = (float*)alloc((size_t)N_NODES * 128 * 4);
  float*  xl     = (float*)alloc((size_t)N_NODES * 128 * 4);
  float*  xrb    = (float*)alloc((size_t)N_NODES * 128 * 4);
  float*  efull  = (float*)alloc((size_t)(N_EDGES + N_NODES) * 16 * 4);
  int*    cnt    = (int*)alloc((size_t)N_NODES * 4);
  int*    indptr = (int*)alloc((size_t)(N_NODES + 1) * 4);
  int*    cursor = (int*)alloc((size_t)N_NODES * 4);
  int*    eord   = (int*)alloc((size_t)(N_EDGES + N_NODES) * 4);
  int*    srcs   = (int*)alloc((size_t)(N_EDGES + N_NODES) * 4);
  float2* ecode  = (float2*)alloc((size_t)(N_EDGES + N_NODES) * 8);
  float*  tabs   = (float*)alloc((size_t)2 * TAB_STRIDE * 4);
  int*    bsum   = (int*)alloc((size_t)SCAN_NB * 4);

  hipMemsetAsync(cnt, 0, (size_t)N_NODES * 4, stream);

  k_encode_nodes<<<(N_NODES + 255) / 256, 256, 0, stream>>>(x, atom_emb, bool_emb, Wn, bn, h0);
  k_encode_edges<<<(N_EDGES + 255) / 256, 256, 0, stream>>>(eattr, dstA, bond_emb, bool_emb, We, be, efull, cnt);
  k_build_tabs<<<1, 256, 0, stream>>>(Wedge1, Wedge2, bond_emb, bool_emb, We, be, tabs);
  k_scan1<<<SCAN_NB, 256, 0, stream>>>(cnt, bsum);
  k_scan2<<<1, 256, 0, stream>>>(bsum);
  k_scan3<<<SCAN_NB, 256, 0, stream>>>(cnt, bsum, indptr, cursor);
  k_fill<<<(N_EDGES + N_NODES + 255) / 256, 256, 0, stream>>>(srcA, dstA, eattr, cursor, eord, srcs, ecode);
  k_loop_attr<<<(N_NODES + 255) / 256, 256, 0, stream>>>(indptr, eord, efull);

  const int GB = (N_NODES + 63) / 64;  // 1563 blocks

  // layer 1 (K=52, A stride 64 zero-padded)
  k_gemm2<64, 52><<<GB, 256, 0, stream>>>(h0, Wl1, bl1, Wr1, br1, xl, xrb);
  k_gat<<<2048, 256, 0, stream>>>(xl, xrb, efull, indptr, srcs, ecode,
                                  tabs, Wedge1, att1, bias1, h);

  // layer 2 (K=128)
  k_gemm2<128, 128><<<GB, 256, 0, stream>>>(h, Wl2, bl2, Wr2, br2, xl, xrb);
  k_gat<<<2048, 256, 0, stream>>>(xl, xrb, efull, indptr, srcs, ecode,
                                  tabs + TAB_STRIDE, Wedge2, att2, bias2, h);

  // layer 3 (shared weights with layer 2)
  k_gemm2<128, 128><<<GB, 256, 0, stream>>>(h, Wl2, bl2, Wr2, br2, xl, xrb);
  k_gat<<<2048, 256, 0, stream>>>(xl, xrb, efull, indptr, srcs, ecode,
                                  tabs + TAB_STRIDE, Wedge2, att2, bias2, h);

  k_readout<<<(N_GRAPHS * 64 + 255) / 256, 256, 0, stream>>>(h, (float*)d_out);
}

// Round 6
// 657.606 us; speedup vs baseline: 5.1321x; 1.1438x over previous
//
#include <hip/hip_runtime.h>

#define N_NODES 100000
#define N_EDGES 400000
#define N_GRAPHS 5000
#define NPG 20
#define SCAN_NB 256
#define SCAN_CHUNK ((N_NODES + SCAN_NB - 1) / SCAN_NB)  // 391
#define TAB_STRIDE 3968  // 22*128 + 8*128 + 128

// ---------------- node encoder: h0[N,64] (cols 52..63 zero) ----------------
__global__ void k_encode_nodes(const float* __restrict__ x,
                               const float* __restrict__ atom_emb,
                               const float* __restrict__ bool_emb,
                               const float* __restrict__ Wn,
                               const float* __restrict__ bn,
                               float* __restrict__ h0) {
  int n = blockIdx.x * blockDim.x + threadIdx.x;
  if (n >= N_NODES) return;
  const float* xr = x + (size_t)n * 14;
  float* h = h0 + (size_t)n * 64;
  int ai = (int)xr[0];
  #pragma unroll
  for (int j = 0; j < 16; j++) h[j] = atom_emb[ai * 16 + j];
  float xc[10];
  #pragma unroll
  for (int k = 0; k < 10; k++) xc[k] = xr[1 + k];
  #pragma unroll
  for (int c = 0; c < 30; c++) {
    float s = bn[c];
    #pragma unroll
    for (int k = 0; k < 10; k++) s += xc[k] * Wn[k * 30 + c];
    h[16 + c] = s;
  }
  #pragma unroll
  for (int t = 0; t < 3; t++) {
    int b = (int)xr[11 + t];
    h[46 + 2 * t]     = bool_emb[2 * b];
    h[46 + 2 * t + 1] = bool_emb[2 * b + 1];
  }
  #pragma unroll
  for (int j = 52; j < 64; j++) h[j] = 0.0f;  // zero pad for K=64 GEMM
}

// ---------------- in-degree histogram ----------------
__global__ void k_hist(const int* __restrict__ dst, int* __restrict__ cnt) {
  int e = blockIdx.x * blockDim.x + threadIdx.x;
  if (e >= N_EDGES) return;
  atomicAdd(cnt + dst[e], 1);
}

// ---------------- logit tables: elin = T1[bi] + ec*v + T2[combo] ------------
// tabs layout per set: [T1 22*128][T2 8*128][v 128]; 2 sets (Wedge1, Wedge2).
__global__ void k_build_tabs(const float* __restrict__ Wedge1,
                             const float* __restrict__ Wedge2,
                             const float* __restrict__ bond_emb,
                             const float* __restrict__ bool_emb,
                             const float* __restrict__ We,
                             const float* __restrict__ be,
                             float* __restrict__ tabs) {
  int t = threadIdx.x;
  int s = t >> 7, c = t & 127;
  const float* W = s ? Wedge2 : Wedge1;
  float* T1 = tabs + s * TAB_STRIDE;
  float* T2 = T1 + 22 * 128;
  float* v  = T1 + 30 * 128;
  for (int b = 0; b < 22; b++) {
    float acc = 0.f;
    #pragma unroll
    for (int k = 0; k < 8; k++) acc += bond_emb[b * 8 + k] * W[k * 128 + c];
    T1[b * 128 + c] = acc;
  }
  float w8 = W[8 * 128 + c], w9 = W[9 * 128 + c];
  v[c] = We[0] * w8 + We[1] * w9;
  float cst = be[0] * w8 + be[1] * w9;
  for (int combo = 0; combo < 8; combo++) {
    float acc = cst;
    #pragma unroll
    for (int tt = 0; tt < 3; tt++) {
      int bt = (combo >> tt) & 1;
      acc += bool_emb[bt * 2 + 0] * W[(10 + 2 * tt + 0) * 128 + c];
      acc += bool_emb[bt * 2 + 1] * W[(10 + 2 * tt + 1) * 128 + c];
    }
    T2[combo * 128 + c] = acc;
  }
}

// ---------------- hierarchical scan over (cnt[n]+1), 3 phases ---------------
__global__ __launch_bounds__(256) void k_scan1(const int* __restrict__ cnt,
                                               int* __restrict__ bsum) {
  __shared__ int red[256];
  int b = blockIdx.x, t = threadIdx.x;
  int beg = b * SCAN_CHUNK;
  int end = beg + SCAN_CHUNK; if (end > N_NODES) end = N_NODES;
  int s = 0;
  for (int i = beg + t; i < end; i += 256) s += cnt[i] + 1;  // coalesced
  red[t] = s;
  __syncthreads();
  for (int off = 128; off > 0; off >>= 1) {
    if (t < off) red[t] += red[t + off];
    __syncthreads();
  }
  if (t == 0) bsum[b] = red[0];
}

__global__ __launch_bounds__(256) void k_scan2(int* __restrict__ bsum) {
  __shared__ int sh[256];
  int t = threadIdx.x;
  sh[t] = bsum[t];
  __syncthreads();
  for (int off = 1; off < 256; off <<= 1) {
    int v = (t >= off) ? sh[t - off] : 0;
    __syncthreads();
    sh[t] += v;
    __syncthreads();
  }
  bsum[t] = (t > 0) ? sh[t - 1] : 0;  // exclusive
}

__global__ __launch_bounds__(256) void k_scan3(const int* __restrict__ cnt,
                                               const int* __restrict__ bsum,
                                               int* __restrict__ indptr,
                                               int* __restrict__ cursor) {
  __shared__ int sh[256];
  __shared__ int carry;
  int b = blockIdx.x, t = threadIdx.x;
  int beg = b * SCAN_CHUNK;
  int end = beg + SCAN_CHUNK; if (end > N_NODES) end = N_NODES;
  if (t == 0) carry = bsum[b];
  __syncthreads();
  for (int base = beg; base < end; base += 256) {
    int i = base + t;
    int v = (i < end) ? cnt[i] + 1 : 0;
    sh[t] = v;
    __syncthreads();
    for (int off = 1; off < 256; off <<= 1) {
      int u = (t >= off) ? sh[t - off] : 0;
      __syncthreads();
      sh[t] += u;
      __syncthreads();
    }
    int excl = sh[t] - v;
    if (i < end) {
      int val = carry + excl;
      indptr[i] = val;
      cursor[i] = val;
    }
    __syncthreads();
    if (t == 255) carry += sh[255];
    __syncthreads();
  }
  if (b == 0 && t == 0) indptr[N_NODES] = N_EDGES + N_NODES;  // total is constant
}

// ---------------- CSR fill: ordinary edges into slots [beg, end-1) ----------
// scode[p] = {src, meta = bi|(combo<<5), ec_bits, 0}. Slot end-1 is reserved
// for the (implicit) self-loop and never written/read.
__global__ void k_fill(const int* __restrict__ srcA,
                       const int* __restrict__ dst,
                       const float* __restrict__ eattr,
                       int* __restrict__ cursor,
                       int4* __restrict__ scode) {
  int e = blockIdx.x * blockDim.x + threadIdx.x;
  if (e >= N_EDGES) return;
  const float* r = eattr + (size_t)e * 5;
  int bi = (int)r[0];
  float ec = r[1];
  int combo = (int)r[2] + 2 * (int)r[3] + 4 * (int)r[4];
  int meta = bi | (combo << 5);
  int d = dst[e];
  int p = atomicAdd(&cursor[d], 1);
  scode[p] = make_int4(srcA[e], meta, __float_as_int(ec), 0);
}

// ---------------- fused dual GEMM: xl/xr = A @ {Wl,Wr} + {bl,br} ------------
template <int KPAD, int K>
__global__ __launch_bounds__(256, 3) void k_gemm2(const float* __restrict__ A,
                                                  const float* __restrict__ Wl,
                                                  const float* __restrict__ bl_,
                                                  const float* __restrict__ Wr,
                                                  const float* __restrict__ br_,
                                                  float* __restrict__ outl,
                                                  float* __restrict__ outr) {
  __shared__ float As[32][68];     // As[k][row] transposed, pad 68
  __shared__ float Ws[2][32 * 128];
  const int tid = threadIdx.x;
  const int tx = tid & 15, ty = tid >> 4;
  const int lane = tid & 63, wv = tid >> 6;
  const int m0 = blockIdx.x * 64;
  const int r0 = ty * 4, c0 = tx * 4;

  float accL[4][8], accR[4][8];
  #pragma unroll
  for (int i = 0; i < 4; i++)
    #pragma unroll
    for (int j = 0; j < 8; j++) { accL[i][j] = 0.0f; accR[i][j] = 0.0f; }

  const int arow = (m0 + lane < N_NODES) ? m0 + lane : N_NODES - 1;

  for (int kk0 = 0; kk0 < KPAD; kk0 += 32) {
    {
      const float* ap = A + (size_t)arow * KPAD + kk0 + wv * 8;
      float4 v0 = ((const float4*)ap)[0];
      float4 v1 = ((const float4*)ap)[1];
      int kb = wv * 8;
      As[kb + 0][lane] = v0.x; As[kb + 1][lane] = v0.y;
      As[kb + 2][lane] = v0.z; As[kb + 3][lane] = v0.w;
      As[kb + 4][lane] = v1.x; As[kb + 5][lane] = v1.y;
      As[kb + 6][lane] = v1.z; As[kb + 7][lane] = v1.w;
    }
    #pragma unroll
    for (int i = 0; i < 4; i++) {
      int idx = tid + i * 256;
      int row = idx >> 5, col4 = idx & 31;
      int wrow = kk0 + row; if (wrow >= K) wrow = K - 1;  // A is zero there
      *(float4*)(Ws[0] + row * 128 + col4 * 4) = *(const float4*)(Wl + (size_t)wrow * 128 + col4 * 4);
      *(float4*)(Ws[1] + row * 128 + col4 * 4) = *(const float4*)(Wr + (size_t)wrow * 128 + col4 * 4);
    }
    __syncthreads();
    #pragma unroll 2
    for (int kk = 0; kk < 32; kk++) {
      float4 av = *(const float4*)&As[kk][r0];
      float a[4] = {av.x, av.y, av.z, av.w};
      float4 l0 = *(const float4*)(Ws[0] + kk * 128 + c0);
      float4 l1 = *(const float4*)(Ws[0] + kk * 128 + c0 + 64);
      float4 rr0 = *(const float4*)(Ws[1] + kk * 128 + c0);
      float4 rr1 = *(const float4*)(Ws[1] + kk * 128 + c0 + 64);
      float wL[8] = {l0.x, l0.y, l0.z, l0.w, l1.x, l1.y, l1.z, l1.w};
      float wR[8] = {rr0.x, rr0.y, rr0.z, rr0.w, rr1.x, rr1.y, rr1.z, rr1.w};
      #pragma unroll
      for (int i = 0; i < 4; i++)
        #pragma unroll
        for (int j = 0; j < 8; j++) {
          accL[i][j] += a[i] * wL[j];
          accR[i][j] += a[i] * wR[j];
        }
    }
    __syncthreads();
  }
  float blv[8], brv[8];
  #pragma unroll
  for (int j = 0; j < 4; j++) {
    blv[j] = bl_[c0 + j]; blv[4 + j] = bl_[c0 + 64 + j];
    brv[j] = br_[c0 + j]; brv[4 + j] = br_[c0 + 64 + j];
  }
  #pragma unroll
  for (int i = 0; i < 4; i++) {
    int n = m0 + r0 + i;
    if (n >= N_NODES) break;
    *(float4*)(outl + (size_t)n * 128 + c0) =
        make_float4(accL[i][0] + blv[0], accL[i][1] + blv[1], accL[i][2] + blv[2], accL[i][3] + blv[3]);
    *(float4*)(outl + (size_t)n * 128 + c0 + 64) =
        make_float4(accL[i][4] + blv[4], accL[i][5] + blv[5], accL[i][6] + blv[6], accL[i][7] + blv[7]);
    *(float4*)(outr + (size_t)n * 128 + c0) =
        make_float4(accR[i][0] + brv[0], accR[i][1] + brv[1], accR[i][2] + brv[2], accR[i][3] + brv[3]);
    *(float4*)(outr + (size_t)n * 128 + c0 + 64) =
        make_float4(accR[i][4] + brv[4], accR[i][5] + brv[5], accR[i][6] + brv[6], accR[i][7] + brv[7]);
  }
}

// ---------------- GATv2 edge pass: wave/node, 4-edge batched reductions -----
// Ordinary edges in [beg, end-1); self-loop handled last with
// elin_self = mean(per-edge elin) (linearity of the edge encoder + Wedge).
__global__ __launch_bounds__(256) void k_gat(const float* __restrict__ xl,
                                             const float* __restrict__ xr,
                                             const int* __restrict__ indptr,
                                             const int4* __restrict__ scode,
                                             const float* __restrict__ tabs,
                                             const float* __restrict__ att,
                                             const float* __restrict__ bias,
                                             float* __restrict__ hout) {
  int wid = (blockIdx.x * 256 + threadIdx.x) >> 6;
  int nw = (gridDim.x * 256) >> 6;
  int lane = threadIdx.x & 63;
  int c = lane * 2;
  const float* T1 = tabs;             // 22 x 128
  const float* T2 = tabs + 22 * 128;  // 8 x 128
  float v0 = tabs[30 * 128 + c], v1 = tabs[30 * 128 + c + 1];
  float att0 = att[c], att1 = att[c + 1];
  float b0 = bias[c], b1 = bias[c + 1];
  wid = __builtin_amdgcn_readfirstlane(wid);
  for (int n = wid; n < N_NODES; n += nw) {
    int beg = indptr[n], end1 = indptr[n + 1] - 1;  // end1 = self-loop slot
    float2 xrv = *(const float2*)(xr + (size_t)n * 128 + c);
    float amax = -1e30f, denom = 0.f, acc0 = 0.f, acc1 = 0.f;
    float els0 = 0.f, els1 = 0.f;
    for (int j = beg; j < end1; j += 4) {
      int4 sc4[4]; float2 xlv[4]; float tt[4], el0[4], el1[4];
      #pragma unroll
      for (int u = 0; u < 4; u++) {
        int jj = (j + u < end1) ? j + u : end1 - 1;
        sc4[u] = scode[jj];
      }
      #pragma unroll
      for (int u = 0; u < 4; u++)
        xlv[u] = *(const float2*)(xl + (size_t)sc4[u].x * 128 + c);
      #pragma unroll
      for (int u = 0; u < 4; u++) {
        int meta = sc4[u].y;
        int bi = meta & 31, combo = (meta >> 5) & 7;
        float ec = __int_as_float(sc4[u].z);
        float2 t1v = *(const float2*)(T1 + bi * 128 + c);
        float2 t2v = *(const float2*)(T2 + combo * 128 + c);
        el0[u] = t1v.x + t2v.x + ec * v0;
        el1[u] = t1v.y + t2v.y + ec * v1;
        float m0 = xlv[u].x + xrv.x + el0[u];
        float m1 = xlv[u].y + xrv.y + el1[u];
        float l0 = m0 > 0.f ? m0 : 0.2f * m0;
        float l1 = m1 > 0.f ? m1 : 0.2f * m1;
        tt[u] = l0 * att0 + l1 * att1;
      }
      // 4 independent reduction chains, interleaved (latency overlap)
      #pragma unroll
      for (int off = 1; off < 64; off <<= 1) {
        tt[0] += __shfl_xor(tt[0], off, 64);
        tt[1] += __shfl_xor(tt[1], off, 64);
        tt[2] += __shfl_xor(tt[2], off, 64);
        tt[3] += __shfl_xor(tt[3], off, 64);
      }
      #pragma unroll
      for (int u = 0; u < 4; u++) {
        bool valid = (j + u < end1);  // wave-uniform
        if (!valid) tt[u] = -1e30f;
        els0 += valid ? el0[u] : 0.f;
        els1 += valid ? el1[u] : 0.f;
      }
      float bm = fmaxf(fmaxf(tt[0], tt[1]), fmaxf(tt[2], tt[3]));
      float nm = fmaxf(amax, bm);
      float sc = __expf(amax - nm);
      denom *= sc; acc0 *= sc; acc1 *= sc;
      #pragma unroll
      for (int u = 0; u < 4; u++) {
        float ex = __expf(tt[u] - nm);
        denom += ex;
        acc0 += ex * xlv[u].x;
        acc1 += ex * xlv[u].y;
      }
      amax = nm;
    }
    // self-loop (always present, processed last)
    int cntn = end1 - beg;
    float inv_cnt = 1.0f / (float)(cntn > 0 ? cntn : 1);
    float elL0 = els0 * inv_cnt, elL1 = els1 * inv_cnt;
    float2 xln = *(const float2*)(xl + (size_t)n * 128 + c);
    float m0 = xln.x + xrv.x + elL0;
    float m1 = xln.y + xrv.y + elL1;
    float l0 = m0 > 0.f ? m0 : 0.2f * m0;
    float l1 = m1 > 0.f ? m1 : 0.2f * m1;
    float ts = l0 * att0 + l1 * att1;
    #pragma unroll
    for (int off = 1; off < 64; off <<= 1) ts += __shfl_xor(ts, off, 64);
    float nm = fmaxf(amax, ts);
    float sc = __expf(amax - nm);
    float ex = __expf(ts - nm);
    denom = denom * sc + ex;
    acc0 = acc0 * sc + ex * xln.x;
    acc1 = acc1 * sc + ex * xln.y;
    float invd = 1.0f / denom;
    float o0 = acc0 * invd + b0;
    float o1 = acc1 * invd + b1;
    float2 o; o.x = o0 > 0.f ? o0 : 0.f; o.y = o1 > 0.f ? o1 : 0.f;
    *(float2*)(hout + (size_t)n * 128 + c) = o;
  }
}

// ---------------- readout: global max pool over 20 contiguous nodes --------
__global__ void k_readout(const float* __restrict__ h, float* __restrict__ out) {
  int wid = (blockIdx.x * blockDim.x + threadIdx.x) >> 6;
  int lane = threadIdx.x & 63;
  if (wid >= N_GRAPHS) return;
  int c = lane * 2;
  float m0 = -1e30f, m1 = -1e30f;
  for (int i = 0; i < NPG; i++) {
    const float2 v = *(const float2*)(h + ((size_t)(wid * NPG + i)) * 128 + c);
    m0 = fmaxf(m0, v.x);
    m1 = fmaxf(m1, v.y);
  }
  float2 o; o.x = m0; o.y = m1;
  *(float2*)(out + (size_t)wid * 128 + c) = o;
}

extern "C" void kernel_launch(void* const* d_in, const int* in_sizes, int n_in,
                              void* d_out, int out_size, void* d_ws, size_t ws_size,
                              hipStream_t stream) {
  (void)in_sizes; (void)n_in; (void)out_size; (void)ws_size;
  const float* x        = (const float*)d_in[0];
  const int*   eindex   = (const int*)d_in[1];
  const float* eattr    = (const float*)d_in[2];
  const float* atom_emb = (const float*)d_in[4];
  const float* bond_emb = (const float*)d_in[5];
  const float* bool_emb = (const float*)d_in[6];
  const float* Wn   = (const float*)d_in[7];
  const float* bn   = (const float*)d_in[8];
  const float* We   = (const float*)d_in[9];
  const float* be   = (const float*)d_in[10];
  const float* Wl1  = (const float*)d_in[11];
  const float* bl1  = (const float*)d_in[12];
  const float* Wr1  = (const float*)d_in[13];
  const float* br1  = (const float*)d_in[14];
  const float* Wedge1 = (const float*)d_in[15];
  const float* att1 = (const float*)d_in[16];
  const float* bias1 = (const float*)d_in[17];
  const float* Wl2  = (const float*)d_in[18];
  const float* bl2  = (const float*)d_in[19];
  const float* Wr2  = (const float*)d_in[20];
  const float* br2  = (const float*)d_in[21];
  const float* Wedge2 = (const float*)d_in[22];
  const float* att2 = (const float*)d_in[23];
  const float* bias2 = (const float*)d_in[24];

  const int* srcA = eindex;
  const int* dstA = eindex + N_EDGES;

  char* p = (char*)d_ws;
  auto alloc = [&](size_t bytes) {
    char* r = p;
    p += (bytes + 255) & ~(size_t)255;
    return r;
  };
  float* h0     = (float*)alloc((size_t)N_NODES * 64 * 4);
  float* h      = (float*)alloc((size_t)N_NODES * 128 * 4);
  float* xl     = (float*)alloc((size_t)N_NODES * 128 * 4);
  float* xrb    = (float*)alloc((size_t)N_NODES * 128 * 4);
  int*   cnt    = (int*)alloc((size_t)N_NODES * 4);
  int*   indptr = (int*)alloc((size_t)(N_NODES + 1) * 4);
  int*   cursor = (int*)alloc((size_t)N_NODES * 4);
  int4*  scode  = (int4*)alloc((size_t)(N_EDGES + N_NODES) * 16);
  float* tabs   = (float*)alloc((size_t)2 * TAB_STRIDE * 4);
  int*   bsum   = (int*)alloc((size_t)SCAN_NB * 4);

  hipMemsetAsync(cnt, 0, (size_t)N_NODES * 4, stream);

  k_encode_nodes<<<(N_NODES + 255) / 256, 256, 0, stream>>>(x, atom_emb, bool_emb, Wn, bn, h0);
  k_hist<<<(N_EDGES + 255) / 256, 256, 0, stream>>>(dstA, cnt);
  k_build_tabs<<<1, 256, 0, stream>>>(Wedge1, Wedge2, bond_emb, bool_emb, We, be, tabs);
  k_scan1<<<SCAN_NB, 256, 0, stream>>>(cnt, bsum);
  k_scan2<<<1, 256, 0, stream>>>(bsum);
  k_scan3<<<SCAN_NB, 256, 0, stream>>>(cnt, bsum, indptr, cursor);
  k_fill<<<(N_EDGES + 255) / 256, 256, 0, stream>>>(srcA, dstA, eattr, cursor, scode);

  const int GB = (N_NODES + 63) / 64;  // 1563 blocks

  // layer 1 (K=52, A stride 64 zero-padded)
  k_gemm2<64, 52><<<GB, 256, 0, stream>>>(h0, Wl1, bl1, Wr1, br1, xl, xrb);
  k_gat<<<2048, 256, 0, stream>>>(xl, xrb, indptr, scode, tabs, att1, bias1, h);

  // layer 2 (K=128)
  k_gemm2<128, 128><<<GB, 256, 0, stream>>>(h, Wl2, bl2, Wr2, br2, xl, xrb);
  k_gat<<<2048, 256, 0, stream>>>(xl, xrb, indptr, scode, tabs + TAB_STRIDE, att2, bias2, h);

  // layer 3 (shared weights with layer 2)
  k_gemm2<128, 128><<<GB, 256, 0, stream>>>(h, Wl2, bl2, Wr2, br2, xl, xrb);
  k_gat<<<2048, 256, 0, stream>>>(xl, xrb, indptr, scode, tabs + TAB_STRIDE, att2, bias2, h);

  k_readout<<<(N_GRAPHS * 64 + 255) / 256, 256, 0, stream>>>(h, (float*)d_out);
}

// Round 7
// 592.131 us; speedup vs baseline: 5.6996x; 1.1106x over previous
//
#include <hip/hip_runtime.h>

#define N_NODES 100000
#define N_EDGES 400000
#define N_GRAPHS 5000
#define NPG 20
#define SCAN_NB 256
#define SCAN_CHUNK ((N_NODES + SCAN_NB - 1) / SCAN_NB)  // 391
#define TAB_STRIDE 3968  // 22*128 + 8*128 + 128
#define F1 8192          // ushorts per K=64 frag array (1024 frags * 8)
#define F2 16384         // ushorts per K=128 frag array (2048 frags * 8)

typedef __attribute__((ext_vector_type(8))) short bf16x8;
typedef __attribute__((ext_vector_type(4))) float f32x4;

__device__ __forceinline__ unsigned short f2bf(float f) {
  unsigned u = __float_as_uint(f);
  unsigned r = (u + 0x7FFFu + ((u >> 16) & 1u)) >> 16;
  return (unsigned short)r;
}
__device__ __forceinline__ float bf2f(unsigned short h) {
  return __uint_as_float(((unsigned)h) << 16);
}

// ---------------- node encoder: h0[N,64] (cols 52..63 zero) ----------------
__global__ void k_encode_nodes(const float* __restrict__ x,
                               const float* __restrict__ atom_emb,
                               const float* __restrict__ bool_emb,
                               const float* __restrict__ Wn,
                               const float* __restrict__ bn,
                               float* __restrict__ h0) {
  int n = blockIdx.x * blockDim.x + threadIdx.x;
  if (n >= N_NODES) return;
  const float* xr = x + (size_t)n * 14;
  float* h = h0 + (size_t)n * 64;
  int ai = (int)xr[0];
  #pragma unroll
  for (int j = 0; j < 16; j++) h[j] = atom_emb[ai * 16 + j];
  float xc[10];
  #pragma unroll
  for (int k = 0; k < 10; k++) xc[k] = xr[1 + k];
  #pragma unroll
  for (int c = 0; c < 30; c++) {
    float s = bn[c];
    #pragma unroll
    for (int k = 0; k < 10; k++) s += xc[k] * Wn[k * 30 + c];
    h[16 + c] = s;
  }
  #pragma unroll
  for (int t = 0; t < 3; t++) {
    int b = (int)xr[11 + t];
    h[46 + 2 * t]     = bool_emb[2 * b];
    h[46 + 2 * t + 1] = bool_emb[2 * b + 1];
  }
  #pragma unroll
  for (int j = 52; j < 64; j++) h[j] = 0.0f;  // zero pad for K=64 GEMM
}

// ---------------- in-degree histogram ----------------
__global__ void k_hist(const int* __restrict__ dst, int* __restrict__ cnt) {
  int e = blockIdx.x * blockDim.x + threadIdx.x;
  if (e >= N_EDGES) return;
  atomicAdd(cnt + dst[e], 1);
}

// ---------------- logit tables: elin = T1[bi] + ec*v + T2[combo] ------------
__global__ void k_build_tabs(const float* __restrict__ Wedge1,
                             const float* __restrict__ Wedge2,
                             const float* __restrict__ bond_emb,
                             const float* __restrict__ bool_emb,
                             const float* __restrict__ We,
                             const float* __restrict__ be,
                             float* __restrict__ tabs) {
  int t = threadIdx.x;
  int s = t >> 7, c = t & 127;
  const float* W = s ? Wedge2 : Wedge1;
  float* T1 = tabs + s * TAB_STRIDE;
  float* T2 = T1 + 22 * 128;
  float* v  = T1 + 30 * 128;
  for (int b = 0; b < 22; b++) {
    float acc = 0.f;
    #pragma unroll
    for (int k = 0; k < 8; k++) acc += bond_emb[b * 8 + k] * W[k * 128 + c];
    T1[b * 128 + c] = acc;
  }
  float w8 = W[8 * 128 + c], w9 = W[9 * 128 + c];
  v[c] = We[0] * w8 + We[1] * w9;
  float cst = be[0] * w8 + be[1] * w9;
  for (int combo = 0; combo < 8; combo++) {
    float acc = cst;
    #pragma unroll
    for (int tt = 0; tt < 3; tt++) {
      int bt = (combo >> tt) & 1;
      acc += bool_emb[bt * 2 + 0] * W[(10 + 2 * tt + 0) * 128 + c];
      acc += bool_emb[bt * 2 + 1] * W[(10 + 2 * tt + 1) * 128 + c];
    }
    T2[combo * 128 + c] = acc;
  }
}

// ---------------- W -> MFMA B-fragment prep (hi/lo split-bf16) --------------
// frag layout per W: [chunk c][ntile t][lane l] -> 8 bf16; element =
// W[(c*32 + (l>>4)*8 + j)*128 + (t*16 + (l&15))], zero for k >= K.
// fr layout (ushort units): Wl1 hi@0 lo@F1 | Wr1 hi@2F1 lo@3F1 |
//                           Wl2 hi@4F1 lo@4F1+F2 | Wr2 hi@4F1+2F2 lo@4F1+3F2
__global__ __launch_bounds__(256) void k_prep(const float* __restrict__ Wl1,
                                              const float* __restrict__ Wr1,
                                              const float* __restrict__ Wl2,
                                              const float* __restrict__ Wr2,
                                              unsigned short* __restrict__ fr) {
  int g = blockIdx.x * 256 + threadIdx.x;
  const float* W; int K; unsigned short *hi, *lo; int fl;
  if (g < 1024)      { W = Wl1; K = 52;  hi = fr;                lo = fr + F1;               fl = g; }
  else if (g < 2048) { W = Wr1; K = 52;  hi = fr + 2 * F1;       lo = fr + 3 * F1;           fl = g - 1024; }
  else if (g < 4096) { W = Wl2; K = 128; hi = fr + 4 * F1;       lo = fr + 4 * F1 + F2;      fl = g - 2048; }
  else if (g < 6144) { W = Wr2; K = 128; hi = fr + 4 * F1 + 2 * F2; lo = fr + 4 * F1 + 3 * F2; fl = g - 4096; }
  else return;
  int l = fl & 63, ctn = fl >> 6;
  int tn = ctn & 7, c = ctn >> 3;
  int n = tn * 16 + (l & 15);
  int kb = c * 32 + (l >> 4) * 8;
  unsigned h8[8], l8[8];
  #pragma unroll
  for (int j = 0; j < 8; j++) {
    int k = kb + j;
    float v = (k < K) ? W[(size_t)k * 128 + n] : 0.f;
    unsigned short hh = f2bf(v);
    h8[j] = hh;
    l8[j] = f2bf(v - bf2f(hh));
  }
  uint4 hv = make_uint4(h8[0] | (h8[1] << 16), h8[2] | (h8[3] << 16),
                        h8[4] | (h8[5] << 16), h8[6] | (h8[7] << 16));
  uint4 lv = make_uint4(l8[0] | (l8[1] << 16), l8[2] | (l8[3] << 16),
                        l8[4] | (l8[5] << 16), l8[6] | (l8[7] << 16));
  *(uint4*)(hi + (size_t)fl * 8) = hv;
  *(uint4*)(lo + (size_t)fl * 8) = lv;
}

// ---------------- hierarchical scan over (cnt[n]+1), 3 phases ---------------
__global__ __launch_bounds__(256) void k_scan1(const int* __restrict__ cnt,
                                               int* __restrict__ bsum) {
  __shared__ int red[256];
  int b = blockIdx.x, t = threadIdx.x;
  int beg = b * SCAN_CHUNK;
  int end = beg + SCAN_CHUNK; if (end > N_NODES) end = N_NODES;
  int s = 0;
  for (int i = beg + t; i < end; i += 256) s += cnt[i] + 1;
  red[t] = s;
  __syncthreads();
  for (int off = 128; off > 0; off >>= 1) {
    if (t < off) red[t] += red[t + off];
    __syncthreads();
  }
  if (t == 0) bsum[b] = red[0];
}

__global__ __launch_bounds__(256) void k_scan2(int* __restrict__ bsum) {
  __shared__ int sh[256];
  int t = threadIdx.x;
  sh[t] = bsum[t];
  __syncthreads();
  for (int off = 1; off < 256; off <<= 1) {
    int v = (t >= off) ? sh[t - off] : 0;
    __syncthreads();
    sh[t] += v;
    __syncthreads();
  }
  bsum[t] = (t > 0) ? sh[t - 1] : 0;  // exclusive
}

__global__ __launch_bounds__(256) void k_scan3(const int* __restrict__ cnt,
                                               const int* __restrict__ bsum,
                                               int* __restrict__ indptr,
                                               int* __restrict__ cursor) {
  __shared__ int sh[256];
  __shared__ int carry;
  int b = blockIdx.x, t = threadIdx.x;
  int beg = b * SCAN_CHUNK;
  int end = beg + SCAN_CHUNK; if (end > N_NODES) end = N_NODES;
  if (t == 0) carry = bsum[b];
  __syncthreads();
  for (int base = beg; base < end; base += 256) {
    int i = base + t;
    int v = (i < end) ? cnt[i] + 1 : 0;
    sh[t] = v;
    __syncthreads();
    for (int off = 1; off < 256; off <<= 1) {
      int u = (t >= off) ? sh[t - off] : 0;
      __syncthreads();
      sh[t] += u;
      __syncthreads();
    }
    int excl = sh[t] - v;
    if (i < end) {
      int val = carry + excl;
      indptr[i] = val;
      cursor[i] = val;
    }
    __syncthreads();
    if (t == 255) carry += sh[255];
    __syncthreads();
  }
  if (b == 0 && t == 0) indptr[N_NODES] = N_EDGES + N_NODES;
}

// ---------------- CSR fill: ordinary edges into slots [beg, end-1) ----------
__global__ void k_fill(const int* __restrict__ srcA,
                       const int* __restrict__ dst,
                       const float* __restrict__ eattr,
                       int* __restrict__ cursor,
                       int4* __restrict__ scode) {
  int e = blockIdx.x * blockDim.x + threadIdx.x;
  if (e >= N_EDGES) return;
  const float* r = eattr + (size_t)e * 5;
  int bi = (int)r[0];
  float ec = r[1];
  int combo = (int)r[2] + 2 * (int)r[3] + 4 * (int)r[4];
  int meta = bi | (combo << 5);
  int d = dst[e];
  int p = atomicAdd(&cursor[d], 1);
  scode[p] = make_int4(srcA[e], meta, __float_as_int(ec), 0);
}

// ---------------- MFMA dual GEMM: xl/xr = A @ {Wl,Wr} + {bl,br} -------------
// One wave per 16-row strip, no LDS/sync. Split-bf16 (3 MFMA) for fp32-class
// accuracy. B-frags read directly from prepped L2-resident arrays.
template <int KPAD>
__global__ __launch_bounds__(256) void k_gemm2m(const float* __restrict__ A,
                                                const unsigned short* __restrict__ WhiL,
                                                const unsigned short* __restrict__ WloL,
                                                const unsigned short* __restrict__ WhiR,
                                                const unsigned short* __restrict__ WloR,
                                                const float* __restrict__ bl_,
                                                const float* __restrict__ br_,
                                                float* __restrict__ outl,
                                                float* __restrict__ outr) {
  const int tw = blockIdx.x * 4 + (threadIdx.x >> 6);
  if (tw >= N_NODES / 16) return;  // 6250 wave-tiles
  const int lane = threadIdx.x & 63;
  const int ml = lane & 15, q = lane >> 4;
  const int m0 = tw * 16;
  f32x4 accL[8], accR[8];
  #pragma unroll
  for (int t = 0; t < 8; t++) {
    accL[t] = (f32x4){0.f, 0.f, 0.f, 0.f};
    accR[t] = (f32x4){0.f, 0.f, 0.f, 0.f};
  }
  const float* arow = A + (size_t)(m0 + ml) * KPAD + q * 8;
  constexpr int NC = KPAD / 32;
  #pragma unroll
  for (int c = 0; c < NC; c++) {
    float4 a0 = *(const float4*)(arow + c * 32);
    float4 a1 = *(const float4*)(arow + c * 32 + 4);
    float av[8] = {a0.x, a0.y, a0.z, a0.w, a1.x, a1.y, a1.z, a1.w};
    bf16x8 ahi, alo;
    #pragma unroll
    for (int j = 0; j < 8; j++) {
      unsigned short hh = f2bf(av[j]);
      ahi[j] = (short)hh;
      alo[j] = (short)f2bf(av[j] - bf2f(hh));
    }
    #pragma unroll
    for (int t = 0; t < 8; t++) {
      size_t fo = ((size_t)(c * 8 + t) * 64 + lane) * 8;
      bf16x8 bhL = *(const bf16x8*)(WhiL + fo);
      bf16x8 blL = *(const bf16x8*)(WloL + fo);
      bf16x8 bhR = *(const bf16x8*)(WhiR + fo);
      bf16x8 blR = *(const bf16x8*)(WloR + fo);
      accL[t] = __builtin_amdgcn_mfma_f32_16x16x32_bf16(ahi, bhL, accL[t], 0, 0, 0);
      accL[t] = __builtin_amdgcn_mfma_f32_16x16x32_bf16(alo, bhL, accL[t], 0, 0, 0);
      accL[t] = __builtin_amdgcn_mfma_f32_16x16x32_bf16(ahi, blL, accL[t], 0, 0, 0);
      accR[t] = __builtin_amdgcn_mfma_f32_16x16x32_bf16(ahi, bhR, accR[t], 0, 0, 0);
      accR[t] = __builtin_amdgcn_mfma_f32_16x16x32_bf16(alo, bhR, accR[t], 0, 0, 0);
      accR[t] = __builtin_amdgcn_mfma_f32_16x16x32_bf16(ahi, blR, accR[t], 0, 0, 0);
    }
  }
  // epilogue: C/D layout col=lane&15, row=quad*4+reg
  #pragma unroll
  for (int t = 0; t < 8; t++) {
    int n = t * 16 + ml;
    float bL = bl_[n], bR = br_[n];
    #pragma unroll
    for (int r = 0; r < 4; r++) {
      int row = m0 + q * 4 + r;
      outl[(size_t)row * 128 + n] = accL[t][r] + bL;
      outr[(size_t)row * 128 + n] = accR[t][r] + bR;
    }
  }
}

// ---------------- GATv2 edge pass: wave/node, 4-edge batched reductions -----
__global__ __launch_bounds__(256) void k_gat(const float* __restrict__ xl,
                                             const float* __restrict__ xr,
                                             const int* __restrict__ indptr,
                                             const int4* __restrict__ scode,
                                             const float* __restrict__ tabs,
                                             const float* __restrict__ att,
                                             const float* __restrict__ bias,
                                             float* __restrict__ hout) {
  int wid = (blockIdx.x * 256 + threadIdx.x) >> 6;
  int nw = (gridDim.x * 256) >> 6;
  int lane = threadIdx.x & 63;
  int c = lane * 2;
  const float* T1 = tabs;             // 22 x 128
  const float* T2 = tabs + 22 * 128;  // 8 x 128
  float v0 = tabs[30 * 128 + c], v1 = tabs[30 * 128 + c + 1];
  float att0 = att[c], att1 = att[c + 1];
  float b0 = bias[c], b1 = bias[c + 1];
  wid = __builtin_amdgcn_readfirstlane(wid);
  for (int n = wid; n < N_NODES; n += nw) {
    int beg = indptr[n], end1 = indptr[n + 1] - 1;  // end1 = self-loop slot
    float2 xrv = *(const float2*)(xr + (size_t)n * 128 + c);
    float amax = -1e30f, denom = 0.f, acc0 = 0.f, acc1 = 0.f;
    float els0 = 0.f, els1 = 0.f;
    for (int j = beg; j < end1; j += 4) {
      int4 sc4[4]; float2 xlv[4]; float tt[4], el0[4], el1[4];
      #pragma unroll
      for (int u = 0; u < 4; u++) {
        int jj = (j + u < end1) ? j + u : end1 - 1;
        sc4[u] = scode[jj];
      }
      #pragma unroll
      for (int u = 0; u < 4; u++)
        xlv[u] = *(const float2*)(xl + (size_t)sc4[u].x * 128 + c);
      #pragma unroll
      for (int u = 0; u < 4; u++) {
        int meta = sc4[u].y;
        int bi = meta & 31, combo = (meta >> 5) & 7;
        float ec = __int_as_float(sc4[u].z);
        float2 t1v = *(const float2*)(T1 + bi * 128 + c);
        float2 t2v = *(const float2*)(T2 + combo * 128 + c);
        el0[u] = t1v.x + t2v.x + ec * v0;
        el1[u] = t1v.y + t2v.y + ec * v1;
        float m0 = xlv[u].x + xrv.x + el0[u];
        float m1 = xlv[u].y + xrv.y + el1[u];
        float l0 = m0 > 0.f ? m0 : 0.2f * m0;
        float l1 = m1 > 0.f ? m1 : 0.2f * m1;
        tt[u] = l0 * att0 + l1 * att1;
      }
      #pragma unroll
      for (int off = 1; off < 64; off <<= 1) {
        tt[0] += __shfl_xor(tt[0], off, 64);
        tt[1] += __shfl_xor(tt[1], off, 64);
        tt[2] += __shfl_xor(tt[2], off, 64);
        tt[3] += __shfl_xor(tt[3], off, 64);
      }
      #pragma unroll
      for (int u = 0; u < 4; u++) {
        bool valid = (j + u < end1);  // wave-uniform
        if (!valid) tt[u] = -1e30f;
        els0 += valid ? el0[u] : 0.f;
        els1 += valid ? el1[u] : 0.f;
      }
      float bm = fmaxf(fmaxf(tt[0], tt[1]), fmaxf(tt[2], tt[3]));
      float nm = fmaxf(amax, bm);
      float sc = __expf(amax - nm);
      denom *= sc; acc0 *= sc; acc1 *= sc;
      #pragma unroll
      for (int u = 0; u < 4; u++) {
        float ex = __expf(tt[u] - nm);
        denom += ex;
        acc0 += ex * xlv[u].x;
        acc1 += ex * xlv[u].y;
      }
      amax = nm;
    }
    // self-loop (always present, processed last)
    int cntn = end1 - beg;
    float inv_cnt = 1.0f / (float)(cntn > 0 ? cntn : 1);
    float elL0 = els0 * inv_cnt, elL1 = els1 * inv_cnt;
    float2 xln = *(const float2*)(xl + (size_t)n * 128 + c);
    float m0 = xln.x + xrv.x + elL0;
    float m1 = xln.y + xrv.y + elL1;
    float l0 = m0 > 0.f ? m0 : 0.2f * m0;
    float l1 = m1 > 0.f ? m1 : 0.2f * m1;
    float ts = l0 * att0 + l1 * att1;
    #pragma unroll
    for (int off = 1; off < 64; off <<= 1) ts += __shfl_xor(ts, off, 64);
    float nm = fmaxf(amax, ts);
    float sc = __expf(amax - nm);
    float ex = __expf(ts - nm);
    denom = denom * sc + ex;
    acc0 = acc0 * sc + ex * xln.x;
    acc1 = acc1 * sc + ex * xln.y;
    float invd = 1.0f / denom;
    float o0 = acc0 * invd + b0;
    float o1 = acc1 * invd + b1;
    float2 o; o.x = o0 > 0.f ? o0 : 0.f; o.y = o1 > 0.f ? o1 : 0.f;
    *(float2*)(hout + (size_t)n * 128 + c) = o;
  }
}

// ---------------- readout: global max pool over 20 contiguous nodes --------
__global__ void k_readout(const float* __restrict__ h, float* __restrict__ out) {
  int wid = (blockIdx.x * blockDim.x + threadIdx.x) >> 6;
  int lane = threadIdx.x & 63;
  if (wid >= N_GRAPHS) return;
  int c = lane * 2;
  float m0 = -1e30f, m1 = -1e30f;
  for (int i = 0; i < NPG; i++) {
    const float2 v = *(const float2*)(h + ((size_t)(wid * NPG + i)) * 128 + c);
    m0 = fmaxf(m0, v.x);
    m1 = fmaxf(m1, v.y);
  }
  float2 o; o.x = m0; o.y = m1;
  *(float2*)(out + (size_t)wid * 128 + c) = o;
}

extern "C" void kernel_launch(void* const* d_in, const int* in_sizes, int n_in,
                              void* d_out, int out_size, void* d_ws, size_t ws_size,
                              hipStream_t stream) {
  (void)in_sizes; (void)n_in; (void)out_size; (void)ws_size;
  const float* x        = (const float*)d_in[0];
  const int*   eindex   = (const int*)d_in[1];
  const float* eattr    = (const float*)d_in[2];
  const float* atom_emb = (const float*)d_in[4];
  const float* bond_emb = (const float*)d_in[5];
  const float* bool_emb = (const float*)d_in[6];
  const float* Wn   = (const float*)d_in[7];
  const float* bn   = (const float*)d_in[8];
  const float* We   = (const float*)d_in[9];
  const float* be   = (const float*)d_in[10];
  const float* Wl1  = (const float*)d_in[11];
  const float* bl1  = (const float*)d_in[12];
  const float* Wr1  = (const float*)d_in[13];
  const float* br1  = (const float*)d_in[14];
  const float* Wedge1 = (const float*)d_in[15];
  const float* att1 = (const float*)d_in[16];
  const float* bias1 = (const float*)d_in[17];
  const float* Wl2  = (const float*)d_in[18];
  const float* bl2  = (const float*)d_in[19];
  const float* Wr2  = (const float*)d_in[20];
  const float* br2  = (const float*)d_in[21];
  const float* Wedge2 = (const float*)d_in[22];
  const float* att2 = (const float*)d_in[23];
  const float* bias2 = (const float*)d_in[24];

  const int* srcA = eindex;
  const int* dstA = eindex + N_EDGES;

  char* p = (char*)d_ws;
  auto alloc = [&](size_t bytes) {
    char* r = p;
    p += (bytes + 255) & ~(size_t)255;
    return r;
  };
  float* h0     = (float*)alloc((size_t)N_NODES * 64 * 4);
  float* h      = (float*)alloc((size_t)N_NODES * 128 * 4);
  float* xl     = (float*)alloc((size_t)N_NODES * 128 * 4);
  float* xrb    = (float*)alloc((size_t)N_NODES * 128 * 4);
  int*   cnt    = (int*)alloc((size_t)N_NODES * 4);
  int*   indptr = (int*)alloc((size_t)(N_NODES + 1) * 4);
  int*   cursor = (int*)alloc((size_t)N_NODES * 4);
  int4*  scode  = (int4*)alloc((size_t)(N_EDGES + N_NODES) * 16);
  float* tabs   = (float*)alloc((size_t)2 * TAB_STRIDE * 4);
  unsigned short* wfrag = (unsigned short*)alloc((size_t)(4 * F1 + 4 * F2) * 2);
  int*   bsum   = (int*)alloc((size_t)SCAN_NB * 4);

  hipMemsetAsync(cnt, 0, (size_t)N_NODES * 4, stream);

  k_encode_nodes<<<(N_NODES + 255) / 256, 256, 0, stream>>>(x, atom_emb, bool_emb, Wn, bn, h0);
  k_hist<<<(N_EDGES + 255) / 256, 256, 0, stream>>>(dstA, cnt);
  k_build_tabs<<<1, 256, 0, stream>>>(Wedge1, Wedge2, bond_emb, bool_emb, We, be, tabs);
  k_prep<<<24, 256, 0, stream>>>(Wl1, Wr1, Wl2, Wr2, wfrag);
  k_scan1<<<SCAN_NB, 256, 0, stream>>>(cnt, bsum);
  k_scan2<<<1, 256, 0, stream>>>(bsum);
  k_scan3<<<SCAN_NB, 256, 0, stream>>>(cnt, bsum, indptr, cursor);
  k_fill<<<(N_EDGES + 255) / 256, 256, 0, stream>>>(srcA, dstA, eattr, cursor, scode);

  const unsigned short* f_l1h = wfrag;
  const unsigned short* f_l1l = wfrag + F1;
  const unsigned short* f_r1h = wfrag + 2 * F1;
  const unsigned short* f_r1l = wfrag + 3 * F1;
  const unsigned short* f_l2h = wfrag + 4 * F1;
  const unsigned short* f_l2l = wfrag + 4 * F1 + F2;
  const unsigned short* f_r2h = wfrag + 4 * F1 + 2 * F2;
  const unsigned short* f_r2l = wfrag + 4 * F1 + 3 * F2;

  const int GB2 = (N_NODES / 16 + 3) / 4;  // 1563 blocks of 4 wave-tiles

  // layer 1 (K=52 zero-padded to 64)
  k_gemm2m<64><<<GB2, 256, 0, stream>>>(h0, f_l1h, f_l1l, f_r1h, f_r1l, bl1, br1, xl, xrb);
  k_gat<<<2048, 256, 0, stream>>>(xl, xrb, indptr, scode, tabs, att1, bias1, h);

  // layer 2 (K=128)
  k_gemm2m<128><<<GB2, 256, 0, stream>>>(h, f_l2h, f_l2l, f_r2h, f_r2l, bl2, br2, xl, xrb);
  k_gat<<<2048, 256, 0, stream>>>(xl, xrb, indptr, scode, tabs + TAB_STRIDE, att2, bias2, h);

  // layer 3 (shared weights with layer 2)
  k_gemm2m<128><<<GB2, 256, 0, stream>>>(h, f_l2h, f_l2l, f_r2h, f_r2l, bl2, br2, xl, xrb);
  k_gat<<<2048, 256, 0, stream>>>(xl, xrb, indptr, scode, tabs + TAB_STRIDE, att2, bias2, h);

  k_readout<<<(N_GRAPHS * 64 + 255) / 256, 256, 0, stream>>>(h, (float*)d_out);
}

// Round 9
// 532.142 us; speedup vs baseline: 6.3421x; 1.1127x over previous
//
#include <hip/hip_runtime.h>

#define N_NODES 100000
#define N_EDGES 400000
#define N_GRAPHS 5000
#define NPG 20
#define SCAN_NB 256
#define SCAN_CHUNK ((N_NODES + SCAN_NB - 1) / SCAN_NB)  // 391
#define TAB_STRIDE 3968  // 22*128 + 8*128 + 128
#define F1 8192          // ushorts per K=64 frag array (1024 frags * 8)
#define F2 16384         // ushorts per K=128 frag array (2048 frags * 8)

typedef __attribute__((ext_vector_type(8))) short bf16x8;
typedef __attribute__((ext_vector_type(4))) float f32x4;

__device__ __forceinline__ unsigned short f2bf(float f) {
  unsigned u = __float_as_uint(f);
  unsigned r = (u + 0x7FFFu + ((u >> 16) & 1u)) >> 16;
  return (unsigned short)r;
}
__device__ __forceinline__ float bf2f(unsigned short h) {
  return __uint_as_float(((unsigned)h) << 16);
}

// ---------------- node encoder: h0[N,64] (cols 52..63 zero) ----------------
__global__ void k_encode_nodes(const float* __restrict__ x,
                               const float* __restrict__ atom_emb,
                               const float* __restrict__ bool_emb,
                               const float* __restrict__ Wn,
                               const float* __restrict__ bn,
                               float* __restrict__ h0) {
  int n = blockIdx.x * blockDim.x + threadIdx.x;
  if (n >= N_NODES) return;
  const float* xr = x + (size_t)n * 14;
  float* h = h0 + (size_t)n * 64;
  int ai = (int)xr[0];
  #pragma unroll
  for (int j = 0; j < 16; j++) h[j] = atom_emb[ai * 16 + j];
  float xc[10];
  #pragma unroll
  for (int k = 0; k < 10; k++) xc[k] = xr[1 + k];
  #pragma unroll
  for (int c = 0; c < 30; c++) {
    float s = bn[c];
    #pragma unroll
    for (int k = 0; k < 10; k++) s += xc[k] * Wn[k * 30 + c];
    h[16 + c] = s;
  }
  #pragma unroll
  for (int t = 0; t < 3; t++) {
    int b = (int)xr[11 + t];
    h[46 + 2 * t]     = bool_emb[2 * b];
    h[46 + 2 * t + 1] = bool_emb[2 * b + 1];
  }
  #pragma unroll
  for (int j = 52; j < 64; j++) h[j] = 0.0f;  // zero pad for K=64 GEMM
}

// ---------------- in-degree histogram ----------------
__global__ void k_hist(const int* __restrict__ dst, int* __restrict__ cnt) {
  int e = blockIdx.x * blockDim.x + threadIdx.x;
  if (e >= N_EDGES) return;
  atomicAdd(cnt + dst[e], 1);
}

// ---------------- logit tables: elin = T1[bi] + ec*v + T2[combo] ------------
__global__ void k_build_tabs(const float* __restrict__ Wedge1,
                             const float* __restrict__ Wedge2,
                             const float* __restrict__ bond_emb,
                             const float* __restrict__ bool_emb,
                             const float* __restrict__ We,
                             const float* __restrict__ be,
                             float* __restrict__ tabs) {
  int t = threadIdx.x;
  int s = t >> 7, c = t & 127;
  const float* W = s ? Wedge2 : Wedge1;
  float* T1 = tabs + s * TAB_STRIDE;
  float* T2 = T1 + 22 * 128;
  float* v  = T1 + 30 * 128;
  for (int b = 0; b < 22; b++) {
    float acc = 0.f;
    #pragma unroll
    for (int k = 0; k < 8; k++) acc += bond_emb[b * 8 + k] * W[k * 128 + c];
    T1[b * 128 + c] = acc;
  }
  float w8 = W[8 * 128 + c], w9 = W[9 * 128 + c];
  v[c] = We[0] * w8 + We[1] * w9;
  float cst = be[0] * w8 + be[1] * w9;
  for (int combo = 0; combo < 8; combo++) {
    float acc = cst;
    #pragma unroll
    for (int tt = 0; tt < 3; tt++) {
      int bt = (combo >> tt) & 1;
      acc += bool_emb[bt * 2 + 0] * W[(10 + 2 * tt + 0) * 128 + c];
      acc += bool_emb[bt * 2 + 1] * W[(10 + 2 * tt + 1) * 128 + c];
    }
    T2[combo * 128 + c] = acc;
  }
}

// ---------------- W -> MFMA B-fragment prep (hi/lo split-bf16) --------------
__global__ __launch_bounds__(256) void k_prep(const float* __restrict__ Wl1,
                                              const float* __restrict__ Wr1,
                                              const float* __restrict__ Wl2,
                                              const float* __restrict__ Wr2,
                                              unsigned short* __restrict__ fr) {
  int g = blockIdx.x * 256 + threadIdx.x;
  const float* W; int K; unsigned short *hi, *lo; int fl;
  if (g < 1024)      { W = Wl1; K = 52;  hi = fr;                lo = fr + F1;               fl = g; }
  else if (g < 2048) { W = Wr1; K = 52;  hi = fr + 2 * F1;       lo = fr + 3 * F1;           fl = g - 1024; }
  else if (g < 4096) { W = Wl2; K = 128; hi = fr + 4 * F1;       lo = fr + 4 * F1 + F2;      fl = g - 2048; }
  else if (g < 6144) { W = Wr2; K = 128; hi = fr + 4 * F1 + 2 * F2; lo = fr + 4 * F1 + 3 * F2; fl = g - 4096; }
  else return;
  int l = fl & 63, ctn = fl >> 6;
  int tn = ctn & 7, c = ctn >> 3;
  int n = tn * 16 + (l & 15);
  int kb = c * 32 + (l >> 4) * 8;
  unsigned h8[8], l8[8];
  #pragma unroll
  for (int j = 0; j < 8; j++) {
    int k = kb + j;
    float v = (k < K) ? W[(size_t)k * 128 + n] : 0.f;
    unsigned short hh = f2bf(v);
    h8[j] = hh;
    l8[j] = f2bf(v - bf2f(hh));
  }
  uint4 hv = make_uint4(h8[0] | (h8[1] << 16), h8[2] | (h8[3] << 16),
                        h8[4] | (h8[5] << 16), h8[6] | (h8[7] << 16));
  uint4 lv = make_uint4(l8[0] | (l8[1] << 16), l8[2] | (l8[3] << 16),
                        l8[4] | (l8[5] << 16), l8[6] | (l8[7] << 16));
  *(uint4*)(hi + (size_t)fl * 8) = hv;
  *(uint4*)(lo + (size_t)fl * 8) = lv;
}

// ---------------- hierarchical scan over (cnt[n]+1), 3 phases ---------------
__global__ __launch_bounds__(256) void k_scan1(const int* __restrict__ cnt,
                                               int* __restrict__ bsum) {
  __shared__ int red[256];
  int b = blockIdx.x, t = threadIdx.x;
  int beg = b * SCAN_CHUNK;
  int end = beg + SCAN_CHUNK; if (end > N_NODES) end = N_NODES;
  int s = 0;
  for (int i = beg + t; i < end; i += 256) s += cnt[i] + 1;
  red[t] = s;
  __syncthreads();
  for (int off = 128; off > 0; off >>= 1) {
    if (t < off) red[t] += red[t + off];
    __syncthreads();
  }
  if (t == 0) bsum[b] = red[0];
}

__global__ __launch_bounds__(256) void k_scan2(int* __restrict__ bsum) {
  __shared__ int sh[256];
  int t = threadIdx.x;
  sh[t] = bsum[t];
  __syncthreads();
  for (int off = 1; off < 256; off <<= 1) {
    int v = (t >= off) ? sh[t - off] : 0;
    __syncthreads();
    sh[t] += v;
    __syncthreads();
  }
  bsum[t] = (t > 0) ? sh[t - 1] : 0;  // exclusive
}

__global__ __launch_bounds__(256) void k_scan3(const int* __restrict__ cnt,
                                               const int* __restrict__ bsum,
                                               int* __restrict__ indptr,
                                               int* __restrict__ cursor) {
  __shared__ int sh[256];
  __shared__ int carry;
  int b = blockIdx.x, t = threadIdx.x;
  int beg = b * SCAN_CHUNK;
  int end = beg + SCAN_CHUNK; if (end > N_NODES) end = N_NODES;
  if (t == 0) carry = bsum[b];
  __syncthreads();
  for (int base = beg; base < end; base += 256) {
    int i = base + t;
    int v = (i < end) ? cnt[i] + 1 : 0;
    sh[t] = v;
    __syncthreads();
    for (int off = 1; off < 256; off <<= 1) {
      int u = (t >= off) ? sh[t - off] : 0;
      __syncthreads();
      sh[t] += u;
      __syncthreads();
    }
    int excl = sh[t] - v;
    if (i < end) {
      int val = carry + excl;
      indptr[i] = val;
      cursor[i] = val;
    }
    __syncthreads();
    if (t == 255) carry += sh[255];
    __syncthreads();
  }
  if (b == 0 && t == 0) indptr[N_NODES] = N_EDGES + N_NODES;
}

// ---------------- CSR fill: ordinary edges into slots [beg, end-1) ----------
__global__ void k_fill(const int* __restrict__ srcA,
                       const int* __restrict__ dst,
                       const float* __restrict__ eattr,
                       int* __restrict__ cursor,
                       int4* __restrict__ scode) {
  int e = blockIdx.x * blockDim.x + threadIdx.x;
  if (e >= N_EDGES) return;
  const float* r = eattr + (size_t)e * 5;
  int bi = (int)r[0];
  float ec = r[1];
  int combo = (int)r[2] + 2 * (int)r[3] + 4 * (int)r[4];
  int meta = bi | (combo << 5);
  int d = dst[e];
  int p = atomicAdd(&cursor[d], 1);
  scode[p] = make_int4(srcA[e], meta, __float_as_int(ec), 0);
}

// ---------------- MFMA dual GEMM: xl/xr = A @ {Wl,Wr} + {bl,br} -------------
template <int KPAD>
__global__ __launch_bounds__(256) void k_gemm2m(const float* __restrict__ A,
                                                const unsigned short* __restrict__ WhiL,
                                                const unsigned short* __restrict__ WloL,
                                                const unsigned short* __restrict__ WhiR,
                                                const unsigned short* __restrict__ WloR,
                                                const float* __restrict__ bl_,
                                                const float* __restrict__ br_,
                                                float* __restrict__ outl,
                                                float* __restrict__ outr) {
  const int tw = blockIdx.x * 4 + (threadIdx.x >> 6);
  if (tw >= N_NODES / 16) return;  // 6250 wave-tiles
  const int lane = threadIdx.x & 63;
  const int ml = lane & 15, q = lane >> 4;
  const int m0 = tw * 16;
  f32x4 accL[8], accR[8];
  #pragma unroll
  for (int t = 0; t < 8; t++) {
    accL[t] = (f32x4){0.f, 0.f, 0.f, 0.f};
    accR[t] = (f32x4){0.f, 0.f, 0.f, 0.f};
  }
  const float* arow = A + (size_t)(m0 + ml) * KPAD + q * 8;
  constexpr int NC = KPAD / 32;
  #pragma unroll
  for (int c = 0; c < NC; c++) {
    float4 a0 = *(const float4*)(arow + c * 32);
    float4 a1 = *(const float4*)(arow + c * 32 + 4);
    float av[8] = {a0.x, a0.y, a0.z, a0.w, a1.x, a1.y, a1.z, a1.w};
    bf16x8 ahi, alo;
    #pragma unroll
    for (int j = 0; j < 8; j++) {
      unsigned short hh = f2bf(av[j]);
      ahi[j] = (short)hh;
      alo[j] = (short)f2bf(av[j] - bf2f(hh));
    }
    #pragma unroll
    for (int t = 0; t < 8; t++) {
      size_t fo = ((size_t)(c * 8 + t) * 64 + lane) * 8;
      bf16x8 bhL = *(const bf16x8*)(WhiL + fo);
      bf16x8 blL = *(const bf16x8*)(WloL + fo);
      bf16x8 bhR = *(const bf16x8*)(WhiR + fo);
      bf16x8 blR = *(const bf16x8*)(WloR + fo);
      accL[t] = __builtin_amdgcn_mfma_f32_16x16x32_bf16(ahi, bhL, accL[t], 0, 0, 0);
      accL[t] = __builtin_amdgcn_mfma_f32_16x16x32_bf16(alo, bhL, accL[t], 0, 0, 0);
      accL[t] = __builtin_amdgcn_mfma_f32_16x16x32_bf16(ahi, blL, accL[t], 0, 0, 0);
      accR[t] = __builtin_amdgcn_mfma_f32_16x16x32_bf16(ahi, bhR, accR[t], 0, 0, 0);
      accR[t] = __builtin_amdgcn_mfma_f32_16x16x32_bf16(alo, bhR, accR[t], 0, 0, 0);
      accR[t] = __builtin_amdgcn_mfma_f32_16x16x32_bf16(ahi, blR, accR[t], 0, 0, 0);
    }
  }
  // epilogue: C/D layout col=lane&15, row=quad*4+reg
  #pragma unroll
  for (int t = 0; t < 8; t++) {
    int n = t * 16 + ml;
    float bL = bl_[n], bR = br_[n];
    #pragma unroll
    for (int r = 0; r < 4; r++) {
      int row = m0 + q * 4 + r;
      outl[(size_t)row * 128 + n] = accL[t][r] + bL;
      outr[(size_t)row * 128 + n] = accR[t][r] + bR;
    }
  }
}

// ---------------- GATv2 edge pass: 32 lanes/node (2 nodes per wave) ---------
// Lane handles 4 channels; half-wave reduction = 5 shuffle steps; ordinary
// edges in [beg,end-1), self-loop last via elin mean. NOTE: empty halves
// (end1==beg) run lock-step iterations with the sibling half — every use of
// scode data is clamped (the reserved self-loop slot is never written and
// the harness poisons d_ws, so sc4[u].x must NEVER form an address unless
// the slot is valid).
__global__ __launch_bounds__(256) void k_gat(const float* __restrict__ xl,
                                             const float* __restrict__ xr,
                                             const int* __restrict__ indptr,
                                             const int4* __restrict__ scode,
                                             const float* __restrict__ tabs,
                                             const float* __restrict__ att,
                                             const float* __restrict__ bias,
                                             float* __restrict__ hout) {
  int wid = (blockIdx.x * 256 + threadIdx.x) >> 6;
  int nw = (gridDim.x * 256) >> 6;
  int lane = threadIdx.x & 63;
  int half = lane >> 5;
  int c = (lane & 31) * 4;  // 4 channels per lane
  const float* T1 = tabs;             // 22 x 128
  const float* T2 = tabs + 22 * 128;  // 8 x 128
  float4 v4 = *(const float4*)(tabs + 30 * 128 + c);
  float4 a4 = *(const float4*)(att + c);
  float4 b4 = *(const float4*)(bias + c);
  wid = __builtin_amdgcn_readfirstlane(wid);
  for (int nb = wid * 2; nb < N_NODES; nb += nw * 2) {
    int n = nb + half;  // N_NODES even -> always valid
    int beg = indptr[n], end1 = indptr[n + 1] - 1;  // end1 = self-loop slot
    int last = (end1 > beg) ? end1 - 1 : beg;       // clamp (may be unwritten!)
    float4 xrv = *(const float4*)(xr + (size_t)n * 128 + c);
    float amax = -1e30f, denom = 0.f;
    float4 acc = make_float4(0.f, 0.f, 0.f, 0.f);
    float4 els = make_float4(0.f, 0.f, 0.f, 0.f);
    int my_it = (end1 - beg + 3) >> 2;
    int ot = __shfl_xor(my_it, 32, 64);
    int iters = my_it > ot ? my_it : ot;  // wave-uniform
    for (int it = 0; it < iters; it++) {
      int j = beg + it * 4;
      int4 sc4[4]; float4 xlv[4]; float tt[4]; float4 el[4];
      bool val[4];
      #pragma unroll
      for (int u = 0; u < 4; u++) {
        val[u] = (j + u < end1);  // uniform within half
        int jj = val[u] ? j + u : last;
        sc4[u] = scode[jj];
      }
      #pragma unroll
      for (int u = 0; u < 4; u++) {
        int s = val[u] ? sc4[u].x : n;  // NEVER use poison as an address
        xlv[u] = *(const float4*)(xl + (size_t)s * 128 + c);
      }
      #pragma unroll
      for (int u = 0; u < 4; u++) {
        int meta = val[u] ? sc4[u].y : 0;  // clamp table indices too
        int bi = meta & 31, combo = (meta >> 5) & 7;
        float ec = val[u] ? __int_as_float(sc4[u].z) : 0.f;
        float4 t1v = *(const float4*)(T1 + bi * 128 + c);
        float4 t2v = *(const float4*)(T2 + combo * 128 + c);
        el[u].x = t1v.x + t2v.x + ec * v4.x;
        el[u].y = t1v.y + t2v.y + ec * v4.y;
        el[u].z = t1v.z + t2v.z + ec * v4.z;
        el[u].w = t1v.w + t2v.w + ec * v4.w;
        float m0 = xlv[u].x + xrv.x + el[u].x;
        float m1 = xlv[u].y + xrv.y + el[u].y;
        float m2 = xlv[u].z + xrv.z + el[u].z;
        float m3 = xlv[u].w + xrv.w + el[u].w;
        float l0 = m0 > 0.f ? m0 : 0.2f * m0;
        float l1 = m1 > 0.f ? m1 : 0.2f * m1;
        float l2 = m2 > 0.f ? m2 : 0.2f * m2;
        float l3 = m3 > 0.f ? m3 : 0.2f * m3;
        tt[u] = l0 * a4.x + l1 * a4.y + l2 * a4.z + l3 * a4.w;
      }
      // 8 independent half-wave reduction chains (4 per node), 5 steps
      #pragma unroll
      for (int off = 1; off < 32; off <<= 1) {
        tt[0] += __shfl_xor(tt[0], off, 64);
        tt[1] += __shfl_xor(tt[1], off, 64);
        tt[2] += __shfl_xor(tt[2], off, 64);
        tt[3] += __shfl_xor(tt[3], off, 64);
      }
      #pragma unroll
      for (int u = 0; u < 4; u++) {
        if (!val[u]) tt[u] = -1e30f;
        els.x += val[u] ? el[u].x : 0.f;
        els.y += val[u] ? el[u].y : 0.f;
        els.z += val[u] ? el[u].z : 0.f;
        els.w += val[u] ? el[u].w : 0.f;
      }
      float bm = fmaxf(fmaxf(tt[0], tt[1]), fmaxf(tt[2], tt[3]));
      float nm = fmaxf(amax, bm);
      float sc = __expf(amax - nm);
      denom *= sc;
      acc.x *= sc; acc.y *= sc; acc.z *= sc; acc.w *= sc;
      #pragma unroll
      for (int u = 0; u < 4; u++) {
        float ex = val[u] ? __expf(tt[u] - nm) : 0.f;
        denom += ex;
        acc.x += ex * xlv[u].x;
        acc.y += ex * xlv[u].y;
        acc.z += ex * xlv[u].z;
        acc.w += ex * xlv[u].w;
      }
      amax = nm;
    }
    // self-loop (always present, processed last)
    int cntn = end1 - beg;
    float inv_cnt = 1.0f / (float)(cntn > 0 ? cntn : 1);
    float4 xln = *(const float4*)(xl + (size_t)n * 128 + c);
    float m0 = xln.x + xrv.x + els.x * inv_cnt;
    float m1 = xln.y + xrv.y + els.y * inv_cnt;
    float m2 = xln.z + xrv.z + els.z * inv_cnt;
    float m3 = xln.w + xrv.w + els.w * inv_cnt;
    float l0 = m0 > 0.f ? m0 : 0.2f * m0;
    float l1 = m1 > 0.f ? m1 : 0.2f * m1;
    float l2 = m2 > 0.f ? m2 : 0.2f * m2;
    float l3 = m3 > 0.f ? m3 : 0.2f * m3;
    float ts = l0 * a4.x + l1 * a4.y + l2 * a4.z + l3 * a4.w;
    #pragma unroll
    for (int off = 1; off < 32; off <<= 1) ts += __shfl_xor(ts, off, 64);
    float nm = fmaxf(amax, ts);
    float sc = __expf(amax - nm);
    float ex = __expf(ts - nm);
    denom = denom * sc + ex;
    acc.x = acc.x * sc + ex * xln.x;
    acc.y = acc.y * sc + ex * xln.y;
    acc.z = acc.z * sc + ex * xln.z;
    acc.w = acc.w * sc + ex * xln.w;
    float invd = 1.0f / denom;
    float o0 = acc.x * invd + b4.x;
    float o1 = acc.y * invd + b4.y;
    float o2 = acc.z * invd + b4.z;
    float o3 = acc.w * invd + b4.w;
    float4 o = make_float4(o0 > 0.f ? o0 : 0.f, o1 > 0.f ? o1 : 0.f,
                           o2 > 0.f ? o2 : 0.f, o3 > 0.f ? o3 : 0.f);
    *(float4*)(hout + (size_t)n * 128 + c) = o;
  }
}

// ---------------- readout: global max pool over 20 contiguous nodes --------
__global__ void k_readout(const float* __restrict__ h, float* __restrict__ out) {
  int wid = (blockIdx.x * blockDim.x + threadIdx.x) >> 6;
  int lane = threadIdx.x & 63;
  if (wid >= N_GRAPHS) return;
  int c = lane * 2;
  float m0 = -1e30f, m1 = -1e30f;
  for (int i = 0; i < NPG; i++) {
    const float2 v = *(const float2*)(h + ((size_t)(wid * NPG + i)) * 128 + c);
    m0 = fmaxf(m0, v.x);
    m1 = fmaxf(m1, v.y);
  }
  float2 o; o.x = m0; o.y = m1;
  *(float2*)(out + (size_t)wid * 128 + c) = o;
}

extern "C" void kernel_launch(void* const* d_in, const int* in_sizes, int n_in,
                              void* d_out, int out_size, void* d_ws, size_t ws_size,
                              hipStream_t stream) {
  (void)in_sizes; (void)n_in; (void)out_size; (void)ws_size;
  const float* x        = (const float*)d_in[0];
  const int*   eindex   = (const int*)d_in[1];
  const float* eattr    = (const float*)d_in[2];
  const float* atom_emb = (const float*)d_in[4];
  const float* bond_emb = (const float*)d_in[5];
  const float* bool_emb = (const float*)d_in[6];
  const float* Wn   = (const float*)d_in[7];
  const float* bn   = (const float*)d_in[8];
  const float* We   = (const float*)d_in[9];
  const float* be   = (const float*)d_in[10];
  const float* Wl1  = (const float*)d_in[11];
  const float* bl1  = (const float*)d_in[12];
  const float* Wr1  = (const float*)d_in[13];
  const float* br1  = (const float*)d_in[14];
  const float* Wedge1 = (const float*)d_in[15];
  const float* att1 = (const float*)d_in[16];
  const float* bias1 = (const float*)d_in[17];
  const float* Wl2  = (const float*)d_in[18];
  const float* bl2  = (const float*)d_in[19];
  const float* Wr2  = (const float*)d_in[20];
  const float* br2  = (const float*)d_in[21];
  const float* Wedge2 = (const float*)d_in[22];
  const float* att2 = (const float*)d_in[23];
  const float* bias2 = (const float*)d_in[24];

  const int* srcA = eindex;
  const int* dstA = eindex + N_EDGES;

  char* p = (char*)d_ws;
  auto alloc = [&](size_t bytes) {
    char* r = p;
    p += (bytes + 255) & ~(size_t)255;
    return r;
  };
  float* h0     = (float*)alloc((size_t)N_NODES * 64 * 4);
  float* h      = (float*)alloc((size_t)N_NODES * 128 * 4);
  float* xl     = (float*)alloc((size_t)N_NODES * 128 * 4);
  float* xrb    = (float*)alloc((size_t)N_NODES * 128 * 4);
  int*   cnt    = (int*)alloc((size_t)N_NODES * 4);
  int*   indptr = (int*)alloc((size_t)(N_NODES + 1) * 4);
  int*   cursor = (int*)alloc((size_t)N_NODES * 4);
  int4*  scode  = (int4*)alloc((size_t)(N_EDGES + N_NODES) * 16);
  float* tabs   = (float*)alloc((size_t)2 * TAB_STRIDE * 4);
  unsigned short* wfrag = (unsigned short*)alloc((size_t)(4 * F1 + 4 * F2) * 2);
  int*   bsum   = (int*)alloc((size_t)SCAN_NB * 4);

  hipMemsetAsync(cnt, 0, (size_t)N_NODES * 4, stream);

  k_encode_nodes<<<(N_NODES + 255) / 256, 256, 0, stream>>>(x, atom_emb, bool_emb, Wn, bn, h0);
  k_hist<<<(N_EDGES + 255) / 256, 256, 0, stream>>>(dstA, cnt);
  k_build_tabs<<<1, 256, 0, stream>>>(Wedge1, Wedge2, bond_emb, bool_emb, We, be, tabs);
  k_prep<<<24, 256, 0, stream>>>(Wl1, Wr1, Wl2, Wr2, wfrag);
  k_scan1<<<SCAN_NB, 256, 0, stream>>>(cnt, bsum);
  k_scan2<<<1, 256, 0, stream>>>(bsum);
  k_scan3<<<SCAN_NB, 256, 0, stream>>>(cnt, bsum, indptr, cursor);
  k_fill<<<(N_EDGES + 255) / 256, 256, 0, stream>>>(srcA, dstA, eattr, cursor, scode);

  const unsigned short* f_l1h = wfrag;
  const unsigned short* f_l1l = wfrag + F1;
  const unsigned short* f_r1h = wfrag + 2 * F1;
  const unsigned short* f_r1l = wfrag + 3 * F1;
  const unsigned short* f_l2h = wfrag + 4 * F1;
  const unsigned short* f_l2l = wfrag + 4 * F1 + F2;
  const unsigned short* f_r2h = wfrag + 4 * F1 + 2 * F2;
  const unsigned short* f_r2l = wfrag + 4 * F1 + 3 * F2;

  const int GB2 = (N_NODES / 16 + 3) / 4;  // 1563 blocks of 4 wave-tiles

  // layer 1 (K=52 zero-padded to 64)
  k_gemm2m<64><<<GB2, 256, 0, stream>>>(h0, f_l1h, f_l1l, f_r1h, f_r1l, bl1, br1, xl, xrb);
  k_gat<<<2048, 256, 0, stream>>>(xl, xrb, indptr, scode, tabs, att1, bias1, h);

  // layer 2 (K=128)
  k_gemm2m<128><<<GB2, 256, 0, stream>>>(h, f_l2h, f_l2l, f_r2h, f_r2l, bl2, br2, xl, xrb);
  k_gat<<<2048, 256, 0, stream>>>(xl, xrb, indptr, scode, tabs + TAB_STRIDE, att2, bias2, h);

  // layer 3 (shared weights with layer 2)
  k_gemm2m<128><<<GB2, 256, 0, stream>>>(h, f_l2h, f_l2l, f_r2h, f_r2l, bl2, br2, xl, xrb);
  k_gat<<<2048, 256, 0, stream>>>(xl, xrb, indptr, scode, tabs + TAB_STRIDE, att2, bias2, h);

  k_readout<<<(N_GRAPHS * 64 + 255) / 256, 256, 0, stream>>>(h, (float*)d_out);
}

// Round 10
// 510.443 us; speedup vs baseline: 6.6117x; 1.0425x over previous
//
#include <hip/hip_runtime.h>

#define N_NODES 100000
#define N_EDGES 400000
#define N_GRAPHS 5000
#define NPG 20
#define SCAN_NB 256
#define SCAN_CHUNK ((N_NODES + SCAN_NB - 1) / SCAN_NB)  // 391
#define TAB_STRIDE (256 * 128 + 128)  // T12[256][128] + v[128]
#define F1 16384  // ushorts per K=64 frag array (1024 frags * 16: hi8|lo8)
#define F2 32768  // ushorts per K=128 frag array (2048 frags * 16)

typedef __attribute__((ext_vector_type(8))) short bf16x8;
typedef __attribute__((ext_vector_type(4))) float f32x4;

__device__ __forceinline__ unsigned short f2bf(float f) {
  unsigned u = __float_as_uint(f);
  unsigned r = (u + 0x7FFFu + ((u >> 16) & 1u)) >> 16;
  return (unsigned short)r;
}
__device__ __forceinline__ float bf2f(unsigned short h) {
  return __uint_as_float(((unsigned)h) << 16);
}

// ---------------- node encoder: h0[N,64] (cols 52..63 zero) ----------------
__global__ void k_encode_nodes(const float* __restrict__ x,
                               const float* __restrict__ atom_emb,
                               const float* __restrict__ bool_emb,
                               const float* __restrict__ Wn,
                               const float* __restrict__ bn,
                               float* __restrict__ h0) {
  int n = blockIdx.x * blockDim.x + threadIdx.x;
  if (n >= N_NODES) return;
  const float* xr = x + (size_t)n * 14;
  float* h = h0 + (size_t)n * 64;
  int ai = (int)xr[0];
  #pragma unroll
  for (int j = 0; j < 16; j++) h[j] = atom_emb[ai * 16 + j];
  float xc[10];
  #pragma unroll
  for (int k = 0; k < 10; k++) xc[k] = xr[1 + k];
  #pragma unroll
  for (int c = 0; c < 30; c++) {
    float s = bn[c];
    #pragma unroll
    for (int k = 0; k < 10; k++) s += xc[k] * Wn[k * 30 + c];
    h[16 + c] = s;
  }
  #pragma unroll
  for (int t = 0; t < 3; t++) {
    int b = (int)xr[11 + t];
    h[46 + 2 * t]     = bool_emb[2 * b];
    h[46 + 2 * t + 1] = bool_emb[2 * b + 1];
  }
  #pragma unroll
  for (int j = 52; j < 64; j++) h[j] = 0.0f;  // zero pad for K=64 GEMM
}

// ---------------- in-degree histogram ----------------
__global__ void k_hist(const int* __restrict__ dst, int* __restrict__ cnt) {
  int e = blockIdx.x * blockDim.x + threadIdx.x;
  if (e >= N_EDGES) return;
  atomicAdd(cnt + dst[e], 1);
}

// ---------------- fused logit table: elin = T12[meta] + ec*v ----------------
// T12[combo*32+bi] = Wedge^T(bond_emb[bi]) + Wedge^T(bool terms + be part).
__global__ void k_build_tabs(const float* __restrict__ Wedge1,
                             const float* __restrict__ Wedge2,
                             const float* __restrict__ bond_emb,
                             const float* __restrict__ bool_emb,
                             const float* __restrict__ We,
                             const float* __restrict__ be,
                             float* __restrict__ tabs) {
  int t = threadIdx.x;
  int s = t >> 7, c = t & 127;
  const float* W = s ? Wedge2 : Wedge1;
  float* T12 = tabs + s * TAB_STRIDE;
  float* v   = T12 + 256 * 128;
  float w8 = W[8 * 128 + c], w9 = W[9 * 128 + c];
  v[c] = We[0] * w8 + We[1] * w9;
  float cst = be[0] * w8 + be[1] * w9;
  float bond[22];
  for (int b = 0; b < 22; b++) {
    float acc = 0.f;
    #pragma unroll
    for (int k = 0; k < 8; k++) acc += bond_emb[b * 8 + k] * W[k * 128 + c];
    bond[b] = acc;
  }
  for (int combo = 0; combo < 8; combo++) {
    float t2 = cst;
    #pragma unroll
    for (int tt = 0; tt < 3; tt++) {
      int bt = (combo >> tt) & 1;
      t2 += bool_emb[bt * 2 + 0] * W[(10 + 2 * tt + 0) * 128 + c];
      t2 += bool_emb[bt * 2 + 1] * W[(10 + 2 * tt + 1) * 128 + c];
    }
    for (int b = 0; b < 22; b++)
      T12[(combo * 32 + b) * 128 + c] = bond[b] + t2;
  }
}

// ---------------- W -> MFMA B-fragment prep (interleaved hi8|lo8) -----------
// frag fl: element j = W[(c*32 + (l>>4)*8 + j)*128 + (tn*16 + (l&15))],
// stored at base + fl*16 (hi) / +8 (lo). Layout: Wl1@0 Wr1@F1 Wl2@2F1 Wr2@2F1+F2
__global__ __launch_bounds__(256) void k_prep(const float* __restrict__ Wl1,
                                              const float* __restrict__ Wr1,
                                              const float* __restrict__ Wl2,
                                              const float* __restrict__ Wr2,
                                              unsigned short* __restrict__ fr) {
  int g = blockIdx.x * 256 + threadIdx.x;
  const float* W; int K; unsigned short* base; int fl;
  if (g < 1024)      { W = Wl1; K = 52;  base = fr;                fl = g; }
  else if (g < 2048) { W = Wr1; K = 52;  base = fr + F1;           fl = g - 1024; }
  else if (g < 4096) { W = Wl2; K = 128; base = fr + 2 * F1;       fl = g - 2048; }
  else if (g < 6144) { W = Wr2; K = 128; base = fr + 2 * F1 + F2;  fl = g - 4096; }
  else return;
  int l = fl & 63, ctn = fl >> 6;
  int tn = ctn & 7, c = ctn >> 3;
  int n = tn * 16 + (l & 15);
  int kb = c * 32 + (l >> 4) * 8;
  unsigned h8[8], l8[8];
  #pragma unroll
  for (int j = 0; j < 8; j++) {
    int k = kb + j;
    float v = (k < K) ? W[(size_t)k * 128 + n] : 0.f;
    unsigned short hh = f2bf(v);
    h8[j] = hh;
    l8[j] = f2bf(v - bf2f(hh));
  }
  uint4 hv = make_uint4(h8[0] | (h8[1] << 16), h8[2] | (h8[3] << 16),
                        h8[4] | (h8[5] << 16), h8[6] | (h8[7] << 16));
  uint4 lv = make_uint4(l8[0] | (l8[1] << 16), l8[2] | (l8[3] << 16),
                        l8[4] | (l8[5] << 16), l8[6] | (l8[7] << 16));
  *(uint4*)(base + (size_t)fl * 16) = hv;
  *(uint4*)(base + (size_t)fl * 16 + 8) = lv;
}

// ---------------- hierarchical scan over (cnt[n]+1), 3 phases ---------------
__global__ __launch_bounds__(256) void k_scan1(const int* __restrict__ cnt,
                                               int* __restrict__ bsum) {
  __shared__ int red[256];
  int b = blockIdx.x, t = threadIdx.x;
  int beg = b * SCAN_CHUNK;
  int end = beg + SCAN_CHUNK; if (end > N_NODES) end = N_NODES;
  int s = 0;
  for (int i = beg + t; i < end; i += 256) s += cnt[i] + 1;
  red[t] = s;
  __syncthreads();
  for (int off = 128; off > 0; off >>= 1) {
    if (t < off) red[t] += red[t + off];
    __syncthreads();
  }
  if (t == 0) bsum[b] = red[0];
}

__global__ __launch_bounds__(256) void k_scan2(int* __restrict__ bsum) {
  __shared__ int sh[256];
  int t = threadIdx.x;
  sh[t] = bsum[t];
  __syncthreads();
  for (int off = 1; off < 256; off <<= 1) {
    int v = (t >= off) ? sh[t - off] : 0;
    __syncthreads();
    sh[t] += v;
    __syncthreads();
  }
  bsum[t] = (t > 0) ? sh[t - 1] : 0;  // exclusive
}

__global__ __launch_bounds__(256) void k_scan3(const int* __restrict__ cnt,
                                               const int* __restrict__ bsum,
                                               int* __restrict__ indptr,
                                               int* __restrict__ cursor) {
  __shared__ int sh[256];
  __shared__ int carry;
  int b = blockIdx.x, t = threadIdx.x;
  int beg = b * SCAN_CHUNK;
  int end = beg + SCAN_CHUNK; if (end > N_NODES) end = N_NODES;
  if (t == 0) carry = bsum[b];
  __syncthreads();
  for (int base = beg; base < end; base += 256) {
    int i = base + t;
    int v = (i < end) ? cnt[i] + 1 : 0;
    sh[t] = v;
    __syncthreads();
    for (int off = 1; off < 256; off <<= 1) {
      int u = (t >= off) ? sh[t - off] : 0;
      __syncthreads();
      sh[t] += u;
      __syncthreads();
    }
    int excl = sh[t] - v;
    if (i < end) {
      int val = carry + excl;
      indptr[i] = val;
      cursor[i] = val;
    }
    __syncthreads();
    if (t == 255) carry += sh[255];
    __syncthreads();
  }
  if (b == 0 && t == 0) indptr[N_NODES] = N_EDGES + N_NODES;
}

// ---------------- CSR fill: ordinary edges into slots [beg, end-1) ----------
__global__ void k_fill(const int* __restrict__ srcA,
                       const int* __restrict__ dst,
                       const float* __restrict__ eattr,
                       int* __restrict__ cursor,
                       int4* __restrict__ scode) {
  int e = blockIdx.x * blockDim.x + threadIdx.x;
  if (e >= N_EDGES) return;
  const float* r = eattr + (size_t)e * 5;
  int bi = (int)r[0];
  float ec = r[1];
  int combo = (int)r[2] + 2 * (int)r[3] + 4 * (int)r[4];
  int meta = bi | (combo << 5);
  int d = dst[e];
  int p = atomicAdd(&cursor[d], 1);
  scode[p] = make_int4(srcA[e], meta, __float_as_int(ec), 0);
}

// ---------------- MFMA dual GEMM, M=32/wave: xl/xr = A @ {Wl,Wr} + b --------
// 2 A-strips share every B-fragment load (halves L2 B traffic). Split-bf16
// (3 MFMA) for fp32-class accuracy. launch_bounds(256,2) caps VGPR at 256.
template <int KPAD>
__global__ __launch_bounds__(256, 2) void k_gemm2m(const float* __restrict__ A,
                                                   const unsigned short* __restrict__ WfL,
                                                   const unsigned short* __restrict__ WfR,
                                                   const float* __restrict__ bl_,
                                                   const float* __restrict__ br_,
                                                   float* __restrict__ outl,
                                                   float* __restrict__ outr) {
  const int tw = blockIdx.x * 4 + (threadIdx.x >> 6);
  if (tw >= N_NODES / 32) return;  // 3125 wave-tiles
  const int lane = threadIdx.x & 63;
  const int ml = lane & 15, q = lane >> 4;
  const int m0 = tw * 32;
  f32x4 aL0[8], aL1[8], aR0[8], aR1[8];
  #pragma unroll
  for (int t = 0; t < 8; t++) {
    aL0[t] = (f32x4){0.f, 0.f, 0.f, 0.f};
    aL1[t] = (f32x4){0.f, 0.f, 0.f, 0.f};
    aR0[t] = (f32x4){0.f, 0.f, 0.f, 0.f};
    aR1[t] = (f32x4){0.f, 0.f, 0.f, 0.f};
  }
  const float* ar0 = A + (size_t)(m0 + ml) * KPAD + q * 8;
  const float* ar1 = ar0 + (size_t)16 * KPAD;
  constexpr int NC = KPAD / 32;
  #pragma unroll
  for (int c = 0; c < NC; c++) {
    float4 x0 = *(const float4*)(ar0 + c * 32);
    float4 x1 = *(const float4*)(ar0 + c * 32 + 4);
    float4 x2 = *(const float4*)(ar1 + c * 32);
    float4 x3 = *(const float4*)(ar1 + c * 32 + 4);
    float a0v[8] = {x0.x, x0.y, x0.z, x0.w, x1.x, x1.y, x1.z, x1.w};
    float a1v[8] = {x2.x, x2.y, x2.z, x2.w, x3.x, x3.y, x3.z, x3.w};
    bf16x8 a0h, a0l, a1h, a1l;
    #pragma unroll
    for (int j = 0; j < 8; j++) {
      unsigned short h0 = f2bf(a0v[j]);
      a0h[j] = (short)h0; a0l[j] = (short)f2bf(a0v[j] - bf2f(h0));
      unsigned short h1 = f2bf(a1v[j]);
      a1h[j] = (short)h1; a1l[j] = (short)f2bf(a1v[j] - bf2f(h1));
    }
    #pragma unroll
    for (int t = 0; t < 8; t++) {
      size_t fo = ((size_t)(c * 8 + t) * 64 + lane) * 16;
      bf16x8 bhL = *(const bf16x8*)(WfL + fo);
      bf16x8 blL = *(const bf16x8*)(WfL + fo + 8);
      bf16x8 bhR = *(const bf16x8*)(WfR + fo);
      bf16x8 blR = *(const bf16x8*)(WfR + fo + 8);
      aL0[t] = __builtin_amdgcn_mfma_f32_16x16x32_bf16(a0h, bhL, aL0[t], 0, 0, 0);
      aL0[t] = __builtin_amdgcn_mfma_f32_16x16x32_bf16(a0l, bhL, aL0[t], 0, 0, 0);
      aL0[t] = __builtin_amdgcn_mfma_f32_16x16x32_bf16(a0h, blL, aL0[t], 0, 0, 0);
      aL1[t] = __builtin_amdgcn_mfma_f32_16x16x32_bf16(a1h, bhL, aL1[t], 0, 0, 0);
      aL1[t] = __builtin_amdgcn_mfma_f32_16x16x32_bf16(a1l, bhL, aL1[t], 0, 0, 0);
      aL1[t] = __builtin_amdgcn_mfma_f32_16x16x32_bf16(a1h, blL, aL1[t], 0, 0, 0);
      aR0[t] = __builtin_amdgcn_mfma_f32_16x16x32_bf16(a0h, bhR, aR0[t], 0, 0, 0);
      aR0[t] = __builtin_amdgcn_mfma_f32_16x16x32_bf16(a0l, bhR, aR0[t], 0, 0, 0);
      aR0[t] = __builtin_amdgcn_mfma_f32_16x16x32_bf16(a0h, blR, aR0[t], 0, 0, 0);
      aR1[t] = __builtin_amdgcn_mfma_f32_16x16x32_bf16(a1h, bhR, aR1[t], 0, 0, 0);
      aR1[t] = __builtin_amdgcn_mfma_f32_16x16x32_bf16(a1l, bhR, aR1[t], 0, 0, 0);
      aR1[t] = __builtin_amdgcn_mfma_f32_16x16x32_bf16(a1h, blR, aR1[t], 0, 0, 0);
    }
  }
  // epilogue: C/D layout col=lane&15, row=quad*4+reg; strips at m0 and m0+16
  #pragma unroll
  for (int t = 0; t < 8; t++) {
    int n = t * 16 + ml;
    float bL = bl_[n], bR = br_[n];
    #pragma unroll
    for (int r = 0; r < 4; r++) {
      int row0 = m0 + q * 4 + r;
      int row1 = row0 + 16;
      outl[(size_t)row0 * 128 + n] = aL0[t][r] + bL;
      outl[(size_t)row1 * 128 + n] = aL1[t][r] + bL;
      outr[(size_t)row0 * 128 + n] = aR0[t][r] + bR;
      outr[(size_t)row1 * 128 + n] = aR1[t][r] + bR;
    }
  }
}

// ---------------- GATv2 edge pass: 32 lanes/node (2 nodes per wave) ---------
// Plain-sum softmax (logits are O(0.3): exp can't overflow; max-subtraction
// is a mathematical no-op on the ratio). Empty halves run lock-step with the
// sibling half — never use unvalidated scode data as an address.
__global__ __launch_bounds__(256) void k_gat(const float* __restrict__ xl,
                                             const float* __restrict__ xr,
                                             const int* __restrict__ indptr,
                                             const int4* __restrict__ scode,
                                             const float* __restrict__ tabs,
                                             const float* __restrict__ att,
                                             const float* __restrict__ bias,
                                             float* __restrict__ hout) {
  int wid = (blockIdx.x * 256 + threadIdx.x) >> 6;
  int nw = (gridDim.x * 256) >> 6;
  int lane = threadIdx.x & 63;
  int half = lane >> 5;
  int c = (lane & 31) * 4;  // 4 channels per lane
  const float* T12 = tabs;  // 256 x 128
  float4 v4 = *(const float4*)(tabs + 256 * 128 + c);
  float4 a4 = *(const float4*)(att + c);
  float4 b4 = *(const float4*)(bias + c);
  wid = __builtin_amdgcn_readfirstlane(wid);
  for (int nb = wid * 2; nb < N_NODES; nb += nw * 2) {
    int n = nb + half;
    int beg = indptr[n], end1 = indptr[n + 1] - 1;  // end1 = self-loop slot
    int last = (end1 > beg) ? end1 - 1 : beg;       // clamp (may be unwritten!)
    float4 xrv = *(const float4*)(xr + (size_t)n * 128 + c);
    float denom = 0.f;
    float4 acc = make_float4(0.f, 0.f, 0.f, 0.f);
    float4 els = make_float4(0.f, 0.f, 0.f, 0.f);
    int my_it = (end1 - beg + 3) >> 2;
    int ot = __shfl_xor(my_it, 32, 64);
    int iters = my_it > ot ? my_it : ot;  // wave-uniform
    for (int it = 0; it < iters; it++) {
      int j = beg + it * 4;
      int4 sc4[4]; float4 xlv[4]; float tt[4]; float4 el[4];
      bool val[4];
      #pragma unroll
      for (int u = 0; u < 4; u++) {
        val[u] = (j + u < end1);  // uniform within half
        int jj = val[u] ? j + u : last;
        sc4[u] = scode[jj];
      }
      #pragma unroll
      for (int u = 0; u < 4; u++) {
        int s = val[u] ? sc4[u].x : n;  // NEVER use poison as an address
        xlv[u] = *(const float4*)(xl + (size_t)s * 128 + c);
      }
      #pragma unroll
      for (int u = 0; u < 4; u++) {
        int meta = val[u] ? (sc4[u].y & 255) : 0;
        float ec = val[u] ? __int_as_float(sc4[u].z) : 0.f;
        float4 t12 = *(const float4*)(T12 + (size_t)meta * 128 + c);
        el[u].x = t12.x + ec * v4.x;
        el[u].y = t12.y + ec * v4.y;
        el[u].z = t12.z + ec * v4.z;
        el[u].w = t12.w + ec * v4.w;
        float m0 = xlv[u].x + xrv.x + el[u].x;
        float m1 = xlv[u].y + xrv.y + el[u].y;
        float m2 = xlv[u].z + xrv.z + el[u].z;
        float m3 = xlv[u].w + xrv.w + el[u].w;
        float l0 = m0 > 0.f ? m0 : 0.2f * m0;
        float l1 = m1 > 0.f ? m1 : 0.2f * m1;
        float l2 = m2 > 0.f ? m2 : 0.2f * m2;
        float l3 = m3 > 0.f ? m3 : 0.2f * m3;
        tt[u] = l0 * a4.x + l1 * a4.y + l2 * a4.z + l3 * a4.w;
      }
      // 8 independent half-wave reduction chains (4 per node), 5 steps
      #pragma unroll
      for (int off = 1; off < 32; off <<= 1) {
        tt[0] += __shfl_xor(tt[0], off, 64);
        tt[1] += __shfl_xor(tt[1], off, 64);
        tt[2] += __shfl_xor(tt[2], off, 64);
        tt[3] += __shfl_xor(tt[3], off, 64);
      }
      #pragma unroll
      for (int u = 0; u < 4; u++) {
        float ex = val[u] ? __expf(tt[u]) : 0.f;
        denom += ex;
        acc.x += ex * xlv[u].x;
        acc.y += ex * xlv[u].y;
        acc.z += ex * xlv[u].z;
        acc.w += ex * xlv[u].w;
        els.x += val[u] ? el[u].x : 0.f;
        els.y += val[u] ? el[u].y : 0.f;
        els.z += val[u] ? el[u].z : 0.f;
        els.w += val[u] ? el[u].w : 0.f;
      }
    }
    // self-loop (always present, processed last)
    int cntn = end1 - beg;
    float inv_cnt = 1.0f / (float)(cntn > 0 ? cntn : 1);
    float4 xln = *(const float4*)(xl + (size_t)n * 128 + c);
    float m0 = xln.x + xrv.x + els.x * inv_cnt;
    float m1 = xln.y + xrv.y + els.y * inv_cnt;
    float m2 = xln.z + xrv.z + els.z * inv_cnt;
    float m3 = xln.w + xrv.w + els.w * inv_cnt;
    float l0 = m0 > 0.f ? m0 : 0.2f * m0;
    float l1 = m1 > 0.f ? m1 : 0.2f * m1;
    float l2 = m2 > 0.f ? m2 : 0.2f * m2;
    float l3 = m3 > 0.f ? m3 : 0.2f * m3;
    float ts = l0 * a4.x + l1 * a4.y + l2 * a4.z + l3 * a4.w;
    #pragma unroll
    for (int off = 1; off < 32; off <<= 1) ts += __shfl_xor(ts, off, 64);
    float ex = __expf(ts);
    denom += ex;
    acc.x += ex * xln.x;
    acc.y += ex * xln.y;
    acc.z += ex * xln.z;
    acc.w += ex * xln.w;
    float invd = 1.0f / denom;
    float o0 = acc.x * invd + b4.x;
    float o1 = acc.y * invd + b4.y;
    float o2 = acc.z * invd + b4.z;
    float o3 = acc.w * invd + b4.w;
    float4 o = make_float4(o0 > 0.f ? o0 : 0.f, o1 > 0.f ? o1 : 0.f,
                           o2 > 0.f ? o2 : 0.f, o3 > 0.f ? o3 : 0.f);
    *(float4*)(hout + (size_t)n * 128 + c) = o;
  }
}

// ---------------- readout: global max pool over 20 contiguous nodes --------
__global__ void k_readout(const float* __restrict__ h, float* __restrict__ out) {
  int wid = (blockIdx.x * blockDim.x + threadIdx.x) >> 6;
  int lane = threadIdx.x & 63;
  if (wid >= N_GRAPHS) return;
  int c = lane * 2;
  float m0 = -1e30f, m1 = -1e30f;
  for (int i = 0; i < NPG; i++) {
    const float2 v = *(const float2*)(h + ((size_t)(wid * NPG + i)) * 128 + c);
    m0 = fmaxf(m0, v.x);
    m1 = fmaxf(m1, v.y);
  }
  float2 o; o.x = m0; o.y = m1;
  *(float2*)(out + (size_t)wid * 128 + c) = o;
}

extern "C" void kernel_launch(void* const* d_in, const int* in_sizes, int n_in,
                              void* d_out, int out_size, void* d_ws, size_t ws_size,
                              hipStream_t stream) {
  (void)in_sizes; (void)n_in; (void)out_size; (void)ws_size;
  const float* x        = (const float*)d_in[0];
  const int*   eindex   = (const int*)d_in[1];
  const float* eattr    = (const float*)d_in[2];
  const float* atom_emb = (const float*)d_in[4];
  const float* bond_emb = (const float*)d_in[5];
  const float* bool_emb = (const float*)d_in[6];
  const float* Wn   = (const float*)d_in[7];
  const float* bn   = (const float*)d_in[8];
  const float* We   = (const float*)d_in[9];
  const float* be   = (const float*)d_in[10];
  const float* Wl1  = (const float*)d_in[11];
  const float* bl1  = (const float*)d_in[12];
  const float* Wr1  = (const float*)d_in[13];
  const float* br1  = (const float*)d_in[14];
  const float* Wedge1 = (const float*)d_in[15];
  const float* att1 = (const float*)d_in[16];
  const float* bias1 = (const float*)d_in[17];
  const float* Wl2  = (const float*)d_in[18];
  const float* bl2  = (const float*)d_in[19];
  const float* Wr2  = (const float*)d_in[20];
  const float* br2  = (const float*)d_in[21];
  const float* Wedge2 = (const float*)d_in[22];
  const float* att2 = (const float*)d_in[23];
  const float* bias2 = (const float*)d_in[24];

  const int* srcA = eindex;
  const int* dstA = eindex + N_EDGES;

  char* p = (char*)d_ws;
  auto alloc = [&](size_t bytes) {
    char* r = p;
    p += (bytes + 255) & ~(size_t)255;
    return r;
  };
  float* h0     = (float*)alloc((size_t)N_NODES * 64 * 4);
  float* h      = (float*)alloc((size_t)N_NODES * 128 * 4);
  float* xl     = (float*)alloc((size_t)N_NODES * 128 * 4);
  float* xrb    = (float*)alloc((size_t)N_NODES * 128 * 4);
  int*   cnt    = (int*)alloc((size_t)N_NODES * 4);
  int*   indptr = (int*)alloc((size_t)(N_NODES + 1) * 4);
  int*   cursor = (int*)alloc((size_t)N_NODES * 4);
  int4*  scode  = (int4*)alloc((size_t)(N_EDGES + N_NODES) * 16);
  float* tabs   = (float*)alloc((size_t)2 * TAB_STRIDE * 4);
  unsigned short* wfrag = (unsigned short*)alloc((size_t)(2 * F1 + 2 * F2) * 2);
  int*   bsum   = (int*)alloc((size_t)SCAN_NB * 4);

  hipMemsetAsync(cnt, 0, (size_t)N_NODES * 4, stream);

  k_encode_nodes<<<(N_NODES + 255) / 256, 256, 0, stream>>>(x, atom_emb, bool_emb, Wn, bn, h0);
  k_hist<<<(N_EDGES + 255) / 256, 256, 0, stream>>>(dstA, cnt);
  k_build_tabs<<<1, 256, 0, stream>>>(Wedge1, Wedge2, bond_emb, bool_emb, We, be, tabs);
  k_prep<<<24, 256, 0, stream>>>(Wl1, Wr1, Wl2, Wr2, wfrag);
  k_scan1<<<SCAN_NB, 256, 0, stream>>>(cnt, bsum);
  k_scan2<<<1, 256, 0, stream>>>(bsum);
  k_scan3<<<SCAN_NB, 256, 0, stream>>>(cnt, bsum, indptr, cursor);
  k_fill<<<(N_EDGES + 255) / 256, 256, 0, stream>>>(srcA, dstA, eattr, cursor, scode);

  const unsigned short* f_l1 = wfrag;
  const unsigned short* f_r1 = wfrag + F1;
  const unsigned short* f_l2 = wfrag + 2 * F1;
  const unsigned short* f_r2 = wfrag + 2 * F1 + F2;

  const int GB2 = (N_NODES / 32 + 3) / 4;  // 782 blocks of 4 wave-tiles

  // layer 1 (K=52 zero-padded to 64)
  k_gemm2m<64><<<GB2, 256, 0, stream>>>(h0, f_l1, f_r1, bl1, br1, xl, xrb);
  k_gat<<<2048, 256, 0, stream>>>(xl, xrb, indptr, scode, tabs, att1, bias1, h);

  // layer 2 (K=128)
  k_gemm2m<128><<<GB2, 256, 0, stream>>>(h, f_l2, f_r2, bl2, br2, xl, xrb);
  k_gat<<<2048, 256, 0, stream>>>(xl, xrb, indptr, scode, tabs + TAB_STRIDE, att2, bias2, h);

  // layer 3 (shared weights with layer 2)
  k_gemm2m<128><<<GB2, 256, 0, stream>>>(h, f_l2, f_r2, bl2, br2, xl, xrb);
  k_gat<<<2048, 256, 0, stream>>>(xl, xrb, indptr, scode, tabs + TAB_STRIDE, att2, bias2, h);

  k_readout<<<(N_GRAPHS * 64 + 255) / 256, 256, 0, stream>>>(h, (float*)d_out);
}

// Round 11
// 466.054 us; speedup vs baseline: 7.2414x; 1.0952x over previous
//
#include <hip/hip_runtime.h>
#include <hip/hip_fp16.h>

#define N_NODES 100000
#define N_EDGES 400000
#define N_GRAPHS 5000
#define NPG 20
#define SCAN_NB 256
#define SCAN_CHUNK ((N_NODES + SCAN_NB - 1) / SCAN_NB)  // 391
#define TAB_STRIDE (256 * 128 + 128)  // T12[256][128] + v[128]
#define F1 16384  // ushorts per K=64 frag array (1024 frags * 16: hi8|lo8)
#define F2 32768  // ushorts per K=128 frag array (2048 frags * 16)
#define NB_ENC ((N_NODES + 255) / 256)   // 391
#define NB_HIST ((N_EDGES + 255) / 256)  // 1563

typedef __attribute__((ext_vector_type(8))) short bf16x8;
typedef __attribute__((ext_vector_type(4))) float f32x4;

__device__ __forceinline__ unsigned short f2bf(float f) {
  unsigned u = __float_as_uint(f);
  unsigned r = (u + 0x7FFFu + ((u >> 16) & 1u)) >> 16;
  return (unsigned short)r;
}
__device__ __forceinline__ float bf2f(unsigned short h) {
  return __uint_as_float(((unsigned)h) << 16);
}
__device__ __forceinline__ float4 h4_to_f4(const __half* p) {
  const __half2* q = (const __half2*)p;
  float2 a = __half22float2(q[0]);
  float2 b = __half22float2(q[1]);
  return make_float4(a.x, a.y, b.x, b.y);
}

// ---------------- fused prologue: encode_nodes | hist | tabs | prep ---------
__global__ __launch_bounds__(256) void k_prologue(
    const float* __restrict__ x, const float* __restrict__ atom_emb,
    const float* __restrict__ bool_emb, const float* __restrict__ Wn,
    const float* __restrict__ bn, float* __restrict__ h0,
    const int* __restrict__ dst, int* __restrict__ cnt,
    const float* __restrict__ Wedge1, const float* __restrict__ Wedge2,
    const float* __restrict__ bond_emb, const float* __restrict__ We,
    const float* __restrict__ be, float* __restrict__ tabs,
    const float* __restrict__ Wl1, const float* __restrict__ Wr1,
    const float* __restrict__ Wl2, const float* __restrict__ Wr2,
    unsigned short* __restrict__ fr) {
  int b = blockIdx.x, tid = threadIdx.x;
  if (b < NB_ENC) {
    // ---- node encoder: h0[N,64] (cols 52..63 zero) ----
    int n = b * 256 + tid;
    if (n >= N_NODES) return;
    const float* xr = x + (size_t)n * 14;
    float* h = h0 + (size_t)n * 64;
    int ai = (int)xr[0];
    #pragma unroll
    for (int j = 0; j < 16; j++) h[j] = atom_emb[ai * 16 + j];
    float xc[10];
    #pragma unroll
    for (int k = 0; k < 10; k++) xc[k] = xr[1 + k];
    #pragma unroll
    for (int c = 0; c < 30; c++) {
      float s = bn[c];
      #pragma unroll
      for (int k = 0; k < 10; k++) s += xc[k] * Wn[k * 30 + c];
      h[16 + c] = s;
    }
    #pragma unroll
    for (int t = 0; t < 3; t++) {
      int bb = (int)xr[11 + t];
      h[46 + 2 * t]     = bool_emb[2 * bb];
      h[46 + 2 * t + 1] = bool_emb[2 * bb + 1];
    }
    #pragma unroll
    for (int j = 52; j < 64; j++) h[j] = 0.0f;
  } else if (b < NB_ENC + NB_HIST) {
    // ---- in-degree histogram ----
    int e = (b - NB_ENC) * 256 + tid;
    if (e >= N_EDGES) return;
    atomicAdd(cnt + dst[e], 1);
  } else if (b == NB_ENC + NB_HIST) {
    // ---- fused logit table: T12[combo*32+bi], v ----
    int s = tid >> 7, c = tid & 127;
    const float* W = s ? Wedge2 : Wedge1;
    float* T12 = tabs + s * TAB_STRIDE;
    float* v   = T12 + 256 * 128;
    float w8 = W[8 * 128 + c], w9 = W[9 * 128 + c];
    v[c] = We[0] * w8 + We[1] * w9;
    float cst = be[0] * w8 + be[1] * w9;
    float bond[22];
    for (int bb = 0; bb < 22; bb++) {
      float acc = 0.f;
      #pragma unroll
      for (int k = 0; k < 8; k++) acc += bond_emb[bb * 8 + k] * W[k * 128 + c];
      bond[bb] = acc;
    }
    for (int combo = 0; combo < 8; combo++) {
      float t2 = cst;
      #pragma unroll
      for (int tt = 0; tt < 3; tt++) {
        int bt = (combo >> tt) & 1;
        t2 += bool_emb[bt * 2 + 0] * W[(10 + 2 * tt + 0) * 128 + c];
        t2 += bool_emb[bt * 2 + 1] * W[(10 + 2 * tt + 1) * 128 + c];
      }
      for (int bb = 0; bb < 22; bb++)
        T12[(combo * 32 + bb) * 128 + c] = bond[bb] + t2;
    }
  } else {
    // ---- W -> MFMA B-fragment prep (interleaved hi8|lo8) ----
    int g = (b - (NB_ENC + NB_HIST + 1)) * 256 + tid;
    const float* W; int K; unsigned short* base; int fl;
    if (g < 1024)      { W = Wl1; K = 52;  base = fr;               fl = g; }
    else if (g < 2048) { W = Wr1; K = 52;  base = fr + F1;          fl = g - 1024; }
    else if (g < 4096) { W = Wl2; K = 128; base = fr + 2 * F1;      fl = g - 2048; }
    else if (g < 6144) { W = Wr2; K = 128; base = fr + 2 * F1 + F2; fl = g - 4096; }
    else return;
    int l = fl & 63, ctn = fl >> 6;
    int tn = ctn & 7, c = ctn >> 3;
    int n = tn * 16 + (l & 15);
    int kb = c * 32 + (l >> 4) * 8;
    unsigned h8[8], l8[8];
    #pragma unroll
    for (int j = 0; j < 8; j++) {
      int k = kb + j;
      float v = (k < K) ? W[(size_t)k * 128 + n] : 0.f;
      unsigned short hh = f2bf(v);
      h8[j] = hh;
      l8[j] = f2bf(v - bf2f(hh));
    }
    uint4 hv = make_uint4(h8[0] | (h8[1] << 16), h8[2] | (h8[3] << 16),
                          h8[4] | (h8[5] << 16), h8[6] | (h8[7] << 16));
    uint4 lv = make_uint4(l8[0] | (l8[1] << 16), l8[2] | (l8[3] << 16),
                          l8[4] | (l8[5] << 16), l8[6] | (l8[7] << 16));
    *(uint4*)(base + (size_t)fl * 16) = hv;
    *(uint4*)(base + (size_t)fl * 16 + 8) = lv;
  }
}

// ---------------- hierarchical scan over (cnt[n]+1), 3 phases ---------------
__global__ __launch_bounds__(256) void k_scan1(const int* __restrict__ cnt,
                                               int* __restrict__ bsum) {
  __shared__ int red[256];
  int b = blockIdx.x, t = threadIdx.x;
  int beg = b * SCAN_CHUNK;
  int end = beg + SCAN_CHUNK; if (end > N_NODES) end = N_NODES;
  int s = 0;
  for (int i = beg + t; i < end; i += 256) s += cnt[i] + 1;
  red[t] = s;
  __syncthreads();
  for (int off = 128; off > 0; off >>= 1) {
    if (t < off) red[t] += red[t + off];
    __syncthreads();
  }
  if (t == 0) bsum[b] = red[0];
}

__global__ __launch_bounds__(256) void k_scan2(int* __restrict__ bsum) {
  __shared__ int sh[256];
  int t = threadIdx.x;
  sh[t] = bsum[t];
  __syncthreads();
  for (int off = 1; off < 256; off <<= 1) {
    int v = (t >= off) ? sh[t - off] : 0;
    __syncthreads();
    sh[t] += v;
    __syncthreads();
  }
  bsum[t] = (t > 0) ? sh[t - 1] : 0;  // exclusive
}

__global__ __launch_bounds__(256) void k_scan3(const int* __restrict__ cnt,
                                               const int* __restrict__ bsum,
                                               int* __restrict__ indptr,
                                               int* __restrict__ cursor) {
  __shared__ int sh[256];
  __shared__ int carry;
  int b = blockIdx.x, t = threadIdx.x;
  int beg = b * SCAN_CHUNK;
  int end = beg + SCAN_CHUNK; if (end > N_NODES) end = N_NODES;
  if (t == 0) carry = bsum[b];
  __syncthreads();
  for (int base = beg; base < end; base += 256) {
    int i = base + t;
    int v = (i < end) ? cnt[i] + 1 : 0;
    sh[t] = v;
    __syncthreads();
    for (int off = 1; off < 256; off <<= 1) {
      int u = (t >= off) ? sh[t - off] : 0;
      __syncthreads();
      sh[t] += u;
      __syncthreads();
    }
    int excl = sh[t] - v;
    if (i < end) {
      int val = carry + excl;
      indptr[i] = val;
      cursor[i] = val;
    }
    __syncthreads();
    if (t == 255) carry += sh[255];
    __syncthreads();
  }
  if (b == 0 && t == 0) indptr[N_NODES] = N_EDGES + N_NODES;
}

// ---------------- CSR fill: ordinary edges into slots [beg, end-1) ----------
__global__ void k_fill(const int* __restrict__ srcA,
                       const int* __restrict__ dst,
                       const float* __restrict__ eattr,
                       int* __restrict__ cursor,
                       int4* __restrict__ scode) {
  int e = blockIdx.x * blockDim.x + threadIdx.x;
  if (e >= N_EDGES) return;
  const float* r = eattr + (size_t)e * 5;
  int bi = (int)r[0];
  float ec = r[1];
  int combo = (int)r[2] + 2 * (int)r[3] + 4 * (int)r[4];
  int meta = bi | (combo << 5);
  int d = dst[e];
  int p = atomicAdd(&cursor[d], 1);
  scode[p] = make_int4(srcA[e], meta, __float_as_int(ec), 0);
}

// ---------------- MFMA dual GEMM, M=32/wave -> fp16 xl/xr -------------------
template <int KPAD>
__global__ __launch_bounds__(256, 2) void k_gemm2m(const float* __restrict__ A,
                                                   const unsigned short* __restrict__ WfL,
                                                   const unsigned short* __restrict__ WfR,
                                                   const float* __restrict__ bl_,
                                                   const float* __restrict__ br_,
                                                   __half* __restrict__ outl,
                                                   __half* __restrict__ outr) {
  const int tw = blockIdx.x * 4 + (threadIdx.x >> 6);
  if (tw >= N_NODES / 32) return;  // 3125 wave-tiles
  const int lane = threadIdx.x & 63;
  const int ml = lane & 15, q = lane >> 4;
  const int m0 = tw * 32;
  f32x4 aL0[8], aL1[8], aR0[8], aR1[8];
  #pragma unroll
  for (int t = 0; t < 8; t++) {
    aL0[t] = (f32x4){0.f, 0.f, 0.f, 0.f};
    aL1[t] = (f32x4){0.f, 0.f, 0.f, 0.f};
    aR0[t] = (f32x4){0.f, 0.f, 0.f, 0.f};
    aR1[t] = (f32x4){0.f, 0.f, 0.f, 0.f};
  }
  const float* ar0 = A + (size_t)(m0 + ml) * KPAD + q * 8;
  const float* ar1 = ar0 + (size_t)16 * KPAD;
  constexpr int NC = KPAD / 32;
  #pragma unroll
  for (int c = 0; c < NC; c++) {
    float4 x0 = *(const float4*)(ar0 + c * 32);
    float4 x1 = *(const float4*)(ar0 + c * 32 + 4);
    float4 x2 = *(const float4*)(ar1 + c * 32);
    float4 x3 = *(const float4*)(ar1 + c * 32 + 4);
    float a0v[8] = {x0.x, x0.y, x0.z, x0.w, x1.x, x1.y, x1.z, x1.w};
    float a1v[8] = {x2.x, x2.y, x2.z, x2.w, x3.x, x3.y, x3.z, x3.w};
    bf16x8 a0h, a0l, a1h, a1l;
    #pragma unroll
    for (int j = 0; j < 8; j++) {
      unsigned short h0 = f2bf(a0v[j]);
      a0h[j] = (short)h0; a0l[j] = (short)f2bf(a0v[j] - bf2f(h0));
      unsigned short h1 = f2bf(a1v[j]);
      a1h[j] = (short)h1; a1l[j] = (short)f2bf(a1v[j] - bf2f(h1));
    }
    #pragma unroll
    for (int t = 0; t < 8; t++) {
      size_t fo = ((size_t)(c * 8 + t) * 64 + lane) * 16;
      bf16x8 bhL = *(const bf16x8*)(WfL + fo);
      bf16x8 blL = *(const bf16x8*)(WfL + fo + 8);
      bf16x8 bhR = *(const bf16x8*)(WfR + fo);
      bf16x8 blR = *(const bf16x8*)(WfR + fo + 8);
      aL0[t] = __builtin_amdgcn_mfma_f32_16x16x32_bf16(a0h, bhL, aL0[t], 0, 0, 0);
      aL0[t] = __builtin_amdgcn_mfma_f32_16x16x32_bf16(a0l, bhL, aL0[t], 0, 0, 0);
      aL0[t] = __builtin_amdgcn_mfma_f32_16x16x32_bf16(a0h, blL, aL0[t], 0, 0, 0);
      aL1[t] = __builtin_amdgcn_mfma_f32_16x16x32_bf16(a1h, bhL, aL1[t], 0, 0, 0);
      aL1[t] = __builtin_amdgcn_mfma_f32_16x16x32_bf16(a1l, bhL, aL1[t], 0, 0, 0);
      aL1[t] = __builtin_amdgcn_mfma_f32_16x16x32_bf16(a1h, blL, aL1[t], 0, 0, 0);
      aR0[t] = __builtin_amdgcn_mfma_f32_16x16x32_bf16(a0h, bhR, aR0[t], 0, 0, 0);
      aR0[t] = __builtin_amdgcn_mfma_f32_16x16x32_bf16(a0l, bhR, aR0[t], 0, 0, 0);
      aR0[t] = __builtin_amdgcn_mfma_f32_16x16x32_bf16(a0h, blR, aR0[t], 0, 0, 0);
      aR1[t] = __builtin_amdgcn_mfma_f32_16x16x32_bf16(a1h, bhR, aR1[t], 0, 0, 0);
      aR1[t] = __builtin_amdgcn_mfma_f32_16x16x32_bf16(a1l, bhR, aR1[t], 0, 0, 0);
      aR1[t] = __builtin_amdgcn_mfma_f32_16x16x32_bf16(a1h, blR, aR1[t], 0, 0, 0);
    }
  }
  // epilogue: C/D layout col=lane&15, row=quad*4+reg; strips at m0 and m0+16
  #pragma unroll
  for (int t = 0; t < 8; t++) {
    int n = t * 16 + ml;
    float bL = bl_[n], bR = br_[n];
    #pragma unroll
    for (int r = 0; r < 4; r++) {
      int row0 = m0 + q * 4 + r;
      int row1 = row0 + 16;
      outl[(size_t)row0 * 128 + n] = __float2half(aL0[t][r] + bL);
      outl[(size_t)row1 * 128 + n] = __float2half(aL1[t][r] + bL);
      outr[(size_t)row0 * 128 + n] = __float2half(aR0[t][r] + bR);
      outr[(size_t)row1 * 128 + n] = __float2half(aR1[t][r] + bR);
    }
  }
}

// ---------------- GATv2 edge pass: 32 lanes/node, fp16 xl/xr ----------------
// Plain-sum softmax (logits O(0.3): exp can't overflow). Empty halves run
// lock-step with the sibling — never use unvalidated scode data as address.
__global__ __launch_bounds__(256) void k_gat(const __half* __restrict__ xl,
                                             const __half* __restrict__ xr,
                                             const int* __restrict__ indptr,
                                             const int4* __restrict__ scode,
                                             const float* __restrict__ tabs,
                                             const float* __restrict__ att,
                                             const float* __restrict__ bias,
                                             float* __restrict__ hout) {
  int wid = (blockIdx.x * 256 + threadIdx.x) >> 6;
  int nw = (gridDim.x * 256) >> 6;
  int lane = threadIdx.x & 63;
  int half = lane >> 5;
  int c = (lane & 31) * 4;  // 4 channels per lane
  const float* T12 = tabs;  // 256 x 128
  float4 v4 = *(const float4*)(tabs + 256 * 128 + c);
  float4 a4 = *(const float4*)(att + c);
  float4 b4 = *(const float4*)(bias + c);
  wid = __builtin_amdgcn_readfirstlane(wid);
  for (int nb = wid * 2; nb < N_NODES; nb += nw * 2) {
    int n = nb + half;
    int beg = indptr[n], end1 = indptr[n + 1] - 1;  // end1 = self-loop slot
    int last = (end1 > beg) ? end1 - 1 : beg;       // clamp (may be unwritten!)
    float4 xrv = h4_to_f4(xr + (size_t)n * 128 + c);
    float denom = 0.f;
    float4 acc = make_float4(0.f, 0.f, 0.f, 0.f);
    float4 els = make_float4(0.f, 0.f, 0.f, 0.f);
    int my_it = (end1 - beg + 3) >> 2;
    int ot = __shfl_xor(my_it, 32, 64);
    int iters = my_it > ot ? my_it : ot;  // wave-uniform
    for (int it = 0; it < iters; it++) {
      int j = beg + it * 4;
      int4 sc4[4]; float4 xlv[4]; float tt[4]; float4 el[4];
      bool val[4];
      #pragma unroll
      for (int u = 0; u < 4; u++) {
        val[u] = (j + u < end1);  // uniform within half
        int jj = val[u] ? j + u : last;
        sc4[u] = scode[jj];
      }
      #pragma unroll
      for (int u = 0; u < 4; u++) {
        int s = val[u] ? sc4[u].x : n;  // NEVER use poison as an address
        xlv[u] = h4_to_f4(xl + (size_t)s * 128 + c);
      }
      #pragma unroll
      for (int u = 0; u < 4; u++) {
        int meta = val[u] ? (sc4[u].y & 255) : 0;
        float ec = val[u] ? __int_as_float(sc4[u].z) : 0.f;
        float4 t12 = *(const float4*)(T12 + (size_t)meta * 128 + c);
        el[u].x = t12.x + ec * v4.x;
        el[u].y = t12.y + ec * v4.y;
        el[u].z = t12.z + ec * v4.z;
        el[u].w = t12.w + ec * v4.w;
        float m0 = xlv[u].x + xrv.x + el[u].x;
        float m1 = xlv[u].y + xrv.y + el[u].y;
        float m2 = xlv[u].z + xrv.z + el[u].z;
        float m3 = xlv[u].w + xrv.w + el[u].w;
        float l0 = m0 > 0.f ? m0 : 0.2f * m0;
        float l1 = m1 > 0.f ? m1 : 0.2f * m1;
        float l2 = m2 > 0.f ? m2 : 0.2f * m2;
        float l3 = m3 > 0.f ? m3 : 0.2f * m3;
        tt[u] = l0 * a4.x + l1 * a4.y + l2 * a4.z + l3 * a4.w;
      }
      // 8 independent half-wave reduction chains (4 per node), 5 steps
      #pragma unroll
      for (int off = 1; off < 32; off <<= 1) {
        tt[0] += __shfl_xor(tt[0], off, 64);
        tt[1] += __shfl_xor(tt[1], off, 64);
        tt[2] += __shfl_xor(tt[2], off, 64);
        tt[3] += __shfl_xor(tt[3], off, 64);
      }
      #pragma unroll
      for (int u = 0; u < 4; u++) {
        float ex = val[u] ? __expf(tt[u]) : 0.f;
        denom += ex;
        acc.x += ex * xlv[u].x;
        acc.y += ex * xlv[u].y;
        acc.z += ex * xlv[u].z;
        acc.w += ex * xlv[u].w;
        els.x += val[u] ? el[u].x : 0.f;
        els.y += val[u] ? el[u].y : 0.f;
        els.z += val[u] ? el[u].z : 0.f;
        els.w += val[u] ? el[u].w : 0.f;
      }
    }
    // self-loop (always present, processed last)
    int cntn = end1 - beg;
    float inv_cnt = 1.0f / (float)(cntn > 0 ? cntn : 1);
    float4 xln = h4_to_f4(xl + (size_t)n * 128 + c);
    float m0 = xln.x + xrv.x + els.x * inv_cnt;
    float m1 = xln.y + xrv.y + els.y * inv_cnt;
    float m2 = xln.z + xrv.z + els.z * inv_cnt;
    float m3 = xln.w + xrv.w + els.w * inv_cnt;
    float l0 = m0 > 0.f ? m0 : 0.2f * m0;
    float l1 = m1 > 0.f ? m1 : 0.2f * m1;
    float l2 = m2 > 0.f ? m2 : 0.2f * m2;
    float l3 = m3 > 0.f ? m3 : 0.2f * m3;
    float ts = l0 * a4.x + l1 * a4.y + l2 * a4.z + l3 * a4.w;
    #pragma unroll
    for (int off = 1; off < 32; off <<= 1) ts += __shfl_xor(ts, off, 64);
    float ex = __expf(ts);
    denom += ex;
    acc.x += ex * xln.x;
    acc.y += ex * xln.y;
    acc.z += ex * xln.z;
    acc.w += ex * xln.w;
    float invd = 1.0f / denom;
    float o0 = acc.x * invd + b4.x;
    float o1 = acc.y * invd + b4.y;
    float o2 = acc.z * invd + b4.z;
    float o3 = acc.w * invd + b4.w;
    float4 o = make_float4(o0 > 0.f ? o0 : 0.f, o1 > 0.f ? o1 : 0.f,
                           o2 > 0.f ? o2 : 0.f, o3 > 0.f ? o3 : 0.f);
    *(float4*)(hout + (size_t)n * 128 + c) = o;
  }
}

// ---------------- readout: global max pool over 20 contiguous nodes --------
__global__ void k_readout(const float* __restrict__ h, float* __restrict__ out) {
  int wid = (blockIdx.x * blockDim.x + threadIdx.x) >> 6;
  int lane = threadIdx.x & 63;
  if (wid >= N_GRAPHS) return;
  int c = lane * 2;
  float m0 = -1e30f, m1 = -1e30f;
  for (int i = 0; i < NPG; i++) {
    const float2 v = *(const float2*)(h + ((size_t)(wid * NPG + i)) * 128 + c);
    m0 = fmaxf(m0, v.x);
    m1 = fmaxf(m1, v.y);
  }
  float2 o; o.x = m0; o.y = m1;
  *(float2*)(out + (size_t)wid * 128 + c) = o;
}

extern "C" void kernel_launch(void* const* d_in, const int* in_sizes, int n_in,
                              void* d_out, int out_size, void* d_ws, size_t ws_size,
                              hipStream_t stream) {
  (void)in_sizes; (void)n_in; (void)out_size; (void)ws_size;
  const float* x        = (const float*)d_in[0];
  const int*   eindex   = (const int*)d_in[1];
  const float* eattr    = (const float*)d_in[2];
  const float* atom_emb = (const float*)d_in[4];
  const float* bond_emb = (const float*)d_in[5];
  const float* bool_emb = (const float*)d_in[6];
  const float* Wn   = (const float*)d_in[7];
  const float* bn   = (const float*)d_in[8];
  const float* We   = (const float*)d_in[9];
  const float* be   = (const float*)d_in[10];
  const float* Wl1  = (const float*)d_in[11];
  const float* bl1  = (const float*)d_in[12];
  const float* Wr1  = (const float*)d_in[13];
  const float* br1  = (const float*)d_in[14];
  const float* Wedge1 = (const float*)d_in[15];
  const float* att1 = (const float*)d_in[16];
  const float* bias1 = (const float*)d_in[17];
  const float* Wl2  = (const float*)d_in[18];
  const float* bl2  = (const float*)d_in[19];
  const float* Wr2  = (const float*)d_in[20];
  const float* br2  = (const float*)d_in[21];
  const float* Wedge2 = (const float*)d_in[22];
  const float* att2 = (const float*)d_in[23];
  const float* bias2 = (const float*)d_in[24];

  const int* srcA = eindex;
  const int* dstA = eindex + N_EDGES;

  char* p = (char*)d_ws;
  auto alloc = [&](size_t bytes) {
    char* r = p;
    p += (bytes + 255) & ~(size_t)255;
    return r;
  };
  float*  h0     = (float*)alloc((size_t)N_NODES * 64 * 4);
  float*  h      = (float*)alloc((size_t)N_NODES * 128 * 4);
  __half* xl     = (__half*)alloc((size_t)N_NODES * 128 * 2);
  __half* xrb    = (__half*)alloc((size_t)N_NODES * 128 * 2);
  int*    cnt    = (int*)alloc((size_t)N_NODES * 4);
  int*    indptr = (int*)alloc((size_t)(N_NODES + 1) * 4);
  int*    cursor = (int*)alloc((size_t)N_NODES * 4);
  int4*   scode  = (int4*)alloc((size_t)(N_EDGES + N_NODES) * 16);
  float*  tabs   = (float*)alloc((size_t)2 * TAB_STRIDE * 4);
  unsigned short* wfrag = (unsigned short*)alloc((size_t)(2 * F1 + 2 * F2) * 2);
  int*    bsum   = (int*)alloc((size_t)SCAN_NB * 4);

  hipMemsetAsync(cnt, 0, (size_t)N_NODES * 4, stream);

  // fused prologue: encode | hist | tabs | prep
  k_prologue<<<NB_ENC + NB_HIST + 1 + 24, 256, 0, stream>>>(
      x, atom_emb, bool_emb, Wn, bn, h0, dstA, cnt,
      Wedge1, Wedge2, bond_emb, We, be, tabs,
      Wl1, Wr1, Wl2, Wr2, wfrag);
  k_scan1<<<SCAN_NB, 256, 0, stream>>>(cnt, bsum);
  k_scan2<<<1, 256, 0, stream>>>(bsum);
  k_scan3<<<SCAN_NB, 256, 0, stream>>>(cnt, bsum, indptr, cursor);
  k_fill<<<(N_EDGES + 255) / 256, 256, 0, stream>>>(srcA, dstA, eattr, cursor, scode);

  const unsigned short* f_l1 = wfrag;
  const unsigned short* f_r1 = wfrag + F1;
  const unsigned short* f_l2 = wfrag + 2 * F1;
  const unsigned short* f_r2 = wfrag + 2 * F1 + F2;

  const int GB2 = (N_NODES / 32 + 3) / 4;  // 782 blocks of 4 wave-tiles

  // layer 1 (K=52 zero-padded to 64)
  k_gemm2m<64><<<GB2, 256, 0, stream>>>(h0, f_l1, f_r1, bl1, br1, xl, xrb);
  k_gat<<<2048, 256, 0, stream>>>(xl, xrb, indptr, scode, tabs, att1, bias1, h);

  // layer 2 (K=128)
  k_gemm2m<128><<<GB2, 256, 0, stream>>>(h, f_l2, f_r2, bl2, br2, xl, xrb);
  k_gat<<<2048, 256, 0, stream>>>(xl, xrb, indptr, scode, tabs + TAB_STRIDE, att2, bias2, h);

  // layer 3 (shared weights with layer 2)
  k_gemm2m<128><<<GB2, 256, 0, stream>>>(h, f_l2, f_r2, bl2, br2, xl, xrb);
  k_gat<<<2048, 256, 0, stream>>>(xl, xrb, indptr, scode, tabs + TAB_STRIDE, att2, bias2, h);

  k_readout<<<(N_GRAPHS * 64 + 255) / 256, 256, 0, stream>>>(h, (float*)d_out);
}